// Round 4
// baseline (718.374 us; speedup 1.0000x reference)
//
#include <hip/hip_runtime.h>
#include <hip/hip_bf16.h>

typedef __hip_bfloat16 bf16;

#define NN 4096
#define NE 32768
#define HH 128
#define MAXZ 100
#define TPB 8    // edges per block, TNE edge kernel
#define EPB 16   // edges per block, msg edge MLP kernel

__device__ __forceinline__ float b2f(bf16 v){ return __bfloat162float(v); }
__device__ __forceinline__ float ldf(const float* p, size_t i){ return p[i]; }
__device__ __forceinline__ float ldf(const bf16*  p, size_t i){ return __bfloat162float(p[i]); }
__device__ __forceinline__ float siluf(float x){ return x / (1.0f + __expf(-x)); }

// dtype detect: flag[0]=1 if float inputs are f32, 0 if bf16. Reads edge_attr words.
__global__ void __launch_bounds__(256) k_detect(const unsigned int* __restrict__ w, int* __restrict__ flag){
  __shared__ int cnt[256];
  int t = threadIdx.x;
  int c = 0;
  for (int i = t; i < 4096; i += 256){
    unsigned int lo = w[i] & 0xffffu;
    int e = (int)((lo >> 7) & 0xffu);
    c += (e >= 110 && e <= 132) ? 1 : 0;
  }
  cnt[t] = c; __syncthreads();
  for (int off=128; off>=1; off>>=1){ if (t<off) cnt[t]+=cnt[t+off]; __syncthreads(); }
  if (t==0) flag[0] = (cnt[0] < 2048) ? 1 : 0;
}

// ---------------- CSR build ----------------
__global__ void __launch_bounds__(256) k_count(const int* __restrict__ dst, int* __restrict__ counts){
  int e = blockIdx.x*256 + threadIdx.x;
  if (e < NE) atomicAdd(&counts[dst[e]], 1);
}

__global__ void __launch_bounds__(1024) k_scan(const int* __restrict__ counts, int* __restrict__ offsets, int* __restrict__ cursor){
  __shared__ int lds[1024];
  int t = threadIdx.x;
  int c0 = counts[4*t+0], c1 = counts[4*t+1], c2 = counts[4*t+2], c3 = counts[4*t+3];
  int s1 = c0+c1, s2 = s1+c2, s3 = s2+c3;
  lds[t] = s3;
  __syncthreads();
  for (int off=1; off<1024; off<<=1){
    int v = lds[t];
    int add = (t>=off)? lds[t-off] : 0;
    __syncthreads();
    lds[t] = v + add;
    __syncthreads();
  }
  int incl = lds[t];
  int base = incl - s3;
  offsets[4*t+0]=base;    offsets[4*t+1]=base+c0; offsets[4*t+2]=base+s1; offsets[4*t+3]=base+s2;
  cursor [4*t+0]=base;    cursor [4*t+1]=base+c0; cursor [4*t+2]=base+s1; cursor [4*t+3]=base+s2;
  if (t==1023) offsets[4096]=incl;
}

__global__ void __launch_bounds__(256) k_fill(const int* __restrict__ dst, int* __restrict__ cursor, int* __restrict__ csr){
  int e = blockIdx.x*256 + threadIdx.x;
  if (e < NE){ int p = atomicAdd(&cursor[dst[e]], 1); csr[p] = e; }
}

// ---------------- edge geometry: C, ev ----------------
template<typename T>
__global__ void __launch_bounds__(256) k_geom(const T* __restrict__ ew, const T* __restrict__ evec,
                       const int* __restrict__ src, const int* __restrict__ dst,
                       float* __restrict__ gC, float* __restrict__ gV, const int* __restrict__ flag){
  if (flag[0] != (int)(sizeof(T)==4)) return;
  int e = blockIdx.x*256 + threadIdx.x;
  if (e >= NE) return;
  float d = ldf(ew, e);
  float c = 0.5f*(cosf(d*0.6283185307179586f)+1.0f);
  c = (d < 5.0f) ? c : 0.0f;
  gC[e] = c;
  float x = ldf(evec, (size_t)e*3+0), y = ldf(evec, (size_t)e*3+1), z = ldf(evec, (size_t)e*3+2);
  if (src[e] != dst[e]){
    float n = sqrtf(x*x+y*y+z*z);
    float inv = 1.0f/fmaxf(n, 1e-12f);
    x*=inv; y*=inv; z*=inv;
  }
  gV[e*3+0]=x; gV[e*3+1]=y; gV[e*3+2]=z;
}

// ---------------- per-z embedding products ----------------
template<typename T>
__global__ void __launch_bounds__(128) k_zemb(const T* __restrict__ emb, const T* __restrict__ emb2_w,
                      float* __restrict__ P1z, float* __restrict__ P2z, const int* __restrict__ flag){
  if (flag[0] != (int)(sizeof(T)==4)) return;
  int zv = blockIdx.x, h = threadIdx.x;
  __shared__ float Zr[128];
  Zr[h] = ldf(emb, (size_t)zv*HH + h);
  __syncthreads();
  float p1=0.f, p2=0.f;
  for (int r=0;r<128;++r){
    float x = Zr[r];
    p1 += x*ldf(emb2_w, (size_t)r*HH+h);
    p2 += x*ldf(emb2_w, (size_t)(r+128)*HH+h);
  }
  P1z[zv*HH+h]=p1; P2z[zv*HH+h]=p2;
}

// ---------------- TNE edge coefficients -> eabuf bf16 [E][3][128] ----------------
template<typename T>
__global__ void __launch_bounds__(128) k_tne_edge(
  const T* __restrict__ eattr, const int* __restrict__ src, const int* __restrict__ dst,
  const int* __restrict__ z,
  const T* __restrict__ dp1_w, const T* __restrict__ dp1_b,
  const T* __restrict__ dp2_w, const T* __restrict__ dp2_b,
  const T* __restrict__ dp3_w, const T* __restrict__ dp3_b,
  const T* __restrict__ emb2_b, const float* __restrict__ P1z, const float* __restrict__ P2z,
  const float* __restrict__ gC, bf16* __restrict__ eabuf, const int* __restrict__ flag)
{
  if (flag[0] != (int)(sizeof(T)==4)) return;
  int e0 = blockIdx.x*TPB;
  int h  = threadIdx.x;
  __shared__ float attr[TPB][32];
  __shared__ int zd[TPB], zs[TPB];
  for (int i=h; i<TPB*32; i+=128) attr[i>>5][i&31] = ldf(eattr, (size_t)e0*32 + i);
  if (h < TPB){ int e=e0+h; zd[h]=z[dst[e]]; zs[h]=z[src[e]]; }
  __syncthreads();
  float w1[TPB], w2[TPB], w3[TPB];
  float b1v=ldf(dp1_b,h), b2v=ldf(dp2_b,h), b3v=ldf(dp3_b,h);
  #pragma unroll
  for (int e=0;e<TPB;++e){ w1[e]=b1v; w2[e]=b2v; w3[e]=b3v; }
  for (int r=0;r<32;++r){
    float u1=ldf(dp1_w,(size_t)r*HH+h), u2=ldf(dp2_w,(size_t)r*HH+h), u3=ldf(dp3_w,(size_t)r*HH+h);
    #pragma unroll
    for (int e=0;e<TPB;++e){ float a=attr[e][r]; w1[e]+=a*u1; w2[e]+=a*u2; w3[e]+=a*u3; }
  }
  float eb = ldf(emb2_b,h);
  #pragma unroll
  for (int e=0;e<TPB;++e){
    float zij = P1z[zd[e]*HH+h] + P2z[zs[e]*HH+h] + eb;
    float c = gC[e0+e];
    bf16* p = eabuf + (size_t)(e0+e)*384;
    p[h]     = __float2bfloat16(zij*w1[e]*c);
    p[128+h] = __float2bfloat16(zij*w2[e]*c);
    p[256+h] = __float2bfloat16(zij*w3[e]*c);
  }
}

// ---------------- TNE node (fused scatter + LN + fsc MLP + cmix) -> X9 ----------------
template<typename T>
__global__ void __launch_bounds__(128) k_tne_node(
  const int* __restrict__ offsets, const int* __restrict__ csr,
  const float* __restrict__ gV, const bf16* __restrict__ eabuf,
  const T* __restrict__ ln_g, const T* __restrict__ ln_b,
  const T* __restrict__ tne_lt,
  const T* __restrict__ s0_w, const T* __restrict__ s0_b,
  const T* __restrict__ s1_w, const T* __restrict__ s1_b,
  float* __restrict__ X9, const int* __restrict__ flag)
{
  if (flag[0] != (int)(sizeof(T)==4)) return;
  int n = blockIdx.x, h = threadIdx.x;
  float a=0, v0=0,v1=0,v2=0, s0=0,s1=0,s2=0,s3=0,s4=0,s5=0;
  int beg = offsets[n], end = offsets[n+1];
  for (int i=beg;i<end;++i){
    int e = csr[i];
    const bf16* p = eabuf + (size_t)e*384;
    float c1 = b2f(p[h]), c2 = b2f(p[128+h]), c3 = b2f(p[256+h]);
    float vx = gV[e*3+0], vy = gV[e*3+1], vz = gV[e*3+2];
    float tr3 = (vx*vx+vy*vy+vz*vz)*(1.0f/3.0f);
    a  += c1;
    v0 += c2*vx; v1 += c2*vy; v2 += c2*vz;
    s0 += c3*(vx*vx - tr3); s1 += c3*vx*vy;          s2 += c3*vx*vz;
    s3 += c3*(vy*vy - tr3); s4 += c3*vy*vz;          s5 += c3*(vz*vz - tr3);
  }
  float tn = 3.0f*a*a + 2.0f*(v0*v0+v1*v1+v2*v2)
           + s0*s0 + s3*s3 + s5*s5 + 2.0f*(s1*s1 + s2*s2 + s4*s4);
  __shared__ float red[128];
  red[h] = tn; __syncthreads();
  for (int off=64; off>=1; off>>=1){ if (h<off) red[h]+=red[h+off]; __syncthreads(); }
  float mean = red[0]*(1.0f/128.0f);
  __syncthreads();
  float dm = tn - mean;
  red[h] = dm*dm; __syncthreads();
  for (int off=64; off>=1; off>>=1){ if (h<off) red[h]+=red[h+off]; __syncthreads(); }
  float var = red[0]*(1.0f/128.0f);
  float ln = dm*rsqrtf(var+1e-5f)*ldf(ln_g,h) + ldf(ln_b,h);
  __shared__ float lnv[128];
  __shared__ float h1[256];
  lnv[h] = ln; __syncthreads();
  float a0 = ldf(s0_b,2*h), a1 = ldf(s0_b,2*h+1);
  for (int r=0;r<128;++r){ float x = lnv[r]; a0 += x*ldf(s0_w,(size_t)r*256+2*h); a1 += x*ldf(s0_w,(size_t)r*256+2*h+1); }
  h1[2*h] = siluf(a0); h1[2*h+1] = siluf(a1);
  __syncthreads();
  float f0 = ldf(s1_b,3*h), f1 = ldf(s1_b,3*h+1), f2 = ldf(s1_b,3*h+2);
  for (int r=0;r<256;++r){ float x = h1[r]; f0 += x*ldf(s1_w,(size_t)r*384+3*h); f1 += x*ldf(s1_w,(size_t)r*384+3*h+1); f2 += x*ldf(s1_w,(size_t)r*384+3*h+2); }
  f0 = siluf(f0); f1 = siluf(f1); f2 = siluf(f2);
  __shared__ float sm[10][128];
  sm[0][h]=a; sm[1][h]=v0; sm[2][h]=v1; sm[3][h]=v2;
  sm[4][h]=s0; sm[5][h]=s1; sm[6][h]=s2; sm[7][h]=s3; sm[8][h]=s4; sm[9][h]=s5;
  __syncthreads();
  float am=0, wm0=0,wm1=0,wm2=0, t0=0,t1=0,t2=0,t3=0,t4=0,t5=0;
  for (int r=0;r<128;++r){
    float w0 = ldf(tne_lt,(size_t)r*128+h);        am += sm[0][r]*w0;
    float w1 = ldf(tne_lt,(size_t)16384+r*128+h);  wm0 += sm[1][r]*w1; wm1 += sm[2][r]*w1; wm2 += sm[3][r]*w1;
    float w2 = ldf(tne_lt,(size_t)32768+r*128+h);  t0 += sm[4][r]*w2; t1 += sm[5][r]*w2; t2 += sm[6][r]*w2;
                                                   t3 += sm[7][r]*w2; t4 += sm[8][r]*w2; t5 += sm[9][r]*w2;
  }
  float x00 = f0*am + f2*t0;
  float x01 = -f1*wm2 + f2*t1;
  float x02 =  f1*wm1 + f2*t2;
  float x10 =  f1*wm2 + f2*t1;
  float x11 = f0*am + f2*t3;
  float x12 = -f1*wm0 + f2*t4;
  float x20 = -f1*wm1 + f2*t2;
  float x21 =  f1*wm0 + f2*t4;
  float x22 = f0*am + f2*t5;
  float* xp = X9 + (size_t)n*1152;
  xp[0*128+h]=x00; xp[1*128+h]=x01; xp[2*128+h]=x02;
  xp[3*128+h]=x10; xp[4*128+h]=x11; xp[5*128+h]=x12;
  xp[6*128+h]=x20; xp[7*128+h]=x21; xp[8*128+h]=x22;
}

// ---------------- msg edge MLP (EPB edges/block) -> eabuf bf16 [E][3][128] ----------------
template<typename T>
__global__ void __launch_bounds__(128) k_msg_edge(
  const T* __restrict__ eattr, const float* __restrict__ gC,
  const T* __restrict__ l0_w, const T* __restrict__ l0_b,
  const T* __restrict__ l1_w, const T* __restrict__ l1_b,
  const T* __restrict__ l2_w, const T* __restrict__ l2_b,
  bf16* __restrict__ eabuf, const int* __restrict__ flag)
{
  if (flag[0] != (int)(sizeof(T)==4)) return;
  int e0 = blockIdx.x*EPB;
  int h = threadIdx.x;
  __shared__ float attr[EPB][32];
  __shared__ float h1[EPB][128];
  __shared__ float h2[EPB][256];
  for (int i=h; i<EPB*32; i+=128) attr[i>>5][i&31] = ldf(eattr, (size_t)e0*32 + i);
  __syncthreads();
  {
    float b = ldf(l0_b,h);
    float a0[EPB];
    #pragma unroll
    for (int e=0;e<EPB;++e) a0[e]=b;
    for (int r=0;r<32;++r){
      float u = ldf(l0_w,(size_t)r*128+h);
      #pragma unroll
      for (int e=0;e<EPB;++e) a0[e] += attr[e][r]*u;
    }
    #pragma unroll
    for (int e=0;e<EPB;++e) h1[e][h] = siluf(a0[e]);
  }
  __syncthreads();
  {
    float ba = ldf(l1_b,2*h), bb = ldf(l1_b,2*h+1);
    float b0[EPB], b1a[EPB];
    #pragma unroll
    for (int e=0;e<EPB;++e){ b0[e]=ba; b1a[e]=bb; }
    for (int r=0;r<128;++r){
      float ua = ldf(l1_w,(size_t)r*256+2*h), ub = ldf(l1_w,(size_t)r*256+2*h+1);
      #pragma unroll
      for (int e=0;e<EPB;++e){ float x = h1[e][r]; b0[e]+=x*ua; b1a[e]+=x*ub; }
    }
    #pragma unroll
    for (int e=0;e<EPB;++e){ h2[e][2*h] = siluf(b0[e]); h2[e][2*h+1] = siluf(b1a[e]); }
  }
  __syncthreads();
  {
    float ba = ldf(l2_b,3*h), bb = ldf(l2_b,3*h+1), bc = ldf(l2_b,3*h+2);
    float c0[EPB], c1[EPB], c2[EPB];
    #pragma unroll
    for (int e=0;e<EPB;++e){ c0[e]=ba; c1[e]=bb; c2[e]=bc; }
    for (int r=0;r<256;++r){
      float u0 = ldf(l2_w,(size_t)r*384+3*h), u1 = ldf(l2_w,(size_t)r*384+3*h+1), u2 = ldf(l2_w,(size_t)r*384+3*h+2);
      #pragma unroll
      for (int e=0;e<EPB;++e){ float x = h2[e][r]; c0[e]+=x*u0; c1[e]+=x*u1; c2[e]+=x*u2; }
    }
    #pragma unroll
    for (int e=0;e<EPB;++e){
      float C = gC[e0+e];
      bf16* p = eabuf + (size_t)(e0+e)*384;
      p[h]     = __float2bfloat16(siluf(c0[e])*C);
      p[128+h] = __float2bfloat16(siluf(c1[e])*C);
      p[256+h] = __float2bfloat16(siluf(c2[e])*C);
    }
  }
}

// ---------------- msg node prep (4 nodes/block): normalize X (WRITE BACK), decompose, cmix lx -> Y10 bf16 ----------------
template<typename T>
__global__ void __launch_bounds__(128) k_msg_prep(
  float* __restrict__ X9, const T* __restrict__ lx, bf16* __restrict__ Y10,
  const int* __restrict__ flag)
{
  if (flag[0] != (int)(sizeof(T)==4)) return;
  int n0 = blockIdx.x*4, h = threadIdx.x;
  __shared__ float sm[4][10][128];
  #pragma unroll
  for (int nn=0;nn<4;++nn){
    float* xp = X9 + (size_t)(n0+nn)*1152;
    float x00=xp[0*128+h], x01=xp[1*128+h], x02=xp[2*128+h];
    float x10=xp[3*128+h], x11=xp[4*128+h], x12=xp[5*128+h];
    float x20=xp[6*128+h], x21=xp[7*128+h], x22=xp[8*128+h];
    float tn = x00*x00+x01*x01+x02*x02+x10*x10+x11*x11+x12*x12+x20*x20+x21*x21+x22*x22;
    float inv = 1.0f/(tn+1.0f);
    x00*=inv; x01*=inv; x02*=inv; x10*=inv; x11*=inv; x12*=inv; x20*=inv; x21*=inv; x22*=inv;
    // Reference REBINDS X to the normalized value before the layer update:
    // X = X/(tnorm+1); ... X = X + dX.  Write the normalized X back. (r3 bug fix)
    xp[0*128+h]=x00; xp[1*128+h]=x01; xp[2*128+h]=x02;
    xp[3*128+h]=x10; xp[4*128+h]=x11; xp[5*128+h]=x12;
    xp[6*128+h]=x20; xp[7*128+h]=x21; xp[8*128+h]=x22;
    float a = (x00+x11+x22)*(1.0f/3.0f);
    sm[nn][0][h]=a;
    sm[nn][1][h]=0.5f*(x21-x12);
    sm[nn][2][h]=0.5f*(x02-x20);
    sm[nn][3][h]=0.5f*(x10-x01);
    sm[nn][4][h]=x00-a;
    sm[nn][5][h]=0.5f*(x01+x10);
    sm[nn][6][h]=0.5f*(x02+x20);
    sm[nn][7][h]=x11-a;
    sm[nn][8][h]=0.5f*(x12+x21);
    sm[nn][9][h]=x22-a;
  }
  __syncthreads();
  float A[4]={0,0,0,0};
  float V0[4]={0,0,0,0}, V1[4]={0,0,0,0}, V2[4]={0,0,0,0};
  float S0[4]={0,0,0,0}, S1[4]={0,0,0,0}, S2[4]={0,0,0,0};
  float S3[4]={0,0,0,0}, S4[4]={0,0,0,0}, S5[4]={0,0,0,0};
  for (int r=0;r<128;++r){
    float w0 = ldf(lx,(size_t)r*128+h), w1 = ldf(lx,(size_t)16384+r*128+h), w2 = ldf(lx,(size_t)32768+r*128+h);
    #pragma unroll
    for (int nn=0;nn<4;++nn){
      A[nn]  += sm[nn][0][r]*w0;
      V0[nn] += sm[nn][1][r]*w1; V1[nn] += sm[nn][2][r]*w1; V2[nn] += sm[nn][3][r]*w1;
      S0[nn] += sm[nn][4][r]*w2; S1[nn] += sm[nn][5][r]*w2; S2[nn] += sm[nn][6][r]*w2;
      S3[nn] += sm[nn][7][r]*w2; S4[nn] += sm[nn][8][r]*w2; S5[nn] += sm[nn][9][r]*w2;
    }
  }
  #pragma unroll
  for (int nn=0;nn<4;++nn){
    bf16* yp = Y10 + (size_t)(n0+nn)*1280;
    yp[0*128+h]=__float2bfloat16(A[nn]);
    yp[1*128+h]=__float2bfloat16(V0[nn]); yp[2*128+h]=__float2bfloat16(V1[nn]); yp[3*128+h]=__float2bfloat16(V2[nn]);
    yp[4*128+h]=__float2bfloat16(S0[nn]); yp[5*128+h]=__float2bfloat16(S1[nn]); yp[6*128+h]=__float2bfloat16(S2[nn]);
    yp[7*128+h]=__float2bfloat16(S3[nn]); yp[8*128+h]=__float2bfloat16(S4[nn]); yp[9*128+h]=__float2bfloat16(S5[nn]);
  }
}

// ---------------- msg scatter + AB + decompose + cmix lt + dX update (fused) ----------------
template<typename T>
__global__ void __launch_bounds__(128) k_msg_sf(
  const int* __restrict__ offsets, const int* __restrict__ csr, const int* __restrict__ srcA,
  const bf16* __restrict__ eabuf, const bf16* __restrict__ Y10, const T* __restrict__ lt,
  float* __restrict__ X9, void* __restrict__ out, const int* __restrict__ flag, int write_out)
{
  if (flag[0] != (int)(sizeof(T)==4)) return;
  int n = blockIdx.x, h = threadIdx.x;
  float am=0, vm0=0,vm1=0,vm2=0, smm0=0,smm1=0,smm2=0,smm3=0,smm4=0,smm5=0;
  int beg = offsets[n], end = offsets[n+1];
  for (int i=beg;i<end;++i){
    int e = csr[i]; int s = srcA[e];
    const bf16* ep = eabuf + (size_t)e*384;
    float e0 = b2f(ep[h]), e1 = b2f(ep[128+h]), e2 = b2f(ep[256+h]);
    const bf16* yp = Y10 + (size_t)s*1280;
    am   += e0*b2f(yp[0*128+h]);
    vm0  += e1*b2f(yp[1*128+h]); vm1 += e1*b2f(yp[2*128+h]); vm2 += e1*b2f(yp[3*128+h]);
    smm0 += e2*b2f(yp[4*128+h]); smm1 += e2*b2f(yp[5*128+h]); smm2 += e2*b2f(yp[6*128+h]);
    smm3 += e2*b2f(yp[7*128+h]); smm4 += e2*b2f(yp[8*128+h]); smm5 += e2*b2f(yp[9*128+h]);
  }
  const bf16* yp = Y10 + (size_t)n*1280;
  float aY=b2f(yp[0*128+h]), u0=b2f(yp[1*128+h]), u1=b2f(yp[2*128+h]), u2=b2f(yp[3*128+h]);
  float q0=b2f(yp[4*128+h]), q1=b2f(yp[5*128+h]), q2=b2f(yp[6*128+h]);
  float q3=b2f(yp[7*128+h]), q4=b2f(yp[8*128+h]), q5=b2f(yp[9*128+h]);
  float m00=am+smm0,   m01=-vm2+smm1, m02= vm1+smm2;
  float m10= vm2+smm1, m11=am+smm3,  m12=-vm0+smm4;
  float m20=-vm1+smm2, m21= vm0+smm4, m22=am+smm5;
  float y00=aY+q0,  y01=-u2+q1, y02= u1+q2;
  float y10= u2+q1, y11=aY+q3,  y12=-u0+q4;
  float y20=-u1+q2, y21= u0+q4, y22=aY+q5;
  float ab00 = m00*y00+m01*y10+m02*y20 + y00*m00+y01*m10+y02*m20;
  float ab01 = m00*y01+m01*y11+m02*y21 + y00*m01+y01*m11+y02*m21;
  float ab02 = m00*y02+m01*y12+m02*y22 + y00*m02+y01*m12+y02*m22;
  float ab10 = m10*y00+m11*y10+m12*y20 + y10*m00+y11*m10+y12*m20;
  float ab11 = m10*y01+m11*y11+m12*y21 + y10*m01+y11*m11+y12*m21;
  float ab12 = m10*y02+m11*y12+m12*y22 + y10*m02+y11*m12+y12*m22;
  float ab20 = m20*y00+m21*y10+m22*y20 + y20*m00+y21*m10+y22*m20;
  float ab21 = m20*y01+m21*y11+m22*y21 + y20*m01+y21*m11+y22*m21;
  float ab22 = m20*y02+m21*y12+m22*y22 + y20*m02+y21*m12+y22*m22;
  float a2 = (ab00+ab11+ab22)*(1.0f/3.0f);
  float w0 = 0.5f*(ab21-ab12), w1 = 0.5f*(ab02-ab20), w2 = 0.5f*(ab10-ab01);
  float t0 = ab00-a2, t1 = 0.5f*(ab01+ab10), t2 = 0.5f*(ab02+ab20);
  float t3 = ab11-a2, t4 = 0.5f*(ab12+ab21), t5 = ab22-a2;
  float dnm = ab00*ab00+ab01*ab01+ab02*ab02+ab10*ab10+ab11*ab11+ab12*ab12
            + ab20*ab20+ab21*ab21+ab22*ab22 + 1.0f;
  float inv = 1.0f/dnm;
  __shared__ float sm[10][128];
  sm[0][h]=a2*inv; sm[1][h]=w0*inv; sm[2][h]=w1*inv; sm[3][h]=w2*inv;
  sm[4][h]=t0*inv; sm[5][h]=t1*inv; sm[6][h]=t2*inv;
  sm[7][h]=t3*inv; sm[8][h]=t4*inv; sm[9][h]=t5*inv;
  __syncthreads();
  float at=0, vt0=0,vt1=0,vt2=0, st0=0,st1=0,st2=0,st3=0,st4=0,st5=0;
  for (int r=0;r<128;++r){
    float ww0 = ldf(lt,(size_t)r*128+h);        at += sm[0][r]*ww0;
    float ww1 = ldf(lt,(size_t)16384+r*128+h);  vt0 += sm[1][r]*ww1; vt1 += sm[2][r]*ww1; vt2 += sm[3][r]*ww1;
    float ww2 = ldf(lt,(size_t)32768+r*128+h);  st0 += sm[4][r]*ww2; st1 += sm[5][r]*ww2; st2 += sm[6][r]*ww2;
                                                st3 += sm[7][r]*ww2; st4 += sm[8][r]*ww2; st5 += sm[9][r]*ww2;
  }
  float d00=at+st0,   d01=-vt2+st1, d02= vt1+st2;
  float d10= vt2+st1, d11=at+st3,  d12=-vt0+st4;
  float d20=-vt1+st2, d21= vt0+st4, d22=at+st5;
  float g00 = d00 + d00*d00+d01*d10+d02*d20;
  float g01 = d01 + d00*d01+d01*d11+d02*d21;
  float g02 = d02 + d00*d02+d01*d12+d02*d22;
  float g10 = d10 + d10*d00+d11*d10+d12*d20;
  float g11 = d11 + d10*d01+d11*d11+d12*d21;
  float g12 = d12 + d10*d02+d11*d12+d12*d22;
  float g20 = d20 + d20*d00+d21*d10+d22*d20;
  float g21 = d21 + d20*d01+d21*d11+d22*d21;
  float g22 = d22 + d20*d02+d21*d12+d22*d22;
  float* xp = X9 + (size_t)n*1152;
  // X here is the NORMALIZED X (written back by k_msg_prep)
  float x00=xp[0*128+h]+g00, x01=xp[1*128+h]+g01, x02=xp[2*128+h]+g02;
  float x10=xp[3*128+h]+g10, x11=xp[4*128+h]+g11, x12=xp[5*128+h]+g12;
  float x20=xp[6*128+h]+g20, x21=xp[7*128+h]+g21, x22=xp[8*128+h]+g22;
  if (write_out){
    T* o = (T*)out + ((size_t)n*128 + h)*9;
    if (sizeof(T)==4){
      float* of = (float*)o;
      of[0]=x00; of[1]=x01; of[2]=x02; of[3]=x10; of[4]=x11; of[5]=x12; of[6]=x20; of[7]=x21; of[8]=x22;
    } else {
      bf16* ob = (bf16*)o;
      ob[0]=__float2bfloat16(x00); ob[1]=__float2bfloat16(x01); ob[2]=__float2bfloat16(x02);
      ob[3]=__float2bfloat16(x10); ob[4]=__float2bfloat16(x11); ob[5]=__float2bfloat16(x12);
      ob[6]=__float2bfloat16(x20); ob[7]=__float2bfloat16(x21); ob[8]=__float2bfloat16(x22);
    }
  } else {
    xp[0*128+h]=x00; xp[1*128+h]=x01; xp[2*128+h]=x02;
    xp[3*128+h]=x10; xp[4*128+h]=x11; xp[5*128+h]=x12;
    xp[6*128+h]=x20; xp[7*128+h]=x21; xp[8*128+h]=x22;
  }
}

extern "C" void kernel_launch(void* const* d_in, const int* in_sizes, int n_in,
                              void* d_out, int out_size, void* d_ws, size_t ws_size,
                              hipStream_t stream)
{
  (void)in_sizes; (void)n_in; (void)out_size; (void)ws_size;
  const int* z    = (const int*)d_in[0];
  const int* eidx = (const int*)d_in[1];
  const int* src  = eidx;
  const int* dst  = eidx + NE;

  // Workspace layout: ~52.8 MiB total.
  char* w = (char*)d_ws;
  int* flag    = (int*)w;   w += 64;
  int* counts  = (int*)w;   w += (size_t)NN*4;
  int* offsets = (int*)w;   w += (size_t)(NN+1)*4 + 60;
  int* cursor  = (int*)w;   w += (size_t)NN*4;
  int* csr     = (int*)w;   w += (size_t)NE*4;
  float* gC    = (float*)w; w += (size_t)NE*4;
  float* gV    = (float*)w; w += (size_t)NE*12;
  float* P1z   = (float*)w; w += (size_t)MAXZ*HH*4;
  float* P2z   = (float*)w; w += (size_t)MAXZ*HH*4;
  bf16* eabuf  = (bf16*)w;  w += (size_t)NE*384*2;   // 25.17 MB
  float* X9    = (float*)w; w += (size_t)NN*1152*4;  // 18.87 MB
  bf16* Y10    = (bf16*)w;  w += (size_t)NN*1280*2;  // 10.49 MB

  k_detect<<<1, 256, 0, stream>>>((const unsigned int*)d_in[4], flag);

  hipMemsetAsync(counts, 0, (size_t)NN*4, stream);
  k_count<<<NE/256, 256, 0, stream>>>(dst, counts);
  k_scan<<<1, 1024, 0, stream>>>(counts, offsets, cursor);
  k_fill<<<NE/256, 256, 0, stream>>>(dst, cursor, csr);

  #define DUAL(call_f32, call_bf16) do { call_f32; call_bf16; } while(0)

  DUAL(
    (k_geom<float><<<NE/256, 256, 0, stream>>>((const float*)d_in[2], (const float*)d_in[3], src, dst, gC, gV, flag)),
    (k_geom<bf16 ><<<NE/256, 256, 0, stream>>>((const bf16* )d_in[2], (const bf16* )d_in[3], src, dst, gC, gV, flag)));

  DUAL(
    (k_zemb<float><<<MAXZ, 128, 0, stream>>>((const float*)d_in[5], (const float*)d_in[12], P1z, P2z, flag)),
    (k_zemb<bf16 ><<<MAXZ, 128, 0, stream>>>((const bf16* )d_in[5], (const bf16* )d_in[12], P1z, P2z, flag)));

  DUAL(
    (k_tne_edge<float><<<NE/TPB, 128, 0, stream>>>((const float*)d_in[4], src, dst, z,
        (const float*)d_in[6], (const float*)d_in[7], (const float*)d_in[8], (const float*)d_in[9],
        (const float*)d_in[10], (const float*)d_in[11], (const float*)d_in[13], P1z, P2z, gC, eabuf, flag)),
    (k_tne_edge<bf16 ><<<NE/TPB, 128, 0, stream>>>((const bf16* )d_in[4], src, dst, z,
        (const bf16* )d_in[6], (const bf16* )d_in[7], (const bf16* )d_in[8], (const bf16* )d_in[9],
        (const bf16* )d_in[10], (const bf16* )d_in[11], (const bf16* )d_in[13], P1z, P2z, gC, eabuf, flag)));

  DUAL(
    (k_tne_node<float><<<NN, 128, 0, stream>>>(offsets, csr, gV, eabuf,
        (const float*)d_in[19], (const float*)d_in[20], (const float*)d_in[14],
        (const float*)d_in[15], (const float*)d_in[16], (const float*)d_in[17], (const float*)d_in[18], X9, flag)),
    (k_tne_node<bf16 ><<<NN, 128, 0, stream>>>(offsets, csr, gV, eabuf,
        (const bf16* )d_in[19], (const bf16* )d_in[20], (const bf16* )d_in[14],
        (const bf16* )d_in[15], (const bf16* )d_in[16], (const bf16* )d_in[17], (const bf16* )d_in[18], X9, flag)));

  for (int l=0; l<2; ++l){
    size_t o0w = (size_t)l*32*128,  o0b = (size_t)l*128;
    size_t o1w = (size_t)l*128*256, o1b = (size_t)l*256;
    size_t o2w = (size_t)l*256*384, o2b = (size_t)l*384;
    size_t oxt = (size_t)l*3*128*128;
    DUAL(
      (k_msg_edge<float><<<NE/EPB, 128, 0, stream>>>((const float*)d_in[4], gC,
          (const float*)d_in[21]+o0w, (const float*)d_in[22]+o0b,
          (const float*)d_in[23]+o1w, (const float*)d_in[24]+o1b,
          (const float*)d_in[25]+o2w, (const float*)d_in[26]+o2b, eabuf, flag)),
      (k_msg_edge<bf16 ><<<NE/EPB, 128, 0, stream>>>((const bf16* )d_in[4], gC,
          (const bf16* )d_in[21]+o0w, (const bf16* )d_in[22]+o0b,
          (const bf16* )d_in[23]+o1w, (const bf16* )d_in[24]+o1b,
          (const bf16* )d_in[25]+o2w, (const bf16* )d_in[26]+o2b, eabuf, flag)));
    DUAL(
      (k_msg_prep<float><<<NN/4, 128, 0, stream>>>(X9, (const float*)d_in[27]+oxt, Y10, flag)),
      (k_msg_prep<bf16 ><<<NN/4, 128, 0, stream>>>(X9, (const bf16* )d_in[27]+oxt, Y10, flag)));
    DUAL(
      (k_msg_sf<float><<<NN, 128, 0, stream>>>(offsets, csr, src, eabuf, Y10,
          (const float*)d_in[28]+oxt, X9, d_out, flag, (l==1)?1:0)),
      (k_msg_sf<bf16 ><<<NN, 128, 0, stream>>>(offsets, csr, src, eabuf, Y10,
          (const bf16* )d_in[28]+oxt, X9, d_out, flag, (l==1)?1:0)));
  }
  #undef DUAL
}

// Round 9
// 717.091 us; speedup vs baseline: 1.0018x; 1.0018x over previous
//
#include <hip/hip_runtime.h>
#include <hip/hip_bf16.h>

typedef __hip_bfloat16 bf16;

#define NN 4096
#define NE 32768
#define HH 128
#define MAXZ 100
#define TPB 8    // edges per block, TNE edge kernel
#define EPB 16   // edges per block, msg edge MLP kernel

__device__ __forceinline__ float b2f(bf16 v){ return __bfloat162float(v); }
__device__ __forceinline__ float ldf(const float* p, size_t i){ return p[i]; }
__device__ __forceinline__ float ldf(const bf16*  p, size_t i){ return __bfloat162float(p[i]); }
__device__ __forceinline__ float siluf(float x){ return x / (1.0f + __expf(-x)); }

// dtype detect: flag[0]=1 if float inputs are f32, 0 if bf16. Reads edge_attr words.
__global__ void __launch_bounds__(256) k_detect(const unsigned int* __restrict__ w, int* __restrict__ flag){
  __shared__ int cnt[256];
  int t = threadIdx.x;
  int c = 0;
  for (int i = t; i < 4096; i += 256){
    unsigned int lo = w[i] & 0xffffu;
    int e = (int)((lo >> 7) & 0xffu);
    c += (e >= 110 && e <= 132) ? 1 : 0;
  }
  cnt[t] = c; __syncthreads();
  for (int off=128; off>=1; off>>=1){ if (t<off) cnt[t]+=cnt[t+off]; __syncthreads(); }
  if (t==0) flag[0] = (cnt[0] < 2048) ? 1 : 0;
}

// ---------------- CSR build ----------------
__global__ void __launch_bounds__(256) k_count(const int* __restrict__ dst, int* __restrict__ counts){
  int e = blockIdx.x*256 + threadIdx.x;
  if (e < NE) atomicAdd(&counts[dst[e]], 1);
}

__global__ void __launch_bounds__(1024) k_scan(const int* __restrict__ counts, int* __restrict__ offsets, int* __restrict__ cursor){
  __shared__ int lds[1024];
  int t = threadIdx.x;
  int c0 = counts[4*t+0], c1 = counts[4*t+1], c2 = counts[4*t+2], c3 = counts[4*t+3];
  int s1 = c0+c1, s2 = s1+c2, s3 = s2+c3;
  lds[t] = s3;
  __syncthreads();
  for (int off=1; off<1024; off<<=1){
    int v = lds[t];
    int add = (t>=off)? lds[t-off] : 0;
    __syncthreads();
    lds[t] = v + add;
    __syncthreads();
  }
  int incl = lds[t];
  int base = incl - s3;
  offsets[4*t+0]=base;    offsets[4*t+1]=base+c0; offsets[4*t+2]=base+s1; offsets[4*t+3]=base+s2;
  cursor [4*t+0]=base;    cursor [4*t+1]=base+c0; cursor [4*t+2]=base+s1; cursor [4*t+3]=base+s2;
  if (t==1023) offsets[4096]=incl;
}

__global__ void __launch_bounds__(256) k_fill(const int* __restrict__ dst, int* __restrict__ cursor, int* __restrict__ csr){
  int e = blockIdx.x*256 + threadIdx.x;
  if (e < NE){ int p = atomicAdd(&cursor[dst[e]], 1); csr[p] = e; }
}

// ---------------- edge geometry: C, ev ----------------
template<typename T>
__global__ void __launch_bounds__(256) k_geom(const T* __restrict__ ew, const T* __restrict__ evec,
                       const int* __restrict__ src, const int* __restrict__ dst,
                       float* __restrict__ gC, float* __restrict__ gV, const int* __restrict__ flag){
  if (flag[0] != (int)(sizeof(T)==4)) return;
  int e = blockIdx.x*256 + threadIdx.x;
  if (e >= NE) return;
  float d = ldf(ew, e);
  float c = 0.5f*(cosf(d*0.6283185307179586f)+1.0f);
  c = (d < 5.0f) ? c : 0.0f;
  gC[e] = c;
  float x = ldf(evec, (size_t)e*3+0), y = ldf(evec, (size_t)e*3+1), z = ldf(evec, (size_t)e*3+2);
  if (src[e] != dst[e]){
    float n = sqrtf(x*x+y*y+z*z);
    float inv = 1.0f/fmaxf(n, 1e-12f);
    x*=inv; y*=inv; z*=inv;
  }
  gV[e*3+0]=x; gV[e*3+1]=y; gV[e*3+2]=z;
}

// ---------------- per-z embedding products ----------------
template<typename T>
__global__ void __launch_bounds__(128) k_zemb(const T* __restrict__ emb, const T* __restrict__ emb2_w,
                      float* __restrict__ P1z, float* __restrict__ P2z, const int* __restrict__ flag){
  if (flag[0] != (int)(sizeof(T)==4)) return;
  int zv = blockIdx.x, h = threadIdx.x;
  __shared__ float Zr[128];
  Zr[h] = ldf(emb, (size_t)zv*HH + h);
  __syncthreads();
  float p1=0.f, p2=0.f;
  for (int r=0;r<128;++r){
    float x = Zr[r];
    p1 += x*ldf(emb2_w, (size_t)r*HH+h);
    p2 += x*ldf(emb2_w, (size_t)(r+128)*HH+h);
  }
  P1z[zv*HH+h]=p1; P2z[zv*HH+h]=p2;
}

// ---------------- TNE edge coefficients -> eabuf bf16 [E][3][128] ----------------
template<typename T>
__global__ void __launch_bounds__(128) k_tne_edge(
  const T* __restrict__ eattr, const int* __restrict__ src, const int* __restrict__ dst,
  const int* __restrict__ z,
  const T* __restrict__ dp1_w, const T* __restrict__ dp1_b,
  const T* __restrict__ dp2_w, const T* __restrict__ dp2_b,
  const T* __restrict__ dp3_w, const T* __restrict__ dp3_b,
  const T* __restrict__ emb2_b, const float* __restrict__ P1z, const float* __restrict__ P2z,
  const float* __restrict__ gC, bf16* __restrict__ eabuf, const int* __restrict__ flag)
{
  if (flag[0] != (int)(sizeof(T)==4)) return;
  int e0 = blockIdx.x*TPB;
  int h  = threadIdx.x;
  __shared__ float attr[TPB][32];
  __shared__ int zd[TPB], zs[TPB];
  for (int i=h; i<TPB*32; i+=128) attr[i>>5][i&31] = ldf(eattr, (size_t)e0*32 + i);
  if (h < TPB){ int e=e0+h; zd[h]=z[dst[e]]; zs[h]=z[src[e]]; }
  __syncthreads();
  float w1[TPB], w2[TPB], w3[TPB];
  float b1v=ldf(dp1_b,h), b2v=ldf(dp2_b,h), b3v=ldf(dp3_b,h);
  #pragma unroll
  for (int e=0;e<TPB;++e){ w1[e]=b1v; w2[e]=b2v; w3[e]=b3v; }
  for (int r=0;r<32;++r){
    float u1=ldf(dp1_w,(size_t)r*HH+h), u2=ldf(dp2_w,(size_t)r*HH+h), u3=ldf(dp3_w,(size_t)r*HH+h);
    #pragma unroll
    for (int e=0;e<TPB;++e){ float a=attr[e][r]; w1[e]+=a*u1; w2[e]+=a*u2; w3[e]+=a*u3; }
  }
  float eb = ldf(emb2_b,h);
  #pragma unroll
  for (int e=0;e<TPB;++e){
    float zij = P1z[zd[e]*HH+h] + P2z[zs[e]*HH+h] + eb;
    float c = gC[e0+e];
    bf16* p = eabuf + (size_t)(e0+e)*384;
    p[h]     = __float2bfloat16(zij*w1[e]*c);
    p[128+h] = __float2bfloat16(zij*w2[e]*c);
    p[256+h] = __float2bfloat16(zij*w3[e]*c);
  }
}

// ---------------- TNE node (fused scatter + LN + fsc MLP + cmix) -> X9 ----------------
template<typename T>
__global__ void __launch_bounds__(128) k_tne_node(
  const int* __restrict__ offsets, const int* __restrict__ csr,
  const float* __restrict__ gV, const bf16* __restrict__ eabuf,
  const T* __restrict__ ln_g, const T* __restrict__ ln_b,
  const T* __restrict__ tne_lt,
  const T* __restrict__ s0_w, const T* __restrict__ s0_b,
  const T* __restrict__ s1_w, const T* __restrict__ s1_b,
  float* __restrict__ X9, const int* __restrict__ flag)
{
  if (flag[0] != (int)(sizeof(T)==4)) return;
  int n = blockIdx.x, h = threadIdx.x;
  float a=0, v0=0,v1=0,v2=0, s0=0,s1=0,s2=0,s3=0,s4=0,s5=0;
  int beg = offsets[n], end = offsets[n+1];
  for (int i=beg;i<end;++i){
    int e = csr[i];
    const bf16* p = eabuf + (size_t)e*384;
    float c1 = b2f(p[h]), c2 = b2f(p[128+h]), c3 = b2f(p[256+h]);
    float vx = gV[e*3+0], vy = gV[e*3+1], vz = gV[e*3+2];
    float tr3 = (vx*vx+vy*vy+vz*vz)*(1.0f/3.0f);
    a  += c1;
    v0 += c2*vx; v1 += c2*vy; v2 += c2*vz;
    s0 += c3*(vx*vx - tr3); s1 += c3*vx*vy;          s2 += c3*vx*vz;
    s3 += c3*(vy*vy - tr3); s4 += c3*vy*vz;          s5 += c3*(vz*vz - tr3);
  }
  float tn = 3.0f*a*a + 2.0f*(v0*v0+v1*v1+v2*v2)
           + s0*s0 + s3*s3 + s5*s5 + 2.0f*(s1*s1 + s2*s2 + s4*s4);
  __shared__ float red[128];
  red[h] = tn; __syncthreads();
  for (int off=64; off>=1; off>>=1){ if (h<off) red[h]+=red[h+off]; __syncthreads(); }
  float mean = red[0]*(1.0f/128.0f);
  __syncthreads();
  float dm = tn - mean;
  red[h] = dm*dm; __syncthreads();
  for (int off=64; off>=1; off>>=1){ if (h<off) red[h]+=red[h+off]; __syncthreads(); }
  float var = red[0]*(1.0f/128.0f);
  float ln = dm*rsqrtf(var+1e-5f)*ldf(ln_g,h) + ldf(ln_b,h);
  __shared__ float lnv[128];
  __shared__ float h1[256];
  lnv[h] = ln; __syncthreads();
  float a0 = ldf(s0_b,2*h), a1 = ldf(s0_b,2*h+1);
  for (int r=0;r<128;++r){ float x = lnv[r]; a0 += x*ldf(s0_w,(size_t)r*256+2*h); a1 += x*ldf(s0_w,(size_t)r*256+2*h+1); }
  h1[2*h] = siluf(a0); h1[2*h+1] = siluf(a1);
  __syncthreads();
  float f0 = ldf(s1_b,3*h), f1 = ldf(s1_b,3*h+1), f2 = ldf(s1_b,3*h+2);
  for (int r=0;r<256;++r){ float x = h1[r]; f0 += x*ldf(s1_w,(size_t)r*384+3*h); f1 += x*ldf(s1_w,(size_t)r*384+3*h+1); f2 += x*ldf(s1_w,(size_t)r*384+3*h+2); }
  f0 = siluf(f0); f1 = siluf(f1); f2 = siluf(f2);
  __shared__ float sm[10][128];
  sm[0][h]=a; sm[1][h]=v0; sm[2][h]=v1; sm[3][h]=v2;
  sm[4][h]=s0; sm[5][h]=s1; sm[6][h]=s2; sm[7][h]=s3; sm[8][h]=s4; sm[9][h]=s5;
  __syncthreads();
  float am=0, wm0=0,wm1=0,wm2=0, t0=0,t1=0,t2=0,t3=0,t4=0,t5=0;
  for (int r=0;r<128;++r){
    float w0 = ldf(tne_lt,(size_t)r*128+h);        am += sm[0][r]*w0;
    float w1 = ldf(tne_lt,(size_t)16384+r*128+h);  wm0 += sm[1][r]*w1; wm1 += sm[2][r]*w1; wm2 += sm[3][r]*w1;
    float w2 = ldf(tne_lt,(size_t)32768+r*128+h);  t0 += sm[4][r]*w2; t1 += sm[5][r]*w2; t2 += sm[6][r]*w2;
                                                   t3 += sm[7][r]*w2; t4 += sm[8][r]*w2; t5 += sm[9][r]*w2;
  }
  float x00 = f0*am + f2*t0;
  float x01 = -f1*wm2 + f2*t1;
  float x02 =  f1*wm1 + f2*t2;
  float x10 =  f1*wm2 + f2*t1;
  float x11 = f0*am + f2*t3;
  float x12 = -f1*wm0 + f2*t4;
  float x20 = -f1*wm1 + f2*t2;
  float x21 =  f1*wm0 + f2*t4;
  float x22 = f0*am + f2*t5;
  float* xp = X9 + (size_t)n*1152;
  xp[0*128+h]=x00; xp[1*128+h]=x01; xp[2*128+h]=x02;
  xp[3*128+h]=x10; xp[4*128+h]=x11; xp[5*128+h]=x12;
  xp[6*128+h]=x20; xp[7*128+h]=x21; xp[8*128+h]=x22;
}

// ---------------- msg edge MLP (EPB edges/block) -> eabuf bf16 [E][3][128] ----------------
template<typename T>
__global__ void __launch_bounds__(128) k_msg_edge(
  const T* __restrict__ eattr, const float* __restrict__ gC,
  const T* __restrict__ l0_w, const T* __restrict__ l0_b,
  const T* __restrict__ l1_w, const T* __restrict__ l1_b,
  const T* __restrict__ l2_w, const T* __restrict__ l2_b,
  bf16* __restrict__ eabuf, const int* __restrict__ flag)
{
  if (flag[0] != (int)(sizeof(T)==4)) return;
  int e0 = blockIdx.x*EPB;
  int h = threadIdx.x;
  __shared__ float attr[EPB][32];
  __shared__ float h1[EPB][128];
  __shared__ float h2[EPB][256];
  for (int i=h; i<EPB*32; i+=128) attr[i>>5][i&31] = ldf(eattr, (size_t)e0*32 + i);
  __syncthreads();
  {
    float b = ldf(l0_b,h);
    float a0[EPB];
    #pragma unroll
    for (int e=0;e<EPB;++e) a0[e]=b;
    for (int r=0;r<32;++r){
      float u = ldf(l0_w,(size_t)r*128+h);
      #pragma unroll
      for (int e=0;e<EPB;++e) a0[e] += attr[e][r]*u;
    }
    #pragma unroll
    for (int e=0;e<EPB;++e) h1[e][h] = siluf(a0[e]);
  }
  __syncthreads();
  {
    float ba = ldf(l1_b,2*h), bb = ldf(l1_b,2*h+1);
    float b0[EPB], b1a[EPB];
    #pragma unroll
    for (int e=0;e<EPB;++e){ b0[e]=ba; b1a[e]=bb; }
    for (int r=0;r<128;++r){
      float ua = ldf(l1_w,(size_t)r*256+2*h), ub = ldf(l1_w,(size_t)r*256+2*h+1);
      #pragma unroll
      for (int e=0;e<EPB;++e){ float x = h1[e][r]; b0[e]+=x*ua; b1a[e]+=x*ub; }
    }
    #pragma unroll
    for (int e=0;e<EPB;++e){ h2[e][2*h] = siluf(b0[e]); h2[e][2*h+1] = siluf(b1a[e]); }
  }
  __syncthreads();
  {
    float ba = ldf(l2_b,3*h), bb = ldf(l2_b,3*h+1), bc = ldf(l2_b,3*h+2);
    float c0[EPB], c1[EPB], c2[EPB];
    #pragma unroll
    for (int e=0;e<EPB;++e){ c0[e]=ba; c1[e]=bb; c2[e]=bc; }
    for (int r=0;r<256;++r){
      float u0 = ldf(l2_w,(size_t)r*384+3*h), u1 = ldf(l2_w,(size_t)r*384+3*h+1), u2 = ldf(l2_w,(size_t)r*384+3*h+2);
      #pragma unroll
      for (int e=0;e<EPB;++e){ float x = h2[e][r]; c0[e]+=x*u0; c1[e]+=x*u1; c2[e]+=x*u2; }
    }
    #pragma unroll
    for (int e=0;e<EPB;++e){
      float C = gC[e0+e];
      bf16* p = eabuf + (size_t)(e0+e)*384;
      p[h]     = __float2bfloat16(siluf(c0[e])*C);
      p[128+h] = __float2bfloat16(siluf(c1[e])*C);
      p[256+h] = __float2bfloat16(siluf(c2[e])*C);
    }
  }
}

// ---------------- msg node prep (4 nodes/block): normalize X (WRITE BACK), decompose, cmix lx -> Y10 bf16 ----------------
template<typename T>
__global__ void __launch_bounds__(128) k_msg_prep(
  float* __restrict__ X9, const T* __restrict__ lx, bf16* __restrict__ Y10,
  const int* __restrict__ flag)
{
  if (flag[0] != (int)(sizeof(T)==4)) return;
  int n0 = blockIdx.x*4, h = threadIdx.x;
  __shared__ float sm[4][10][128];
  #pragma unroll
  for (int nn=0;nn<4;++nn){
    float* xp = X9 + (size_t)(n0+nn)*1152;
    float x00=xp[0*128+h], x01=xp[1*128+h], x02=xp[2*128+h];
    float x10=xp[3*128+h], x11=xp[4*128+h], x12=xp[5*128+h];
    float x20=xp[6*128+h], x21=xp[7*128+h], x22=xp[8*128+h];
    float tn = x00*x00+x01*x01+x02*x02+x10*x10+x11*x11+x12*x12+x20*x20+x21*x21+x22*x22;
    float inv = 1.0f/(tn+1.0f);
    x00*=inv; x01*=inv; x02*=inv; x10*=inv; x11*=inv; x12*=inv; x20*=inv; x21*=inv; x22*=inv;
    // Reference REBINDS X to the normalized value before the layer update:
    // X = X/(tnorm+1); ... X = X + dX.  Write the normalized X back. (r3 bug fix)
    xp[0*128+h]=x00; xp[1*128+h]=x01; xp[2*128+h]=x02;
    xp[3*128+h]=x10; xp[4*128+h]=x11; xp[5*128+h]=x12;
    xp[6*128+h]=x20; xp[7*128+h]=x21; xp[8*128+h]=x22;
    float a = (x00+x11+x22)*(1.0f/3.0f);
    sm[nn][0][h]=a;
    sm[nn][1][h]=0.5f*(x21-x12);
    sm[nn][2][h]=0.5f*(x02-x20);
    sm[nn][3][h]=0.5f*(x10-x01);
    sm[nn][4][h]=x00-a;
    sm[nn][5][h]=0.5f*(x01+x10);
    sm[nn][6][h]=0.5f*(x02+x20);
    sm[nn][7][h]=x11-a;
    sm[nn][8][h]=0.5f*(x12+x21);
    sm[nn][9][h]=x22-a;
  }
  __syncthreads();
  float A[4]={0,0,0,0};
  float V0[4]={0,0,0,0}, V1[4]={0,0,0,0}, V2[4]={0,0,0,0};
  float S0[4]={0,0,0,0}, S1[4]={0,0,0,0}, S2[4]={0,0,0,0};
  float S3[4]={0,0,0,0}, S4[4]={0,0,0,0}, S5[4]={0,0,0,0};
  for (int r=0;r<128;++r){
    float w0 = ldf(lx,(size_t)r*128+h), w1 = ldf(lx,(size_t)16384+r*128+h), w2 = ldf(lx,(size_t)32768+r*128+h);
    #pragma unroll
    for (int nn=0;nn<4;++nn){
      A[nn]  += sm[nn][0][r]*w0;
      V0[nn] += sm[nn][1][r]*w1; V1[nn] += sm[nn][2][r]*w1; V2[nn] += sm[nn][3][r]*w1;
      S0[nn] += sm[nn][4][r]*w2; S1[nn] += sm[nn][5][r]*w2; S2[nn] += sm[nn][6][r]*w2;
      S3[nn] += sm[nn][7][r]*w2; S4[nn] += sm[nn][8][r]*w2; S5[nn] += sm[nn][9][r]*w2;
    }
  }
  #pragma unroll
  for (int nn=0;nn<4;++nn){
    bf16* yp = Y10 + (size_t)(n0+nn)*1280;
    yp[0*128+h]=__float2bfloat16(A[nn]);
    yp[1*128+h]=__float2bfloat16(V0[nn]); yp[2*128+h]=__float2bfloat16(V1[nn]); yp[3*128+h]=__float2bfloat16(V2[nn]);
    yp[4*128+h]=__float2bfloat16(S0[nn]); yp[5*128+h]=__float2bfloat16(S1[nn]); yp[6*128+h]=__float2bfloat16(S2[nn]);
    yp[7*128+h]=__float2bfloat16(S3[nn]); yp[8*128+h]=__float2bfloat16(S4[nn]); yp[9*128+h]=__float2bfloat16(S5[nn]);
  }
}

// ---------------- msg scatter + AB + decompose + cmix lt + dX update (fused) ----------------
template<typename T>
__global__ void __launch_bounds__(128) k_msg_sf(
  const int* __restrict__ offsets, const int* __restrict__ csr, const int* __restrict__ srcA,
  const bf16* __restrict__ eabuf, const bf16* __restrict__ Y10, const T* __restrict__ lt,
  float* __restrict__ X9, void* __restrict__ out, const int* __restrict__ flag, int write_out)
{
  if (flag[0] != (int)(sizeof(T)==4)) return;
  int n = blockIdx.x, h = threadIdx.x;
  float am=0, vm0=0,vm1=0,vm2=0, smm0=0,smm1=0,smm2=0,smm3=0,smm4=0,smm5=0;
  int beg = offsets[n], end = offsets[n+1];
  for (int i=beg;i<end;++i){
    int e = csr[i]; int s = srcA[e];
    const bf16* ep = eabuf + (size_t)e*384;
    float e0 = b2f(ep[h]), e1 = b2f(ep[128+h]), e2 = b2f(ep[256+h]);
    const bf16* yp = Y10 + (size_t)s*1280;
    am   += e0*b2f(yp[0*128+h]);
    vm0  += e1*b2f(yp[1*128+h]); vm1 += e1*b2f(yp[2*128+h]); vm2 += e1*b2f(yp[3*128+h]);
    smm0 += e2*b2f(yp[4*128+h]); smm1 += e2*b2f(yp[5*128+h]); smm2 += e2*b2f(yp[6*128+h]);
    smm3 += e2*b2f(yp[7*128+h]); smm4 += e2*b2f(yp[8*128+h]); smm5 += e2*b2f(yp[9*128+h]);
  }
  const bf16* yp = Y10 + (size_t)n*1280;
  float aY=b2f(yp[0*128+h]), u0=b2f(yp[1*128+h]), u1=b2f(yp[2*128+h]), u2=b2f(yp[3*128+h]);
  float q0=b2f(yp[4*128+h]), q1=b2f(yp[5*128+h]), q2=b2f(yp[6*128+h]);
  float q3=b2f(yp[7*128+h]), q4=b2f(yp[8*128+h]), q5=b2f(yp[9*128+h]);
  float m00=am+smm0,   m01=-vm2+smm1, m02= vm1+smm2;
  float m10= vm2+smm1, m11=am+smm3,  m12=-vm0+smm4;
  float m20=-vm1+smm2, m21= vm0+smm4, m22=am+smm5;
  float y00=aY+q0,  y01=-u2+q1, y02= u1+q2;
  float y10= u2+q1, y11=aY+q3,  y12=-u0+q4;
  float y20=-u1+q2, y21= u0+q4, y22=aY+q5;
  float ab00 = m00*y00+m01*y10+m02*y20 + y00*m00+y01*m10+y02*m20;
  float ab01 = m00*y01+m01*y11+m02*y21 + y00*m01+y01*m11+y02*m21;
  float ab02 = m00*y02+m01*y12+m02*y22 + y00*m02+y01*m12+y02*m22;
  float ab10 = m10*y00+m11*y10+m12*y20 + y10*m00+y11*m10+y12*m20;
  float ab11 = m10*y01+m11*y11+m12*y21 + y10*m01+y11*m11+y12*m21;
  float ab12 = m10*y02+m11*y12+m12*y22 + y10*m02+y11*m12+y12*m22;
  float ab20 = m20*y00+m21*y10+m22*y20 + y20*m00+y21*m10+y22*m20;
  float ab21 = m20*y01+m21*y11+m22*y21 + y20*m01+y21*m11+y22*m21;
  float ab22 = m20*y02+m21*y12+m22*y22 + y20*m02+y21*m12+y22*m22;
  float a2 = (ab00+ab11+ab22)*(1.0f/3.0f);
  float w0 = 0.5f*(ab21-ab12), w1 = 0.5f*(ab02-ab20), w2 = 0.5f*(ab10-ab01);
  float t0 = ab00-a2, t1 = 0.5f*(ab01+ab10), t2 = 0.5f*(ab02+ab20);
  float t3 = ab11-a2, t4 = 0.5f*(ab12+ab21), t5 = ab22-a2;
  float dnm = ab00*ab00+ab01*ab01+ab02*ab02+ab10*ab10+ab11*ab11+ab12*ab12
            + ab20*ab20+ab21*ab21+ab22*ab22 + 1.0f;
  float inv = 1.0f/dnm;
  __shared__ float sm[10][128];
  sm[0][h]=a2*inv; sm[1][h]=w0*inv; sm[2][h]=w1*inv; sm[3][h]=w2*inv;
  sm[4][h]=t0*inv; sm[5][h]=t1*inv; sm[6][h]=t2*inv;
  sm[7][h]=t3*inv; sm[8][h]=t4*inv; sm[9][h]=t5*inv;
  __syncthreads();
  float at=0, vt0=0,vt1=0,vt2=0, st0=0,st1=0,st2=0,st3=0,st4=0,st5=0;
  for (int r=0;r<128;++r){
    float ww0 = ldf(lt,(size_t)r*128+h);        at += sm[0][r]*ww0;
    float ww1 = ldf(lt,(size_t)16384+r*128+h);  vt0 += sm[1][r]*ww1; vt1 += sm[2][r]*ww1; vt2 += sm[3][r]*ww1;
    float ww2 = ldf(lt,(size_t)32768+r*128+h);  st0 += sm[4][r]*ww2; st1 += sm[5][r]*ww2; st2 += sm[6][r]*ww2;
                                                st3 += sm[7][r]*ww2; st4 += sm[8][r]*ww2; st5 += sm[9][r]*ww2;
  }
  float d00=at+st0,   d01=-vt2+st1, d02= vt1+st2;
  float d10= vt2+st1, d11=at+st3,  d12=-vt0+st4;
  float d20=-vt1+st2, d21= vt0+st4, d22=at+st5;
  float g00 = d00 + d00*d00+d01*d10+d02*d20;
  float g01 = d01 + d00*d01+d01*d11+d02*d21;
  float g02 = d02 + d00*d02+d01*d12+d02*d22;
  float g10 = d10 + d10*d00+d11*d10+d12*d20;
  float g11 = d11 + d10*d01+d11*d11+d12*d21;
  float g12 = d12 + d10*d02+d11*d12+d12*d22;
  float g20 = d20 + d20*d00+d21*d10+d22*d20;
  float g21 = d21 + d20*d01+d21*d11+d22*d21;
  float g22 = d22 + d20*d02+d21*d12+d22*d22;
  float* xp = X9 + (size_t)n*1152;
  // X here is the NORMALIZED X (written back by k_msg_prep)
  float x00=xp[0*128+h]+g00, x01=xp[1*128+h]+g01, x02=xp[2*128+h]+g02;
  float x10=xp[3*128+h]+g10, x11=xp[4*128+h]+g11, x12=xp[5*128+h]+g12;
  float x20=xp[6*128+h]+g20, x21=xp[7*128+h]+g21, x22=xp[8*128+h]+g22;
  if (write_out){
    T* o = (T*)out + ((size_t)n*128 + h)*9;
    if (sizeof(T)==4){
      float* of = (float*)o;
      of[0]=x00; of[1]=x01; of[2]=x02; of[3]=x10; of[4]=x11; of[5]=x12; of[6]=x20; of[7]=x21; of[8]=x22;
    } else {
      bf16* ob = (bf16*)o;
      ob[0]=__float2bfloat16(x00); ob[1]=__float2bfloat16(x01); ob[2]=__float2bfloat16(x02);
      ob[3]=__float2bfloat16(x10); ob[4]=__float2bfloat16(x11); ob[5]=__float2bfloat16(x12);
      ob[6]=__float2bfloat16(x20); ob[7]=__float2bfloat16(x21); ob[8]=__float2bfloat16(x22);
    }
  } else {
    xp[0*128+h]=x00; xp[1*128+h]=x01; xp[2*128+h]=x02;
    xp[3*128+h]=x10; xp[4*128+h]=x11; xp[5*128+h]=x12;
    xp[6*128+h]=x20; xp[7*128+h]=x21; xp[8*128+h]=x22;
  }
}

extern "C" void kernel_launch(void* const* d_in, const int* in_sizes, int n_in,
                              void* d_out, int out_size, void* d_ws, size_t ws_size,
                              hipStream_t stream)
{
  (void)in_sizes; (void)n_in; (void)out_size; (void)ws_size;
  const int* z    = (const int*)d_in[0];
  const int* eidx = (const int*)d_in[1];
  const int* src  = eidx;
  const int* dst  = eidx + NE;

  // Workspace layout: ~52.8 MiB total.
  char* w = (char*)d_ws;
  int* flag    = (int*)w;   w += 64;
  int* counts  = (int*)w;   w += (size_t)NN*4;
  int* offsets = (int*)w;   w += (size_t)(NN+1)*4 + 60;
  int* cursor  = (int*)w;   w += (size_t)NN*4;
  int* csr     = (int*)w;   w += (size_t)NE*4;
  float* gC    = (float*)w; w += (size_t)NE*4;
  float* gV    = (float*)w; w += (size_t)NE*12;
  float* P1z   = (float*)w; w += (size_t)MAXZ*HH*4;
  float* P2z   = (float*)w; w += (size_t)MAXZ*HH*4;
  bf16* eabuf  = (bf16*)w;  w += (size_t)NE*384*2;   // 25.17 MB
  float* X9    = (float*)w; w += (size_t)NN*1152*4;  // 18.87 MB
  bf16* Y10    = (bf16*)w;  w += (size_t)NN*1280*2;  // 10.49 MB

  k_detect<<<1, 256, 0, stream>>>((const unsigned int*)d_in[4], flag);

  hipMemsetAsync(counts, 0, (size_t)NN*4, stream);
  k_count<<<NE/256, 256, 0, stream>>>(dst, counts);
  k_scan<<<1, 1024, 0, stream>>>(counts, offsets, cursor);
  k_fill<<<NE/256, 256, 0, stream>>>(dst, cursor, csr);

  #define DUAL(call_f32, call_bf16) do { call_f32; call_bf16; } while(0)

  DUAL(
    (k_geom<float><<<NE/256, 256, 0, stream>>>((const float*)d_in[2], (const float*)d_in[3], src, dst, gC, gV, flag)),
    (k_geom<bf16 ><<<NE/256, 256, 0, stream>>>((const bf16* )d_in[2], (const bf16* )d_in[3], src, dst, gC, gV, flag)));

  DUAL(
    (k_zemb<float><<<MAXZ, 128, 0, stream>>>((const float*)d_in[5], (const float*)d_in[12], P1z, P2z, flag)),
    (k_zemb<bf16 ><<<MAXZ, 128, 0, stream>>>((const bf16* )d_in[5], (const bf16* )d_in[12], P1z, P2z, flag)));

  DUAL(
    (k_tne_edge<float><<<NE/TPB, 128, 0, stream>>>((const float*)d_in[4], src, dst, z,
        (const float*)d_in[6], (const float*)d_in[7], (const float*)d_in[8], (const float*)d_in[9],
        (const float*)d_in[10], (const float*)d_in[11], (const float*)d_in[13], P1z, P2z, gC, eabuf, flag)),
    (k_tne_edge<bf16 ><<<NE/TPB, 128, 0, stream>>>((const bf16* )d_in[4], src, dst, z,
        (const bf16* )d_in[6], (const bf16* )d_in[7], (const bf16* )d_in[8], (const bf16* )d_in[9],
        (const bf16* )d_in[10], (const bf16* )d_in[11], (const bf16* )d_in[13], P1z, P2z, gC, eabuf, flag)));

  DUAL(
    (k_tne_node<float><<<NN, 128, 0, stream>>>(offsets, csr, gV, eabuf,
        (const float*)d_in[19], (const float*)d_in[20], (const float*)d_in[14],
        (const float*)d_in[15], (const float*)d_in[16], (const float*)d_in[17], (const float*)d_in[18], X9, flag)),
    (k_tne_node<bf16 ><<<NN, 128, 0, stream>>>(offsets, csr, gV, eabuf,
        (const bf16* )d_in[19], (const bf16* )d_in[20], (const bf16* )d_in[14],
        (const bf16* )d_in[15], (const bf16* )d_in[16], (const bf16* )d_in[17], (const bf16* )d_in[18], X9, flag)));

  for (int l=0; l<2; ++l){
    size_t o0w = (size_t)l*32*128,  o0b = (size_t)l*128;
    size_t o1w = (size_t)l*128*256, o1b = (size_t)l*256;
    size_t o2w = (size_t)l*256*384, o2b = (size_t)l*384;
    size_t oxt = (size_t)l*3*128*128;
    DUAL(
      (k_msg_edge<float><<<NE/EPB, 128, 0, stream>>>((const float*)d_in[4], gC,
          (const float*)d_in[21]+o0w, (const float*)d_in[22]+o0b,
          (const float*)d_in[23]+o1w, (const float*)d_in[24]+o1b,
          (const float*)d_in[25]+o2w, (const float*)d_in[26]+o2b, eabuf, flag)),
      (k_msg_edge<bf16 ><<<NE/EPB, 128, 0, stream>>>((const bf16* )d_in[4], gC,
          (const bf16* )d_in[21]+o0w, (const bf16* )d_in[22]+o0b,
          (const bf16* )d_in[23]+o1w, (const bf16* )d_in[24]+o1b,
          (const bf16* )d_in[25]+o2w, (const bf16* )d_in[26]+o2b, eabuf, flag)));
    DUAL(
      (k_msg_prep<float><<<NN/4, 128, 0, stream>>>(X9, (const float*)d_in[27]+oxt, Y10, flag)),
      (k_msg_prep<bf16 ><<<NN/4, 128, 0, stream>>>(X9, (const bf16* )d_in[27]+oxt, Y10, flag)));
    DUAL(
      (k_msg_sf<float><<<NN, 128, 0, stream>>>(offsets, csr, src, eabuf, Y10,
          (const float*)d_in[28]+oxt, X9, d_out, flag, (l==1)?1:0)),
      (k_msg_sf<bf16 ><<<NN, 128, 0, stream>>>(offsets, csr, src, eabuf, Y10,
          (const bf16* )d_in[28]+oxt, X9, d_out, flag, (l==1)?1:0)));
  }
  #undef DUAL
}

// Round 10
// 680.612 us; speedup vs baseline: 1.0555x; 1.0536x over previous
//
#include <hip/hip_runtime.h>
#include <hip/hip_bf16.h>

typedef __hip_bfloat16 bf16;
typedef __attribute__((ext_vector_type(8))) short short8v;   // 8 bf16 = 4 VGPRs (MFMA A/B frag)
typedef __attribute__((ext_vector_type(4))) float f32x4;     // MFMA C/D frag

#define NN 4096
#define NE 32768
#define HH 128
#define MAXZ 100
#define TPB 8    // edges per block, TNE edge kernel
#define EPB 16   // edges per block, scalar msg edge MLP kernel

// ENVIRONMENT FACTS (established r0-r9):
//  - device float tensors are FLOAT32 (in_npz 7.13MB == f32 raw 7.55MB compressed;
//    every bf16-hardcoded kernel NaN'd, every detector kernel ran f32 path fine).
//  - detector+dual-dispatch kept anyway: ~40us insurance against dtype drift.
//  - workspace >= 74MB proven usable (r1-sub wrote/read at 66-74MB, bit-identical
//    results to 53MB layout). This kernel uses ~58.5MB.

__device__ __forceinline__ float b2f(bf16 v){ return __bfloat162float(v); }
__device__ __forceinline__ float ldf(const float* p, size_t i){ return p[i]; }
__device__ __forceinline__ float ldf(const bf16*  p, size_t i){ return __bfloat162float(p[i]); }
__device__ __forceinline__ float siluf(float x){ return x / (1.0f + __expf(-x)); }
__device__ __forceinline__ unsigned short f2bu(float x){
  bf16 h = __float2bfloat16(x);
  return *reinterpret_cast<unsigned short*>(&h);
}

// dtype detect: flag[0]=1 if float inputs are f32, 0 if bf16. Reads edge_attr words.
__global__ void __launch_bounds__(256) k_detect(const unsigned int* __restrict__ w, int* __restrict__ flag){
  __shared__ int cnt[256];
  int t = threadIdx.x;
  int c = 0;
  for (int i = t; i < 4096; i += 256){
    unsigned int lo = w[i] & 0xffffu;
    int e = (int)((lo >> 7) & 0xffu);
    c += (e >= 110 && e <= 132) ? 1 : 0;
  }
  cnt[t] = c; __syncthreads();
  for (int off=128; off>=1; off>>=1){ if (t<off) cnt[t]+=cnt[t+off]; __syncthreads(); }
  if (t==0) flag[0] = (cnt[0] < 2048) ? 1 : 0;
}

// ---------------- CSR build ----------------
__global__ void __launch_bounds__(256) k_count(const int* __restrict__ dst, int* __restrict__ counts){
  int e = blockIdx.x*256 + threadIdx.x;
  if (e < NE) atomicAdd(&counts[dst[e]], 1);
}

__global__ void __launch_bounds__(1024) k_scan(const int* __restrict__ counts, int* __restrict__ offsets, int* __restrict__ cursor){
  __shared__ int lds[1024];
  int t = threadIdx.x;
  int c0 = counts[4*t+0], c1 = counts[4*t+1], c2 = counts[4*t+2], c3 = counts[4*t+3];
  int s1 = c0+c1, s2 = s1+c2, s3 = s2+c3;
  lds[t] = s3;
  __syncthreads();
  for (int off=1; off<1024; off<<=1){
    int v = lds[t];
    int add = (t>=off)? lds[t-off] : 0;
    __syncthreads();
    lds[t] = v + add;
    __syncthreads();
  }
  int incl = lds[t];
  int base = incl - s3;
  offsets[4*t+0]=base;    offsets[4*t+1]=base+c0; offsets[4*t+2]=base+s1; offsets[4*t+3]=base+s2;
  cursor [4*t+0]=base;    cursor [4*t+1]=base+c0; cursor [4*t+2]=base+s1; cursor [4*t+3]=base+s2;
  if (t==1023) offsets[4096]=incl;
}

__global__ void __launch_bounds__(256) k_fill(const int* __restrict__ dst, int* __restrict__ cursor, int* __restrict__ csr){
  int e = blockIdx.x*256 + threadIdx.x;
  if (e < NE){ int p = atomicAdd(&cursor[dst[e]], 1); csr[p] = e; }
}

// ---------------- edge geometry ----------------
template<typename T>
__global__ void __launch_bounds__(256) k_geom(const T* __restrict__ ew, const T* __restrict__ evec,
                       const int* __restrict__ src, const int* __restrict__ dst,
                       float* __restrict__ gC, float* __restrict__ gV, const int* __restrict__ flag){
  if (flag[0] != (int)(sizeof(T)==4)) return;
  int e = blockIdx.x*256 + threadIdx.x;
  if (e >= NE) return;
  float d = ldf(ew, e);
  float c = 0.5f*(cosf(d*0.6283185307179586f)+1.0f);
  c = (d < 5.0f) ? c : 0.0f;
  gC[e] = c;
  float x = ldf(evec, (size_t)e*3+0), y = ldf(evec, (size_t)e*3+1), z = ldf(evec, (size_t)e*3+2);
  if (src[e] != dst[e]){
    float n = sqrtf(x*x+y*y+z*z);
    float inv = 1.0f/fmaxf(n, 1e-12f);
    x*=inv; y*=inv; z*=inv;
  }
  gV[e*3+0]=x; gV[e*3+1]=y; gV[e*3+2]=z;
}

// ---------------- per-z embedding products ----------------
template<typename T>
__global__ void __launch_bounds__(128) k_zemb(const T* __restrict__ emb, const T* __restrict__ emb2_w,
                      float* __restrict__ P1z, float* __restrict__ P2z, const int* __restrict__ flag){
  if (flag[0] != (int)(sizeof(T)==4)) return;
  int zv = blockIdx.x, h = threadIdx.x;
  __shared__ float Zr[128];
  Zr[h] = ldf(emb, (size_t)zv*HH + h);
  __syncthreads();
  float p1=0.f, p2=0.f;
  for (int r=0;r<128;++r){
    float x = Zr[r];
    p1 += x*ldf(emb2_w, (size_t)r*HH+h);
    p2 += x*ldf(emb2_w, (size_t)(r+128)*HH+h);
  }
  P1z[zv*HH+h]=p1; P2z[zv*HH+h]=p2;
}

// ---------------- convert edge_attr -> bf16 buffer ----------------
template<typename T>
__global__ void __launch_bounds__(256) k_cvt_attr(const T* __restrict__ in, unsigned short* __restrict__ out,
                                                  const int* __restrict__ flag){
  if (flag[0] != (int)(sizeof(T)==4)) return;
  int i = blockIdx.x*256 + threadIdx.x;   // NE*32 = 1048576 elements
  out[i] = f2bu(ldf(in, (size_t)i));
}

// ---------------- weight repack into MFMA B-fragment layout (bf16 out) ----------------
// B-frag (16x16x32 bf16): lane holds W[kt*32 + (lane>>4)*8 + j][nt*16 + (lane&15)], j=0..7.
// Tile order: tile = nt*ktiles + kt; out[tile*64 + lane][8].
struct PackDescs {
  const void*     W[6];
  unsigned short* out[6];
  int K[6]; int N[6];
};
template<typename T>
__global__ void __launch_bounds__(256) k_pack(PackDescs d, const int* __restrict__ flag){
  if (flag[0] != (int)(sizeof(T)==4)) return;
  int y = blockIdx.y;
  int K = d.K[y], N = d.N[y];
  int ktiles = K>>5, ntiles = N>>4;
  int total = ktiles*ntiles*64;
  int idx = blockIdx.x*256 + threadIdx.x;
  if (idx >= total) return;
  int lane = idx & 63, tile = idx >> 6;
  int kt = tile % ktiles, nt = tile / ktiles;
  const T* W = (const T*)d.W[y];
  int n = nt*16 + (lane&15), k0 = kt*32 + (lane>>4)*8;
  unsigned int t[8];
  #pragma unroll
  for (int j=0;j<8;++j) t[j] = f2bu(ldf(W, (size_t)(k0+j)*N + n));
  uint4 v;
  v.x = t[0] | (t[1]<<16);
  v.y = t[2] | (t[3]<<16);
  v.z = t[4] | (t[5]<<16);
  v.w = t[6] | (t[7]<<16);
  *reinterpret_cast<uint4*>(d.out[y] + ((size_t)tile*64 + lane)*8) = v;
}

// ---------------- TNE edge coefficients -> eabuf bf16 [E][3][128] ----------------
template<typename T>
__global__ void __launch_bounds__(128) k_tne_edge(
  const T* __restrict__ eattr, const int* __restrict__ src, const int* __restrict__ dst,
  const int* __restrict__ z,
  const T* __restrict__ dp1_w, const T* __restrict__ dp1_b,
  const T* __restrict__ dp2_w, const T* __restrict__ dp2_b,
  const T* __restrict__ dp3_w, const T* __restrict__ dp3_b,
  const T* __restrict__ emb2_b, const float* __restrict__ P1z, const float* __restrict__ P2z,
  const float* __restrict__ gC, bf16* __restrict__ eabuf, const int* __restrict__ flag)
{
  if (flag[0] != (int)(sizeof(T)==4)) return;
  int e0 = blockIdx.x*TPB;
  int h  = threadIdx.x;
  __shared__ float attr[TPB][32];
  __shared__ int zd[TPB], zs[TPB];
  for (int i=h; i<TPB*32; i+=128) attr[i>>5][i&31] = ldf(eattr, (size_t)e0*32 + i);
  if (h < TPB){ int e=e0+h; zd[h]=z[dst[e]]; zs[h]=z[src[e]]; }
  __syncthreads();
  float w1[TPB], w2[TPB], w3[TPB];
  float b1v=ldf(dp1_b,h), b2v=ldf(dp2_b,h), b3v=ldf(dp3_b,h);
  #pragma unroll
  for (int e=0;e<TPB;++e){ w1[e]=b1v; w2[e]=b2v; w3[e]=b3v; }
  for (int r=0;r<32;++r){
    float u1=ldf(dp1_w,(size_t)r*HH+h), u2=ldf(dp2_w,(size_t)r*HH+h), u3=ldf(dp3_w,(size_t)r*HH+h);
    #pragma unroll
    for (int e=0;e<TPB;++e){ float a=attr[e][r]; w1[e]+=a*u1; w2[e]+=a*u2; w3[e]+=a*u3; }
  }
  float eb = ldf(emb2_b,h);
  #pragma unroll
  for (int e=0;e<TPB;++e){
    float zij = P1z[zd[e]*HH+h] + P2z[zs[e]*HH+h] + eb;
    float c = gC[e0+e];
    bf16* p = eabuf + (size_t)(e0+e)*384;
    p[h]     = __float2bfloat16(zij*w1[e]*c);
    p[128+h] = __float2bfloat16(zij*w2[e]*c);
    p[256+h] = __float2bfloat16(zij*w3[e]*c);
  }
}

// ---------------- TNE node ----------------
template<typename T>
__global__ void __launch_bounds__(128) k_tne_node(
  const int* __restrict__ offsets, const int* __restrict__ csr,
  const float* __restrict__ gV, const bf16* __restrict__ eabuf,
  const T* __restrict__ ln_g, const T* __restrict__ ln_b,
  const T* __restrict__ tne_lt,
  const T* __restrict__ s0_w, const T* __restrict__ s0_b,
  const T* __restrict__ s1_w, const T* __restrict__ s1_b,
  float* __restrict__ X9, const int* __restrict__ flag)
{
  if (flag[0] != (int)(sizeof(T)==4)) return;
  int n = blockIdx.x, h = threadIdx.x;
  float a=0, v0=0,v1=0,v2=0, s0=0,s1=0,s2=0,s3=0,s4=0,s5=0;
  int beg = offsets[n], end = offsets[n+1];
  for (int i=beg;i<end;++i){
    int e = csr[i];
    const bf16* p = eabuf + (size_t)e*384;
    float c1 = b2f(p[h]), c2 = b2f(p[128+h]), c3 = b2f(p[256+h]);
    float vx = gV[e*3+0], vy = gV[e*3+1], vz = gV[e*3+2];
    float tr3 = (vx*vx+vy*vy+vz*vz)*(1.0f/3.0f);
    a  += c1;
    v0 += c2*vx; v1 += c2*vy; v2 += c2*vz;
    s0 += c3*(vx*vx - tr3); s1 += c3*vx*vy;          s2 += c3*vx*vz;
    s3 += c3*(vy*vy - tr3); s4 += c3*vy*vz;          s5 += c3*(vz*vz - tr3);
  }
  float tn = 3.0f*a*a + 2.0f*(v0*v0+v1*v1+v2*v2)
           + s0*s0 + s3*s3 + s5*s5 + 2.0f*(s1*s1 + s2*s2 + s4*s4);
  __shared__ float red[128];
  red[h] = tn; __syncthreads();
  for (int off=64; off>=1; off>>=1){ if (h<off) red[h]+=red[h+off]; __syncthreads(); }
  float mean = red[0]*(1.0f/128.0f);
  __syncthreads();
  float dm = tn - mean;
  red[h] = dm*dm; __syncthreads();
  for (int off=64; off>=1; off>>=1){ if (h<off) red[h]+=red[h+off]; __syncthreads(); }
  float var = red[0]*(1.0f/128.0f);
  float ln = dm*rsqrtf(var+1e-5f)*ldf(ln_g,h) + ldf(ln_b,h);
  __shared__ float lnv[128];
  __shared__ float h1[256];
  lnv[h] = ln; __syncthreads();
  float a0 = ldf(s0_b,2*h), a1 = ldf(s0_b,2*h+1);
  for (int r=0;r<128;++r){ float x = lnv[r]; a0 += x*ldf(s0_w,(size_t)r*256+2*h); a1 += x*ldf(s0_w,(size_t)r*256+2*h+1); }
  h1[2*h] = siluf(a0); h1[2*h+1] = siluf(a1);
  __syncthreads();
  float f0 = ldf(s1_b,3*h), f1 = ldf(s1_b,3*h+1), f2 = ldf(s1_b,3*h+2);
  for (int r=0;r<256;++r){ float x = h1[r]; f0 += x*ldf(s1_w,(size_t)r*384+3*h); f1 += x*ldf(s1_w,(size_t)r*384+3*h+1); f2 += x*ldf(s1_w,(size_t)r*384+3*h+2); }
  f0 = siluf(f0); f1 = siluf(f1); f2 = siluf(f2);
  __shared__ float sm[10][128];
  sm[0][h]=a; sm[1][h]=v0; sm[2][h]=v1; sm[3][h]=v2;
  sm[4][h]=s0; sm[5][h]=s1; sm[6][h]=s2; sm[7][h]=s3; sm[8][h]=s4; sm[9][h]=s5;
  __syncthreads();
  float am=0, wm0=0,wm1=0,wm2=0, t0=0,t1=0,t2=0,t3=0,t4=0,t5=0;
  for (int r=0;r<128;++r){
    float w0 = ldf(tne_lt,(size_t)r*128+h);        am += sm[0][r]*w0;
    float w1 = ldf(tne_lt,(size_t)16384+r*128+h);  wm0 += sm[1][r]*w1; wm1 += sm[2][r]*w1; wm2 += sm[3][r]*w1;
    float w2 = ldf(tne_lt,(size_t)32768+r*128+h);  t0 += sm[4][r]*w2; t1 += sm[5][r]*w2; t2 += sm[6][r]*w2;
                                                   t3 += sm[7][r]*w2; t4 += sm[8][r]*w2; t5 += sm[9][r]*w2;
  }
  float x00 = f0*am + f2*t0;
  float x01 = -f1*wm2 + f2*t1;
  float x02 =  f1*wm1 + f2*t2;
  float x10 =  f1*wm2 + f2*t1;
  float x11 = f0*am + f2*t3;
  float x12 = -f1*wm0 + f2*t4;
  float x20 = -f1*wm1 + f2*t2;
  float x21 =  f1*wm0 + f2*t4;
  float x22 = f0*am + f2*t5;
  float* xp = X9 + (size_t)n*1152;
  xp[0*128+h]=x00; xp[1*128+h]=x01; xp[2*128+h]=x02;
  xp[3*128+h]=x10; xp[4*128+h]=x11; xp[5*128+h]=x12;
  xp[6*128+h]=x20; xp[7*128+h]=x21; xp[8*128+h]=x22;
}

// ---------------- msg edge MLP via MFMA (validated per-layer, scalar fallback) ----------------
// Per wave: 16 edges. A-frag: m=lane&15, k=(lane>>4)*8+j. B-frag pre-packed.
// C/D: col n=lane&15, row m=(lane>>4)*4+reg [m89-verified].
template<typename T>
__global__ void __launch_bounds__(128) k_msg_edge_mfma(
  const unsigned short* __restrict__ eattr_c, const float* __restrict__ gC,
  const unsigned short* __restrict__ p0, const unsigned short* __restrict__ p1,
  const unsigned short* __restrict__ p2,
  const T* __restrict__ b0, const T* __restrict__ b1, const T* __restrict__ b2,
  unsigned short* __restrict__ eabuf, const int* __restrict__ flag)
{
  if (flag[0] != (int)(sizeof(T)==4)) return;
  int wid  = threadIdx.x >> 6;
  int lane = threadIdx.x & 63;
  int e0 = blockIdx.x*32 + wid*16;
  int m = lane & 15, g = lane >> 4;
  __shared__ __align__(16) unsigned short h1p[2][2048];
  __shared__ __align__(16) unsigned short h2p[2][4096];
  float cc[4];
  #pragma unroll
  for (int r=0;r<4;++r) cc[r] = gC[e0 + g*4 + r];
  short8v a1 = *reinterpret_cast<const short8v*>(eattr_c + (size_t)(e0+m)*32 + g*8);
  #pragma unroll
  for (int nt=0; nt<8; ++nt){
    float bias = ldf(b0, nt*16+m);
    f32x4 acc = {bias,bias,bias,bias};
    short8v b = *reinterpret_cast<const short8v*>(p0 + ((size_t)nt*64 + lane)*8);
    acc = __builtin_amdgcn_mfma_f32_16x16x32_bf16(a1, b, acc, 0,0,0);
    #pragma unroll
    for (int r=0;r<4;++r){
      int n = nt*16 + m, row = g*4 + r;
      h1p[wid][(n>>5)*512 + (((n>>3)&3)*16+row)*8 + (n&7)] = f2bu(siluf(acc[r]));
    }
  }
  __syncthreads();
  short8v a2[4];
  #pragma unroll
  for (int ks=0; ks<4; ++ks) a2[ks] = *reinterpret_cast<const short8v*>(&h1p[wid][ks*512 + lane*8]);
  for (int nt=0; nt<16; ++nt){
    float bias = ldf(b1, nt*16+m);
    f32x4 acc = {bias,bias,bias,bias};
    #pragma unroll
    for (int ks=0; ks<4; ++ks){
      short8v b = *reinterpret_cast<const short8v*>(p1 + ((size_t)(nt*4+ks)*64 + lane)*8);
      acc = __builtin_amdgcn_mfma_f32_16x16x32_bf16(a2[ks], b, acc, 0,0,0);
    }
    #pragma unroll
    for (int r=0;r<4;++r){
      int n = nt*16 + m, row = g*4 + r;
      h2p[wid][(n>>5)*512 + (((n>>3)&3)*16+row)*8 + (n&7)] = f2bu(siluf(acc[r]));
    }
  }
  __syncthreads();
  short8v a3[8];
  #pragma unroll
  for (int ks=0; ks<8; ++ks) a3[ks] = *reinterpret_cast<const short8v*>(&h2p[wid][ks*512 + lane*8]);
  for (int nt=0; nt<24; ++nt){
    float bias = ldf(b2, nt*16+m);
    f32x4 acc = {bias,bias,bias,bias};
    #pragma unroll
    for (int ks=0; ks<8; ++ks){
      short8v b = *reinterpret_cast<const short8v*>(p2 + ((size_t)(nt*8+ks)*64 + lane)*8);
      acc = __builtin_amdgcn_mfma_f32_16x16x32_bf16(a3[ks], b, acc, 0,0,0);
    }
    #pragma unroll
    for (int r=0;r<4;++r){
      int n = nt*16 + m, row = g*4 + r;
      float v = siluf(acc[r]) * cc[r];
      eabuf[(size_t)(e0+row)*384 + (n%3)*128 + (n/3)] = f2bu(v);
    }
  }
}

// ---------------- scalar msg edge MLP. mode 0: 512-edge sample->esamp; mode 1: guarded full fallback ----------------
template<typename T>
__global__ void __launch_bounds__(128) k_msg_edge_scalar(
  const T* __restrict__ eattr, const float* __restrict__ gC,
  const T* __restrict__ l0_w, const T* __restrict__ l0_b,
  const T* __restrict__ l1_w, const T* __restrict__ l1_b,
  const T* __restrict__ l2_w, const T* __restrict__ l2_b,
  bf16* __restrict__ outb, const int* __restrict__ ok, int mode, const int* __restrict__ flag)
{
  if (flag[0] != (int)(sizeof(T)==4)) return;
  if (mode == 1 && ok[0] != 0) return;   // MFMA validated -> skip fallback
  int e0, so;
  if (mode == 0){
    e0 = (blockIdx.x < 16) ? blockIdx.x*EPB : (NE-256) + (blockIdx.x-16)*EPB;
    so = blockIdx.x*EPB;
  } else { e0 = blockIdx.x*EPB; so = e0; }
  int h = threadIdx.x;
  __shared__ float attr[EPB][32];
  __shared__ float h1[EPB][128];
  __shared__ float h2[EPB][256];
  for (int i=h; i<EPB*32; i+=128) attr[i>>5][i&31] = ldf(eattr, (size_t)e0*32 + i);
  __syncthreads();
  {
    float b = ldf(l0_b,h);
    float a0[EPB];
    #pragma unroll
    for (int e=0;e<EPB;++e) a0[e]=b;
    for (int r=0;r<32;++r){
      float u = ldf(l0_w,(size_t)r*128+h);
      #pragma unroll
      for (int e=0;e<EPB;++e) a0[e] += attr[e][r]*u;
    }
    #pragma unroll
    for (int e=0;e<EPB;++e) h1[e][h] = siluf(a0[e]);
  }
  __syncthreads();
  {
    float ba = ldf(l1_b,2*h), bb = ldf(l1_b,2*h+1);
    float b0[EPB], b1a[EPB];
    #pragma unroll
    for (int e=0;e<EPB;++e){ b0[e]=ba; b1a[e]=bb; }
    for (int r=0;r<128;++r){
      float ua = ldf(l1_w,(size_t)r*256+2*h), ub = ldf(l1_w,(size_t)r*256+2*h+1);
      #pragma unroll
      for (int e=0;e<EPB;++e){ float x = h1[e][r]; b0[e]+=x*ua; b1a[e]+=x*ub; }
    }
    #pragma unroll
    for (int e=0;e<EPB;++e){ h2[e][2*h] = siluf(b0[e]); h2[e][2*h+1] = siluf(b1a[e]); }
  }
  __syncthreads();
  {
    float ba = ldf(l2_b,3*h), bb = ldf(l2_b,3*h+1), bc = ldf(l2_b,3*h+2);
    float c0[EPB], c1[EPB], c2[EPB];
    #pragma unroll
    for (int e=0;e<EPB;++e){ c0[e]=ba; c1[e]=bb; c2[e]=bc; }
    for (int r=0;r<256;++r){
      float u0 = ldf(l2_w,(size_t)r*384+3*h), u1 = ldf(l2_w,(size_t)r*384+3*h+1), u2 = ldf(l2_w,(size_t)r*384+3*h+2);
      #pragma unroll
      for (int e=0;e<EPB;++e){ float x = h2[e][r]; c0[e]+=x*u0; c1[e]+=x*u1; c2[e]+=x*u2; }
    }
    #pragma unroll
    for (int e=0;e<EPB;++e){
      float C = gC[e0+e];
      bf16* p = outb + (size_t)(so+e)*384;
      p[h]     = __float2bfloat16(siluf(c0[e])*C);
      p[128+h] = __float2bfloat16(siluf(c1[e])*C);
      p[256+h] = __float2bfloat16(siluf(c2[e])*C);
    }
  }
}

// ---------------- validation: sample compare + finite scan ----------------
__global__ void __launch_bounds__(256) k_cmp(const bf16* __restrict__ eabuf, const bf16* __restrict__ esamp,
                                             int* __restrict__ ok){
  int i = blockIdx.x*256 + threadIdx.x;   // i < 512*384
  int s = i/384, j = i%384;
  int e = (s < 256) ? s : (NE-256 + (s-256));
  float va = b2f(eabuf[(size_t)e*384 + j]);
  float vb = b2f(esamp[i]);
  float d = fabsf(va - vb);
  if (!(d <= 0.08f)) atomicExch(ok, 0);   // catches NaN/inf too
}

__global__ void __launch_bounds__(256) k_finite(const unsigned short* __restrict__ a, int* __restrict__ ok){
  size_t i = ((size_t)blockIdx.x*256 + threadIdx.x)*8;  // NE*384 shorts total
  uint4 v = *reinterpret_cast<const uint4*>(a + i);
  bool bad = false;
  #pragma unroll
  for (int k=0;k<4;++k){
    unsigned int w = (k==0)?v.x:(k==1)?v.y:(k==2)?v.z:v.w;
    unsigned int lo = w & 0xffffu, hi = w >> 16;
    if (((lo>>7)&0xffu)==0xffu || ((hi>>7)&0xffu)==0xffu) bad = true;
  }
  if (bad) atomicExch(ok, 0);
}

// ---------------- msg node prep (4 nodes/block): normalize X (WRITE BACK), decompose, cmix lx -> Y10 bf16 ----------------
template<typename T>
__global__ void __launch_bounds__(128) k_msg_prep(
  float* __restrict__ X9, const T* __restrict__ lx, bf16* __restrict__ Y10,
  const int* __restrict__ flag)
{
  if (flag[0] != (int)(sizeof(T)==4)) return;
  int n0 = blockIdx.x*4, h = threadIdx.x;
  __shared__ float sm[4][10][128];
  #pragma unroll
  for (int nn=0;nn<4;++nn){
    float* xp = X9 + (size_t)(n0+nn)*1152;
    float x00=xp[0*128+h], x01=xp[1*128+h], x02=xp[2*128+h];
    float x10=xp[3*128+h], x11=xp[4*128+h], x12=xp[5*128+h];
    float x20=xp[6*128+h], x21=xp[7*128+h], x22=xp[8*128+h];
    float tn = x00*x00+x01*x01+x02*x02+x10*x10+x11*x11+x12*x12+x20*x20+x21*x21+x22*x22;
    float inv = 1.0f/(tn+1.0f);
    x00*=inv; x01*=inv; x02*=inv; x10*=inv; x11*=inv; x12*=inv; x20*=inv; x21*=inv; x22*=inv;
    // Reference REBINDS X to normalized before the update: X = X/(tnorm+1); ... X = X + dX
    xp[0*128+h]=x00; xp[1*128+h]=x01; xp[2*128+h]=x02;
    xp[3*128+h]=x10; xp[4*128+h]=x11; xp[5*128+h]=x12;
    xp[6*128+h]=x20; xp[7*128+h]=x21; xp[8*128+h]=x22;
    float a = (x00+x11+x22)*(1.0f/3.0f);
    sm[nn][0][h]=a;
    sm[nn][1][h]=0.5f*(x21-x12);
    sm[nn][2][h]=0.5f*(x02-x20);
    sm[nn][3][h]=0.5f*(x10-x01);
    sm[nn][4][h]=x00-a;
    sm[nn][5][h]=0.5f*(x01+x10);
    sm[nn][6][h]=0.5f*(x02+x20);
    sm[nn][7][h]=x11-a;
    sm[nn][8][h]=0.5f*(x12+x21);
    sm[nn][9][h]=x22-a;
  }
  __syncthreads();
  float A[4]={0,0,0,0};
  float V0[4]={0,0,0,0}, V1[4]={0,0,0,0}, V2[4]={0,0,0,0};
  float S0[4]={0,0,0,0}, S1[4]={0,0,0,0}, S2[4]={0,0,0,0};
  float S3[4]={0,0,0,0}, S4[4]={0,0,0,0}, S5[4]={0,0,0,0};
  for (int r=0;r<128;++r){
    float w0 = ldf(lx,(size_t)r*128+h), w1 = ldf(lx,(size_t)16384+r*128+h), w2 = ldf(lx,(size_t)32768+r*128+h);
    #pragma unroll
    for (int nn=0;nn<4;++nn){
      A[nn]  += sm[nn][0][r]*w0;
      V0[nn] += sm[nn][1][r]*w1; V1[nn] += sm[nn][2][r]*w1; V2[nn] += sm[nn][3][r]*w1;
      S0[nn] += sm[nn][4][r]*w2; S1[nn] += sm[nn][5][r]*w2; S2[nn] += sm[nn][6][r]*w2;
      S3[nn] += sm[nn][7][r]*w2; S4[nn] += sm[nn][8][r]*w2; S5[nn] += sm[nn][9][r]*w2;
    }
  }
  #pragma unroll
  for (int nn=0;nn<4;++nn){
    bf16* yp = Y10 + (size_t)(n0+nn)*1280;
    yp[0*128+h]=__float2bfloat16(A[nn]);
    yp[1*128+h]=__float2bfloat16(V0[nn]); yp[2*128+h]=__float2bfloat16(V1[nn]); yp[3*128+h]=__float2bfloat16(V2[nn]);
    yp[4*128+h]=__float2bfloat16(S0[nn]); yp[5*128+h]=__float2bfloat16(S1[nn]); yp[6*128+h]=__float2bfloat16(S2[nn]);
    yp[7*128+h]=__float2bfloat16(S3[nn]); yp[8*128+h]=__float2bfloat16(S4[nn]); yp[9*128+h]=__float2bfloat16(S5[nn]);
  }
}

// ---------------- msg scatter + AB + decompose + cmix lt + dX update (fused) ----------------
template<typename T>
__global__ void __launch_bounds__(128) k_msg_sf(
  const int* __restrict__ offsets, const int* __restrict__ csr, const int* __restrict__ srcA,
  const bf16* __restrict__ eabuf, const bf16* __restrict__ Y10, const T* __restrict__ lt,
  float* __restrict__ X9, void* __restrict__ out, const int* __restrict__ flag, int write_out)
{
  if (flag[0] != (int)(sizeof(T)==4)) return;
  int n = blockIdx.x, h = threadIdx.x;
  float am=0, vm0=0,vm1=0,vm2=0, smm0=0,smm1=0,smm2=0,smm3=0,smm4=0,smm5=0;
  int beg = offsets[n], end = offsets[n+1];
  for (int i=beg;i<end;++i){
    int e = csr[i]; int s = srcA[e];
    const bf16* ep = eabuf + (size_t)e*384;
    float e0 = b2f(ep[h]), e1 = b2f(ep[128+h]), e2 = b2f(ep[256+h]);
    const bf16* yp = Y10 + (size_t)s*1280;
    am   += e0*b2f(yp[0*128+h]);
    vm0  += e1*b2f(yp[1*128+h]); vm1 += e1*b2f(yp[2*128+h]); vm2 += e1*b2f(yp[3*128+h]);
    smm0 += e2*b2f(yp[4*128+h]); smm1 += e2*b2f(yp[5*128+h]); smm2 += e2*b2f(yp[6*128+h]);
    smm3 += e2*b2f(yp[7*128+h]); smm4 += e2*b2f(yp[8*128+h]); smm5 += e2*b2f(yp[9*128+h]);
  }
  const bf16* yp = Y10 + (size_t)n*1280;
  float aY=b2f(yp[0*128+h]), u0=b2f(yp[1*128+h]), u1=b2f(yp[2*128+h]), u2=b2f(yp[3*128+h]);
  float q0=b2f(yp[4*128+h]), q1=b2f(yp[5*128+h]), q2=b2f(yp[6*128+h]);
  float q3=b2f(yp[7*128+h]), q4=b2f(yp[8*128+h]), q5=b2f(yp[9*128+h]);
  float m00=am+smm0,   m01=-vm2+smm1, m02= vm1+smm2;
  float m10= vm2+smm1, m11=am+smm3,  m12=-vm0+smm4;
  float m20=-vm1+smm2, m21= vm0+smm4, m22=am+smm5;
  float y00=aY+q0,  y01=-u2+q1, y02= u1+q2;
  float y10= u2+q1, y11=aY+q3,  y12=-u0+q4;
  float y20=-u1+q2, y21= u0+q4, y22=aY+q5;
  float ab00 = m00*y00+m01*y10+m02*y20 + y00*m00+y01*m10+y02*m20;
  float ab01 = m00*y01+m01*y11+m02*y21 + y00*m01+y01*m11+y02*m21;
  float ab02 = m00*y02+m01*y12+m02*y22 + y00*m02+y01*m12+y02*m22;
  float ab10 = m10*y00+m11*y10+m12*y20 + y10*m00+y11*m10+y12*m20;
  float ab11 = m10*y01+m11*y11+m12*y21 + y10*m01+y11*m11+y12*m21;
  float ab12 = m10*y02+m11*y12+m12*y22 + y10*m02+y11*m12+y12*m22;
  float ab20 = m20*y00+m21*y10+m22*y20 + y20*m00+y21*m10+y22*m20;
  float ab21 = m20*y01+m21*y11+m22*y21 + y20*m01+y21*m11+y22*m21;
  float ab22 = m20*y02+m21*y12+m22*y22 + y20*m02+y21*m12+y22*m22;
  float a2 = (ab00+ab11+ab22)*(1.0f/3.0f);
  float w0 = 0.5f*(ab21-ab12), w1 = 0.5f*(ab02-ab20), w2 = 0.5f*(ab10-ab01);
  float t0 = ab00-a2, t1 = 0.5f*(ab01+ab10), t2 = 0.5f*(ab02+ab20);
  float t3 = ab11-a2, t4 = 0.5f*(ab12+ab21), t5 = ab22-a2;
  float dnm = ab00*ab00+ab01*ab01+ab02*ab02+ab10*ab10+ab11*ab11+ab12*ab12
            + ab20*ab20+ab21*ab21+ab22*ab22 + 1.0f;
  float inv = 1.0f/dnm;
  __shared__ float sm[10][128];
  sm[0][h]=a2*inv; sm[1][h]=w0*inv; sm[2][h]=w1*inv; sm[3][h]=w2*inv;
  sm[4][h]=t0*inv; sm[5][h]=t1*inv; sm[6][h]=t2*inv;
  sm[7][h]=t3*inv; sm[8][h]=t4*inv; sm[9][h]=t5*inv;
  __syncthreads();
  float at=0, vt0=0,vt1=0,vt2=0, st0=0,st1=0,st2=0,st3=0,st4=0,st5=0;
  for (int r=0;r<128;++r){
    float ww0 = ldf(lt,(size_t)r*128+h);        at += sm[0][r]*ww0;
    float ww1 = ldf(lt,(size_t)16384+r*128+h);  vt0 += sm[1][r]*ww1; vt1 += sm[2][r]*ww1; vt2 += sm[3][r]*ww1;
    float ww2 = ldf(lt,(size_t)32768+r*128+h);  st0 += sm[4][r]*ww2; st1 += sm[5][r]*ww2; st2 += sm[6][r]*ww2;
                                                st3 += sm[7][r]*ww2; st4 += sm[8][r]*ww2; st5 += sm[9][r]*ww2;
  }
  float d00=at+st0,   d01=-vt2+st1, d02= vt1+st2;
  float d10= vt2+st1, d11=at+st3,  d12=-vt0+st4;
  float d20=-vt1+st2, d21= vt0+st4, d22=at+st5;
  float g00 = d00 + d00*d00+d01*d10+d02*d20;
  float g01 = d01 + d00*d01+d01*d11+d02*d21;
  float g02 = d02 + d00*d02+d01*d12+d02*d22;
  float g10 = d10 + d10*d00+d11*d10+d12*d20;
  float g11 = d11 + d10*d01+d11*d11+d12*d21;
  float g12 = d12 + d10*d02+d11*d12+d12*d22;
  float g20 = d20 + d20*d00+d21*d10+d22*d20;
  float g21 = d21 + d20*d01+d21*d11+d22*d21;
  float g22 = d22 + d20*d02+d21*d12+d22*d22;
  float* xp = X9 + (size_t)n*1152;
  float x00=xp[0*128+h]+g00, x01=xp[1*128+h]+g01, x02=xp[2*128+h]+g02;
  float x10=xp[3*128+h]+g10, x11=xp[4*128+h]+g11, x12=xp[5*128+h]+g12;
  float x20=xp[6*128+h]+g20, x21=xp[7*128+h]+g21, x22=xp[8*128+h]+g22;
  if (write_out){
    T* o = (T*)out + ((size_t)n*128 + h)*9;
    if (sizeof(T)==4){
      float* of = (float*)o;
      of[0]=x00; of[1]=x01; of[2]=x02; of[3]=x10; of[4]=x11; of[5]=x12; of[6]=x20; of[7]=x21; of[8]=x22;
    } else {
      bf16* ob = (bf16*)o;
      ob[0]=__float2bfloat16(x00); ob[1]=__float2bfloat16(x01); ob[2]=__float2bfloat16(x02);
      ob[3]=__float2bfloat16(x10); ob[4]=__float2bfloat16(x11); ob[5]=__float2bfloat16(x12);
      ob[6]=__float2bfloat16(x20); ob[7]=__float2bfloat16(x21); ob[8]=__float2bfloat16(x22);
    }
  } else {
    xp[0*128+h]=x00; xp[1*128+h]=x01; xp[2*128+h]=x02;
    xp[3*128+h]=x10; xp[4*128+h]=x11; xp[5*128+h]=x12;
    xp[6*128+h]=x20; xp[7*128+h]=x21; xp[8*128+h]=x22;
  }
}

extern "C" void kernel_launch(void* const* d_in, const int* in_sizes, int n_in,
                              void* d_out, int out_size, void* d_ws, size_t ws_size,
                              hipStream_t stream)
{
  (void)in_sizes; (void)n_in; (void)out_size; (void)ws_size;
  const int* z    = (const int*)d_in[0];
  const int* eidx = (const int*)d_in[1];
  const int* src  = eidx;
  const int* dst  = eidx + NE;

  // Workspace: ~58.5 MiB (proven budget >= 74 MiB).
  char* w = (char*)d_ws;
  int* flag    = (int*)w;   w += 64;
  int* ok      = (int*)w;   w += 64;
  int* counts  = (int*)w;   w += (size_t)NN*4;
  int* offsets = (int*)w;   w += (size_t)(NN+1)*4 + 60;
  int* cursor  = (int*)w;   w += (size_t)NN*4;
  int* csr     = (int*)w;   w += (size_t)NE*4;
  float* gC    = (float*)w; w += (size_t)NE*4;
  float* gV    = (float*)w; w += (size_t)NE*12;
  float* P1z   = (float*)w; w += (size_t)MAXZ*HH*4;
  float* P2z   = (float*)w; w += (size_t)MAXZ*HH*4;
  bf16* eabuf  = (bf16*)w;  w += (size_t)NE*384*2;       // 25.17 MB
  float* X9    = (float*)w; w += (size_t)NN*1152*4;      // 18.87 MB
  bf16* Y10    = (bf16*)w;  w += (size_t)NN*1280*2;      // 10.49 MB
  unsigned short* eattr_c = (unsigned short*)w; w += (size_t)NE*32*2;   // 2.10 MB
  bf16* esamp  = (bf16*)w;  w += (size_t)512*384*2;      // 0.39 MB
  unsigned short* pw0[2]; unsigned short* pw1[2]; unsigned short* pw2[2];
  for (int l=0;l<2;++l){
    pw0[l] = (unsigned short*)w; w += 8*64*8*2;      //   8 KB
    pw1[l] = (unsigned short*)w; w += 64*64*8*2;     //  64 KB
    pw2[l] = (unsigned short*)w; w += 192*64*8*2;    // 192 KB
  }

  k_detect<<<1, 256, 0, stream>>>((const unsigned int*)d_in[4], flag);
  hipMemsetAsync(counts, 0, (size_t)NN*4, stream);
  hipMemsetAsync(ok, 0x01, 8, stream);   // ok[l] nonzero = MFMA trusted
  k_count<<<NE/256, 256, 0, stream>>>(dst, counts);
  k_scan<<<1, 1024, 0, stream>>>(counts, offsets, cursor);
  k_fill<<<NE/256, 256, 0, stream>>>(dst, cursor, csr);

  #define DUAL(call_f32, call_bf16) do { call_f32; call_bf16; } while(0)

  DUAL(
    (k_geom<float><<<NE/256, 256, 0, stream>>>((const float*)d_in[2], (const float*)d_in[3], src, dst, gC, gV, flag)),
    (k_geom<bf16 ><<<NE/256, 256, 0, stream>>>((const bf16* )d_in[2], (const bf16* )d_in[3], src, dst, gC, gV, flag)));
  DUAL(
    (k_zemb<float><<<MAXZ, 128, 0, stream>>>((const float*)d_in[5], (const float*)d_in[12], P1z, P2z, flag)),
    (k_zemb<bf16 ><<<MAXZ, 128, 0, stream>>>((const bf16* )d_in[5], (const bf16* )d_in[12], P1z, P2z, flag)));
  DUAL(
    (k_cvt_attr<float><<<NE*32/256, 256, 0, stream>>>((const float*)d_in[4], eattr_c, flag)),
    (k_cvt_attr<bf16 ><<<NE*32/256, 256, 0, stream>>>((const bf16* )d_in[4], eattr_c, flag)));

  // pack msg MLP weights (both layers, 6 matrices) into MFMA B-fragment bf16 form
  PackDescs pd;
  for (int l=0;l<2;++l){
    pd.W[l*3+0] = (const void*)((const float*)d_in[21] + (size_t)l*32*128);
    pd.W[l*3+1] = (const void*)((const float*)d_in[23] + (size_t)l*128*256);
    pd.W[l*3+2] = (const void*)((const float*)d_in[25] + (size_t)l*256*384);
    pd.out[l*3+0] = pw0[l]; pd.K[l*3+0]=32;  pd.N[l*3+0]=128;
    pd.out[l*3+1] = pw1[l]; pd.K[l*3+1]=128; pd.N[l*3+1]=256;
    pd.out[l*3+2] = pw2[l]; pd.K[l*3+2]=256; pd.N[l*3+2]=384;
  }
  PackDescs pdb = pd;   // bf16 variant: same byte offsets computed with bf16 element size
  for (int l=0;l<2;++l){
    pdb.W[l*3+0] = (const void*)((const bf16*)d_in[21] + (size_t)l*32*128);
    pdb.W[l*3+1] = (const void*)((const bf16*)d_in[23] + (size_t)l*128*256);
    pdb.W[l*3+2] = (const void*)((const bf16*)d_in[25] + (size_t)l*256*384);
  }
  DUAL(
    (k_pack<float><<<dim3(48, 6), 256, 0, stream>>>(pd,  flag)),
    (k_pack<bf16 ><<<dim3(48, 6), 256, 0, stream>>>(pdb, flag)));

  DUAL(
    (k_tne_edge<float><<<NE/TPB, 128, 0, stream>>>((const float*)d_in[4], src, dst, z,
        (const float*)d_in[6], (const float*)d_in[7], (const float*)d_in[8], (const float*)d_in[9],
        (const float*)d_in[10], (const float*)d_in[11], (const float*)d_in[13], P1z, P2z, gC, eabuf, flag)),
    (k_tne_edge<bf16 ><<<NE/TPB, 128, 0, stream>>>((const bf16* )d_in[4], src, dst, z,
        (const bf16* )d_in[6], (const bf16* )d_in[7], (const bf16* )d_in[8], (const bf16* )d_in[9],
        (const bf16* )d_in[10], (const bf16* )d_in[11], (const bf16* )d_in[13], P1z, P2z, gC, eabuf, flag)));
  DUAL(
    (k_tne_node<float><<<NN, 128, 0, stream>>>(offsets, csr, gV, eabuf,
        (const float*)d_in[19], (const float*)d_in[20], (const float*)d_in[14],
        (const float*)d_in[15], (const float*)d_in[16], (const float*)d_in[17], (const float*)d_in[18], X9, flag)),
    (k_tne_node<bf16 ><<<NN, 128, 0, stream>>>(offsets, csr, gV, eabuf,
        (const bf16* )d_in[19], (const bf16* )d_in[20], (const bf16* )d_in[14],
        (const bf16* )d_in[15], (const bf16* )d_in[16], (const bf16* )d_in[17], (const bf16* )d_in[18], X9, flag)));

  for (int l=0; l<2; ++l){
    size_t o0w = (size_t)l*32*128,  o0b = (size_t)l*128;
    size_t o1w = (size_t)l*128*256, o1b = (size_t)l*256;
    size_t o2w = (size_t)l*256*384, o2b = (size_t)l*384;
    size_t oxt = (size_t)l*3*128*128;
    // 1) MFMA candidate
    DUAL(
      (k_msg_edge_mfma<float><<<NE/32, 128, 0, stream>>>(eattr_c, gC, pw0[l], pw1[l], pw2[l],
          (const float*)d_in[22]+o0b, (const float*)d_in[24]+o1b, (const float*)d_in[26]+o2b,
          (unsigned short*)eabuf, flag)),
      (k_msg_edge_mfma<bf16 ><<<NE/32, 128, 0, stream>>>(eattr_c, gC, pw0[l], pw1[l], pw2[l],
          (const bf16* )d_in[22]+o0b, (const bf16* )d_in[24]+o1b, (const bf16* )d_in[26]+o2b,
          (unsigned short*)eabuf, flag)));
    // 2) scalar sample (proven path) -> esamp
    DUAL(
      (k_msg_edge_scalar<float><<<32, 128, 0, stream>>>((const float*)d_in[4], gC,
          (const float*)d_in[21]+o0w, (const float*)d_in[22]+o0b,
          (const float*)d_in[23]+o1w, (const float*)d_in[24]+o1b,
          (const float*)d_in[25]+o2w, (const float*)d_in[26]+o2b, esamp, ok+l, 0, flag)),
      (k_msg_edge_scalar<bf16 ><<<32, 128, 0, stream>>>((const bf16* )d_in[4], gC,
          (const bf16* )d_in[21]+o0w, (const bf16* )d_in[22]+o0b,
          (const bf16* )d_in[23]+o1w, (const bf16* )d_in[24]+o1b,
          (const bf16* )d_in[25]+o2w, (const bf16* )d_in[26]+o2b, esamp, ok+l, 0, flag)));
    // 3) validate
    k_cmp<<<768, 256, 0, stream>>>(eabuf, esamp, ok+l);
    k_finite<<<6144, 256, 0, stream>>>((const unsigned short*)eabuf, ok+l);
    // 4) guarded full scalar fallback (skips if validated)
    DUAL(
      (k_msg_edge_scalar<float><<<NE/EPB, 128, 0, stream>>>((const float*)d_in[4], gC,
          (const float*)d_in[21]+o0w, (const float*)d_in[22]+o0b,
          (const float*)d_in[23]+o1w, (const float*)d_in[24]+o1b,
          (const float*)d_in[25]+o2w, (const float*)d_in[26]+o2b, eabuf, ok+l, 1, flag)),
      (k_msg_edge_scalar<bf16 ><<<NE/EPB, 128, 0, stream>>>((const bf16* )d_in[4], gC,
          (const bf16* )d_in[21]+o0w, (const bf16* )d_in[22]+o0b,
          (const bf16* )d_in[23]+o1w, (const bf16* )d_in[24]+o1b,
          (const bf16* )d_in[25]+o2w, (const bf16* )d_in[26]+o2b, eabuf, ok+l, 1, flag)));
    // 5) rest of layer
    DUAL(
      (k_msg_prep<float><<<NN/4, 128, 0, stream>>>(X9, (const float*)d_in[27]+oxt, Y10, flag)),
      (k_msg_prep<bf16 ><<<NN/4, 128, 0, stream>>>(X9, (const bf16* )d_in[27]+oxt, Y10, flag)));
    DUAL(
      (k_msg_sf<float><<<NN, 128, 0, stream>>>(offsets, csr, src, eabuf, Y10,
          (const float*)d_in[28]+oxt, X9, d_out, flag, (l==1)?1:0)),
      (k_msg_sf<bf16 ><<<NN, 128, 0, stream>>>(offsets, csr, src, eabuf, Y10,
          (const bf16* )d_in[28]+oxt, X9, d_out, flag, (l==1)?1:0)));
  }
  #undef DUAL
}

// Round 11
// 495.941 us; speedup vs baseline: 1.4485x; 1.3724x over previous
//
#include <hip/hip_runtime.h>
#include <hip/hip_bf16.h>

typedef __hip_bfloat16 bf16;
typedef __attribute__((ext_vector_type(8))) short short8v;   // 8 bf16 = 4 VGPRs (MFMA A/B frag)
typedef __attribute__((ext_vector_type(4))) float f32x4;     // MFMA C/D frag

#define NN 4096
#define NE 32768
#define HH 128
#define MAXZ 100
#define TPB 8    // edges per block, TNE edge kernel

// ENVIRONMENT FACTS (r0-r10): device float tensors are FLOAT32; detector+dual kept
// as insurance. MFMA msg-edge path hardware-validated r10 (absmax shifted => used).

__device__ __forceinline__ float b2f(bf16 v){ return __bfloat162float(v); }
__device__ __forceinline__ float ldf(const float* p, size_t i){ return p[i]; }
__device__ __forceinline__ float ldf(const bf16*  p, size_t i){ return __bfloat162float(p[i]); }
__device__ __forceinline__ float siluf(float x){ return x / (1.0f + __expf(-x)); }
__device__ __forceinline__ unsigned short f2bu(float x){
  bf16 h = __float2bfloat16(x);
  return *reinterpret_cast<unsigned short*>(&h);
}

// dtype detect: flag[0]=1 if float inputs are f32, 0 if bf16.
__global__ void __launch_bounds__(256) k_detect(const unsigned int* __restrict__ w, int* __restrict__ flag){
  __shared__ int cnt[256];
  int t = threadIdx.x;
  int c = 0;
  for (int i = t; i < 4096; i += 256){
    unsigned int lo = w[i] & 0xffffu;
    int e = (int)((lo >> 7) & 0xffu);
    c += (e >= 110 && e <= 132) ? 1 : 0;
  }
  cnt[t] = c; __syncthreads();
  for (int off=128; off>=1; off>>=1){ if (t<off) cnt[t]+=cnt[t+off]; __syncthreads(); }
  if (t==0) flag[0] = (cnt[0] < 2048) ? 1 : 0;
}

// ---------------- CSR build ----------------
__global__ void __launch_bounds__(256) k_count(const int* __restrict__ dst, int* __restrict__ counts){
  int e = blockIdx.x*256 + threadIdx.x;
  if (e < NE) atomicAdd(&counts[dst[e]], 1);
}

__global__ void __launch_bounds__(1024) k_scan(const int* __restrict__ counts, int* __restrict__ offsets, int* __restrict__ cursor){
  __shared__ int lds[1024];
  int t = threadIdx.x;
  int c0 = counts[4*t+0], c1 = counts[4*t+1], c2 = counts[4*t+2], c3 = counts[4*t+3];
  int s1 = c0+c1, s2 = s1+c2, s3 = s2+c3;
  lds[t] = s3;
  __syncthreads();
  for (int off=1; off<1024; off<<=1){
    int v = lds[t];
    int add = (t>=off)? lds[t-off] : 0;
    __syncthreads();
    lds[t] = v + add;
    __syncthreads();
  }
  int incl = lds[t];
  int base = incl - s3;
  offsets[4*t+0]=base;    offsets[4*t+1]=base+c0; offsets[4*t+2]=base+s1; offsets[4*t+3]=base+s2;
  cursor [4*t+0]=base;    cursor [4*t+1]=base+c0; cursor [4*t+2]=base+s1; cursor [4*t+3]=base+s2;
  if (t==1023) offsets[4096]=incl;
}

__global__ void __launch_bounds__(256) k_fill(const int* __restrict__ dst, int* __restrict__ cursor, int* __restrict__ csr){
  int e = blockIdx.x*256 + threadIdx.x;
  if (e < NE){ int p = atomicAdd(&cursor[dst[e]], 1); csr[p] = e; }
}

// ---------------- edge geometry ----------------
template<typename T>
__global__ void __launch_bounds__(256) k_geom(const T* __restrict__ ew, const T* __restrict__ evec,
                       const int* __restrict__ src, const int* __restrict__ dst,
                       float* __restrict__ gC, float* __restrict__ gV, const int* __restrict__ flag){
  if (flag[0] != (int)(sizeof(T)==4)) return;
  int e = blockIdx.x*256 + threadIdx.x;
  if (e >= NE) return;
  float d = ldf(ew, e);
  float c = 0.5f*(cosf(d*0.6283185307179586f)+1.0f);
  c = (d < 5.0f) ? c : 0.0f;
  gC[e] = c;
  float x = ldf(evec, (size_t)e*3+0), y = ldf(evec, (size_t)e*3+1), z = ldf(evec, (size_t)e*3+2);
  if (src[e] != dst[e]){
    float n = sqrtf(x*x+y*y+z*z);
    float inv = 1.0f/fmaxf(n, 1e-12f);
    x*=inv; y*=inv; z*=inv;
  }
  gV[e*3+0]=x; gV[e*3+1]=y; gV[e*3+2]=z;
}

// ---------------- per-z embedding products ----------------
template<typename T>
__global__ void __launch_bounds__(128) k_zemb(const T* __restrict__ emb, const T* __restrict__ emb2_w,
                      float* __restrict__ P1z, float* __restrict__ P2z, const int* __restrict__ flag){
  if (flag[0] != (int)(sizeof(T)==4)) return;
  int zv = blockIdx.x, h = threadIdx.x;
  __shared__ float Zr[128];
  Zr[h] = ldf(emb, (size_t)zv*HH + h);
  __syncthreads();
  float p1=0.f, p2=0.f;
  for (int r=0;r<128;++r){
    float x = Zr[r];
    p1 += x*ldf(emb2_w, (size_t)r*HH+h);
    p2 += x*ldf(emb2_w, (size_t)(r+128)*HH+h);
  }
  P1z[zv*HH+h]=p1; P2z[zv*HH+h]=p2;
}

// ---------------- convert edge_attr -> bf16 buffer ----------------
template<typename T>
__global__ void __launch_bounds__(256) k_cvt_attr(const T* __restrict__ in, unsigned short* __restrict__ out,
                                                  const int* __restrict__ flag){
  if (flag[0] != (int)(sizeof(T)==4)) return;
  int i = blockIdx.x*256 + threadIdx.x;   // NE*32 = 1048576 elements
  out[i] = f2bu(ldf(in, (size_t)i));
}

// ---------------- weight repack into MFMA B-fragment layout (bf16 out) ----------------
struct PackDescs {
  const void*     W[6];
  unsigned short* out[6];
  int K[6]; int N[6];
};
template<typename T>
__global__ void __launch_bounds__(256) k_pack(PackDescs d, const int* __restrict__ flag){
  if (flag[0] != (int)(sizeof(T)==4)) return;
  int y = blockIdx.y;
  int K = d.K[y], N = d.N[y];
  int ktiles = K>>5, ntiles = N>>4;
  int total = ktiles*ntiles*64;
  int idx = blockIdx.x*256 + threadIdx.x;
  if (idx >= total) return;
  int lane = idx & 63, tile = idx >> 6;
  int kt = tile % ktiles, nt = tile / ktiles;
  const T* W = (const T*)d.W[y];
  int n = nt*16 + (lane&15), k0 = kt*32 + (lane>>4)*8;
  unsigned int t[8];
  #pragma unroll
  for (int j=0;j<8;++j) t[j] = f2bu(ldf(W, (size_t)(k0+j)*N + n));
  uint4 v;
  v.x = t[0] | (t[1]<<16);
  v.y = t[2] | (t[3]<<16);
  v.z = t[4] | (t[5]<<16);
  v.w = t[6] | (t[7]<<16);
  *reinterpret_cast<uint4*>(d.out[y] + ((size_t)tile*64 + lane)*8) = v;
}

// ---------------- TNE edge coefficients -> eabuf bf16 [E][3][128] ----------------
template<typename T>
__global__ void __launch_bounds__(128) k_tne_edge(
  const T* __restrict__ eattr, const int* __restrict__ src, const int* __restrict__ dst,
  const int* __restrict__ z,
  const T* __restrict__ dp1_w, const T* __restrict__ dp1_b,
  const T* __restrict__ dp2_w, const T* __restrict__ dp2_b,
  const T* __restrict__ dp3_w, const T* __restrict__ dp3_b,
  const T* __restrict__ emb2_b, const float* __restrict__ P1z, const float* __restrict__ P2z,
  const float* __restrict__ gC, bf16* __restrict__ eabuf, const int* __restrict__ flag)
{
  if (flag[0] != (int)(sizeof(T)==4)) return;
  int e0 = blockIdx.x*TPB;
  int h  = threadIdx.x;
  __shared__ float attr[TPB][32];
  __shared__ int zd[TPB], zs[TPB];
  for (int i=h; i<TPB*32; i+=128) attr[i>>5][i&31] = ldf(eattr, (size_t)e0*32 + i);
  if (h < TPB){ int e=e0+h; zd[h]=z[dst[e]]; zs[h]=z[src[e]]; }
  __syncthreads();
  float w1[TPB], w2[TPB], w3[TPB];
  float b1v=ldf(dp1_b,h), b2v=ldf(dp2_b,h), b3v=ldf(dp3_b,h);
  #pragma unroll
  for (int e=0;e<TPB;++e){ w1[e]=b1v; w2[e]=b2v; w3[e]=b3v; }
  for (int r=0;r<32;++r){
    float u1=ldf(dp1_w,(size_t)r*HH+h), u2=ldf(dp2_w,(size_t)r*HH+h), u3=ldf(dp3_w,(size_t)r*HH+h);
    #pragma unroll
    for (int e=0;e<TPB;++e){ float a=attr[e][r]; w1[e]+=a*u1; w2[e]+=a*u2; w3[e]+=a*u3; }
  }
  float eb = ldf(emb2_b,h);
  #pragma unroll
  for (int e=0;e<TPB;++e){
    float zij = P1z[zd[e]*HH+h] + P2z[zs[e]*HH+h] + eb;
    float c = gC[e0+e];
    bf16* p = eabuf + (size_t)(e0+e)*384;
    p[h]     = __float2bfloat16(zij*w1[e]*c);
    p[128+h] = __float2bfloat16(zij*w2[e]*c);
    p[256+h] = __float2bfloat16(zij*w3[e]*c);
  }
}

// ---------------- TNE node: 4 nodes/block (weight loads amortized 4x) ----------------
template<typename T>
__global__ void __launch_bounds__(128) k_tne_node(
  const int* __restrict__ offsets, const int* __restrict__ csr,
  const float* __restrict__ gV, const bf16* __restrict__ eabuf,
  const T* __restrict__ ln_g, const T* __restrict__ ln_b,
  const T* __restrict__ tne_lt,
  const T* __restrict__ s0_w, const T* __restrict__ s0_b,
  const T* __restrict__ s1_w, const T* __restrict__ s1_b,
  float* __restrict__ X9, const int* __restrict__ flag)
{
  if (flag[0] != (int)(sizeof(T)==4)) return;
  int n0 = blockIdx.x*4, h = threadIdx.x;
  __shared__ float sm[4][10][128];
  __shared__ float red[128];
  __shared__ float lnv[4][128];
  __shared__ float h1s[4][256];
  float tnv[4];
  #pragma unroll
  for (int nn=0;nn<4;++nn){
    int n = n0+nn;
    float a=0, v0=0,v1=0,v2=0, s0=0,s1=0,s2=0,s3=0,s4=0,s5=0;
    int beg = offsets[n], end = offsets[n+1];
    for (int i=beg;i<end;++i){
      int e = csr[i];
      const bf16* p = eabuf + (size_t)e*384;
      float c1 = b2f(p[h]), c2 = b2f(p[128+h]), c3 = b2f(p[256+h]);
      float vx = gV[e*3+0], vy = gV[e*3+1], vz = gV[e*3+2];
      float tr3 = (vx*vx+vy*vy+vz*vz)*(1.0f/3.0f);
      a  += c1;
      v0 += c2*vx; v1 += c2*vy; v2 += c2*vz;
      s0 += c3*(vx*vx - tr3); s1 += c3*vx*vy;          s2 += c3*vx*vz;
      s3 += c3*(vy*vy - tr3); s4 += c3*vy*vz;          s5 += c3*(vz*vz - tr3);
    }
    sm[nn][0][h]=a; sm[nn][1][h]=v0; sm[nn][2][h]=v1; sm[nn][3][h]=v2;
    sm[nn][4][h]=s0; sm[nn][5][h]=s1; sm[nn][6][h]=s2; sm[nn][7][h]=s3; sm[nn][8][h]=s4; sm[nn][9][h]=s5;
    tnv[nn] = 3.0f*a*a + 2.0f*(v0*v0+v1*v1+v2*v2)
            + s0*s0 + s3*s3 + s5*s5 + 2.0f*(s1*s1 + s2*s2 + s4*s4);
  }
  // LayerNorm per node (reductions over h)
  float gg = ldf(ln_g,h), bb = ldf(ln_b,h);
  #pragma unroll
  for (int nn=0;nn<4;++nn){
    __syncthreads();
    red[h] = tnv[nn]; __syncthreads();
    for (int off=64; off>=1; off>>=1){ if (h<off) red[h]+=red[h+off]; __syncthreads(); }
    float mean = red[0]*(1.0f/128.0f);
    __syncthreads();
    float dm = tnv[nn] - mean;
    red[h] = dm*dm; __syncthreads();
    for (int off=64; off>=1; off>>=1){ if (h<off) red[h]+=red[h+off]; __syncthreads(); }
    float var = red[0]*(1.0f/128.0f);
    lnv[nn][h] = dm*rsqrtf(var+1e-5f)*gg + bb;
  }
  __syncthreads();
  // fsc MLP stage 1: 128 -> 256 (cols 2h, 2h+1), 4 nodes per weight load
  {
    float ba = ldf(s0_b,2*h), bc = ldf(s0_b,2*h+1);
    float a0[4], a1[4];
    #pragma unroll
    for (int nn=0;nn<4;++nn){ a0[nn]=ba; a1[nn]=bc; }
    for (int r=0;r<128;++r){
      float u0 = ldf(s0_w,(size_t)r*256+2*h), u1 = ldf(s0_w,(size_t)r*256+2*h+1);
      #pragma unroll
      for (int nn=0;nn<4;++nn){ float x = lnv[nn][r]; a0[nn]+=x*u0; a1[nn]+=x*u1; }
    }
    #pragma unroll
    for (int nn=0;nn<4;++nn){ h1s[nn][2*h] = siluf(a0[nn]); h1s[nn][2*h+1] = siluf(a1[nn]); }
  }
  __syncthreads();
  // fsc MLP stage 2: 256 -> 384 (cols 3h..3h+2)
  float f0[4], f1[4], f2[4];
  {
    float b0 = ldf(s1_b,3*h), b1 = ldf(s1_b,3*h+1), b2 = ldf(s1_b,3*h+2);
    #pragma unroll
    for (int nn=0;nn<4;++nn){ f0[nn]=b0; f1[nn]=b1; f2[nn]=b2; }
    for (int r=0;r<256;++r){
      float u0 = ldf(s1_w,(size_t)r*384+3*h), u1 = ldf(s1_w,(size_t)r*384+3*h+1), u2 = ldf(s1_w,(size_t)r*384+3*h+2);
      #pragma unroll
      for (int nn=0;nn<4;++nn){ float x = h1s[nn][r]; f0[nn]+=x*u0; f1[nn]+=x*u1; f2[nn]+=x*u2; }
    }
    #pragma unroll
    for (int nn=0;nn<4;++nn){ f0[nn]=siluf(f0[nn]); f1[nn]=siluf(f1[nn]); f2[nn]=siluf(f2[nn]); }
  }
  // cmix batched over 4 nodes
  float am[4]={0,0,0,0};
  float wm0[4]={0,0,0,0}, wm1[4]={0,0,0,0}, wm2[4]={0,0,0,0};
  float t0[4]={0,0,0,0}, t1[4]={0,0,0,0}, t2[4]={0,0,0,0};
  float t3[4]={0,0,0,0}, t4[4]={0,0,0,0}, t5[4]={0,0,0,0};
  for (int r=0;r<128;++r){
    float w0 = ldf(tne_lt,(size_t)r*128+h);
    float w1 = ldf(tne_lt,(size_t)16384+r*128+h);
    float w2 = ldf(tne_lt,(size_t)32768+r*128+h);
    #pragma unroll
    for (int nn=0;nn<4;++nn){
      am[nn]  += sm[nn][0][r]*w0;
      wm0[nn] += sm[nn][1][r]*w1; wm1[nn] += sm[nn][2][r]*w1; wm2[nn] += sm[nn][3][r]*w1;
      t0[nn] += sm[nn][4][r]*w2; t1[nn] += sm[nn][5][r]*w2; t2[nn] += sm[nn][6][r]*w2;
      t3[nn] += sm[nn][7][r]*w2; t4[nn] += sm[nn][8][r]*w2; t5[nn] += sm[nn][9][r]*w2;
    }
  }
  #pragma unroll
  for (int nn=0;nn<4;++nn){
    float x00 = f0[nn]*am[nn] + f2[nn]*t0[nn];
    float x01 = -f1[nn]*wm2[nn] + f2[nn]*t1[nn];
    float x02 =  f1[nn]*wm1[nn] + f2[nn]*t2[nn];
    float x10 =  f1[nn]*wm2[nn] + f2[nn]*t1[nn];
    float x11 = f0[nn]*am[nn] + f2[nn]*t3[nn];
    float x12 = -f1[nn]*wm0[nn] + f2[nn]*t4[nn];
    float x20 = -f1[nn]*wm1[nn] + f2[nn]*t2[nn];
    float x21 =  f1[nn]*wm0[nn] + f2[nn]*t4[nn];
    float x22 = f0[nn]*am[nn] + f2[nn]*t5[nn];
    float* xp = X9 + (size_t)(n0+nn)*1152;
    xp[0*128+h]=x00; xp[1*128+h]=x01; xp[2*128+h]=x02;
    xp[3*128+h]=x10; xp[4*128+h]=x11; xp[5*128+h]=x12;
    xp[6*128+h]=x20; xp[7*128+h]=x21; xp[8*128+h]=x22;
  }
}

// ---------------- msg edge MLP via MFMA (r10-validated, byte-identical) ----------------
template<typename T>
__global__ void __launch_bounds__(128) k_msg_edge_mfma(
  const unsigned short* __restrict__ eattr_c, const float* __restrict__ gC,
  const unsigned short* __restrict__ p0, const unsigned short* __restrict__ p1,
  const unsigned short* __restrict__ p2,
  const T* __restrict__ b0, const T* __restrict__ b1, const T* __restrict__ b2,
  unsigned short* __restrict__ eabuf, const int* __restrict__ flag)
{
  if (flag[0] != (int)(sizeof(T)==4)) return;
  int wid  = threadIdx.x >> 6;
  int lane = threadIdx.x & 63;
  int e0 = blockIdx.x*32 + wid*16;
  int m = lane & 15, g = lane >> 4;
  __shared__ __align__(16) unsigned short h1p[2][2048];
  __shared__ __align__(16) unsigned short h2p[2][4096];
  float cc[4];
  #pragma unroll
  for (int r=0;r<4;++r) cc[r] = gC[e0 + g*4 + r];
  short8v a1 = *reinterpret_cast<const short8v*>(eattr_c + (size_t)(e0+m)*32 + g*8);
  #pragma unroll
  for (int nt=0; nt<8; ++nt){
    float bias = ldf(b0, nt*16+m);
    f32x4 acc = {bias,bias,bias,bias};
    short8v b = *reinterpret_cast<const short8v*>(p0 + ((size_t)nt*64 + lane)*8);
    acc = __builtin_amdgcn_mfma_f32_16x16x32_bf16(a1, b, acc, 0,0,0);
    #pragma unroll
    for (int r=0;r<4;++r){
      int n = nt*16 + m, row = g*4 + r;
      h1p[wid][(n>>5)*512 + (((n>>3)&3)*16+row)*8 + (n&7)] = f2bu(siluf(acc[r]));
    }
  }
  __syncthreads();
  short8v a2[4];
  #pragma unroll
  for (int ks=0; ks<4; ++ks) a2[ks] = *reinterpret_cast<const short8v*>(&h1p[wid][ks*512 + lane*8]);
  for (int nt=0; nt<16; ++nt){
    float bias = ldf(b1, nt*16+m);
    f32x4 acc = {bias,bias,bias,bias};
    #pragma unroll
    for (int ks=0; ks<4; ++ks){
      short8v b = *reinterpret_cast<const short8v*>(p1 + ((size_t)(nt*4+ks)*64 + lane)*8);
      acc = __builtin_amdgcn_mfma_f32_16x16x32_bf16(a2[ks], b, acc, 0,0,0);
    }
    #pragma unroll
    for (int r=0;r<4;++r){
      int n = nt*16 + m, row = g*4 + r;
      h2p[wid][(n>>5)*512 + (((n>>3)&3)*16+row)*8 + (n&7)] = f2bu(siluf(acc[r]));
    }
  }
  __syncthreads();
  short8v a3[8];
  #pragma unroll
  for (int ks=0; ks<8; ++ks) a3[ks] = *reinterpret_cast<const short8v*>(&h2p[wid][ks*512 + lane*8]);
  for (int nt=0; nt<24; ++nt){
    float bias = ldf(b2, nt*16+m);
    f32x4 acc = {bias,bias,bias,bias};
    #pragma unroll
    for (int ks=0; ks<8; ++ks){
      short8v b = *reinterpret_cast<const short8v*>(p2 + ((size_t)(nt*8+ks)*64 + lane)*8);
      acc = __builtin_amdgcn_mfma_f32_16x16x32_bf16(a3[ks], b, acc, 0,0,0);
    }
    #pragma unroll
    for (int r=0;r<4;++r){
      int n = nt*16 + m, row = g*4 + r;
      float v = siluf(acc[r]) * cc[r];
      eabuf[(size_t)(e0+row)*384 + (n%3)*128 + (n/3)] = f2bu(v);
    }
  }
}

// ---------------- msg node prep (4 nodes/block) ----------------
template<typename T>
__global__ void __launch_bounds__(128) k_msg_prep(
  float* __restrict__ X9, const T* __restrict__ lx, bf16* __restrict__ Y10,
  const int* __restrict__ flag)
{
  if (flag[0] != (int)(sizeof(T)==4)) return;
  int n0 = blockIdx.x*4, h = threadIdx.x;
  __shared__ float sm[4][10][128];
  #pragma unroll
  for (int nn=0;nn<4;++nn){
    float* xp = X9 + (size_t)(n0+nn)*1152;
    float x00=xp[0*128+h], x01=xp[1*128+h], x02=xp[2*128+h];
    float x10=xp[3*128+h], x11=xp[4*128+h], x12=xp[5*128+h];
    float x20=xp[6*128+h], x21=xp[7*128+h], x22=xp[8*128+h];
    float tn = x00*x00+x01*x01+x02*x02+x10*x10+x11*x11+x12*x12+x20*x20+x21*x21+x22*x22;
    float inv = 1.0f/(tn+1.0f);
    x00*=inv; x01*=inv; x02*=inv; x10*=inv; x11*=inv; x12*=inv; x20*=inv; x21*=inv; x22*=inv;
    // Reference REBINDS X to normalized before the update.
    xp[0*128+h]=x00; xp[1*128+h]=x01; xp[2*128+h]=x02;
    xp[3*128+h]=x10; xp[4*128+h]=x11; xp[5*128+h]=x12;
    xp[6*128+h]=x20; xp[7*128+h]=x21; xp[8*128+h]=x22;
    float a = (x00+x11+x22)*(1.0f/3.0f);
    sm[nn][0][h]=a;
    sm[nn][1][h]=0.5f*(x21-x12);
    sm[nn][2][h]=0.5f*(x02-x20);
    sm[nn][3][h]=0.5f*(x10-x01);
    sm[nn][4][h]=x00-a;
    sm[nn][5][h]=0.5f*(x01+x10);
    sm[nn][6][h]=0.5f*(x02+x20);
    sm[nn][7][h]=x11-a;
    sm[nn][8][h]=0.5f*(x12+x21);
    sm[nn][9][h]=x22-a;
  }
  __syncthreads();
  float A[4]={0,0,0,0};
  float V0[4]={0,0,0,0}, V1[4]={0,0,0,0}, V2[4]={0,0,0,0};
  float S0[4]={0,0,0,0}, S1[4]={0,0,0,0}, S2[4]={0,0,0,0};
  float S3[4]={0,0,0,0}, S4[4]={0,0,0,0}, S5[4]={0,0,0,0};
  for (int r=0;r<128;++r){
    float w0 = ldf(lx,(size_t)r*128+h), w1 = ldf(lx,(size_t)16384+r*128+h), w2 = ldf(lx,(size_t)32768+r*128+h);
    #pragma unroll
    for (int nn=0;nn<4;++nn){
      A[nn]  += sm[nn][0][r]*w0;
      V0[nn] += sm[nn][1][r]*w1; V1[nn] += sm[nn][2][r]*w1; V2[nn] += sm[nn][3][r]*w1;
      S0[nn] += sm[nn][4][r]*w2; S1[nn] += sm[nn][5][r]*w2; S2[nn] += sm[nn][6][r]*w2;
      S3[nn] += sm[nn][7][r]*w2; S4[nn] += sm[nn][8][r]*w2; S5[nn] += sm[nn][9][r]*w2;
    }
  }
  #pragma unroll
  for (int nn=0;nn<4;++nn){
    bf16* yp = Y10 + (size_t)(n0+nn)*1280;
    yp[0*128+h]=__float2bfloat16(A[nn]);
    yp[1*128+h]=__float2bfloat16(V0[nn]); yp[2*128+h]=__float2bfloat16(V1[nn]); yp[3*128+h]=__float2bfloat16(V2[nn]);
    yp[4*128+h]=__float2bfloat16(S0[nn]); yp[5*128+h]=__float2bfloat16(S1[nn]); yp[6*128+h]=__float2bfloat16(S2[nn]);
    yp[7*128+h]=__float2bfloat16(S3[nn]); yp[8*128+h]=__float2bfloat16(S4[nn]); yp[9*128+h]=__float2bfloat16(S5[nn]);
  }
}

// ---------------- msg scatter+AB+decompose + 4-node-batched lt cmix + dX update ----------------
template<typename T>
__global__ void __launch_bounds__(128) k_msg_sf(
  const int* __restrict__ offsets, const int* __restrict__ csr, const int* __restrict__ srcA,
  const bf16* __restrict__ eabuf, const bf16* __restrict__ Y10, const T* __restrict__ lt,
  float* __restrict__ X9, void* __restrict__ out, const int* __restrict__ flag, int write_out)
{
  if (flag[0] != (int)(sizeof(T)==4)) return;
  int n0 = blockIdx.x*4, h = threadIdx.x;
  __shared__ float sm[4][10][128];
  #pragma unroll
  for (int nn=0;nn<4;++nn){
    int n = n0+nn;
    float am=0, vm0=0,vm1=0,vm2=0, smm0=0,smm1=0,smm2=0,smm3=0,smm4=0,smm5=0;
    int beg = offsets[n], end = offsets[n+1];
    for (int i=beg;i<end;++i){
      int e = csr[i]; int s = srcA[e];
      const bf16* ep = eabuf + (size_t)e*384;
      float e0 = b2f(ep[h]), e1 = b2f(ep[128+h]), e2 = b2f(ep[256+h]);
      const bf16* yp = Y10 + (size_t)s*1280;
      am   += e0*b2f(yp[0*128+h]);
      vm0  += e1*b2f(yp[1*128+h]); vm1 += e1*b2f(yp[2*128+h]); vm2 += e1*b2f(yp[3*128+h]);
      smm0 += e2*b2f(yp[4*128+h]); smm1 += e2*b2f(yp[5*128+h]); smm2 += e2*b2f(yp[6*128+h]);
      smm3 += e2*b2f(yp[7*128+h]); smm4 += e2*b2f(yp[8*128+h]); smm5 += e2*b2f(yp[9*128+h]);
    }
    const bf16* yp = Y10 + (size_t)n*1280;
    float aY=b2f(yp[0*128+h]), u0=b2f(yp[1*128+h]), u1=b2f(yp[2*128+h]), u2=b2f(yp[3*128+h]);
    float q0=b2f(yp[4*128+h]), q1=b2f(yp[5*128+h]), q2=b2f(yp[6*128+h]);
    float q3=b2f(yp[7*128+h]), q4=b2f(yp[8*128+h]), q5=b2f(yp[9*128+h]);
    float m00=am+smm0,   m01=-vm2+smm1, m02= vm1+smm2;
    float m10= vm2+smm1, m11=am+smm3,  m12=-vm0+smm4;
    float m20=-vm1+smm2, m21= vm0+smm4, m22=am+smm5;
    float y00=aY+q0,  y01=-u2+q1, y02= u1+q2;
    float y10= u2+q1, y11=aY+q3,  y12=-u0+q4;
    float y20=-u1+q2, y21= u0+q4, y22=aY+q5;
    float ab00 = m00*y00+m01*y10+m02*y20 + y00*m00+y01*m10+y02*m20;
    float ab01 = m00*y01+m01*y11+m02*y21 + y00*m01+y01*m11+y02*m21;
    float ab02 = m00*y02+m01*y12+m02*y22 + y00*m02+y01*m12+y02*m22;
    float ab10 = m10*y00+m11*y10+m12*y20 + y10*m00+y11*m10+y12*m20;
    float ab11 = m10*y01+m11*y11+m12*y21 + y10*m01+y11*m11+y12*m21;
    float ab12 = m10*y02+m11*y12+m12*y22 + y10*m02+y11*m12+y12*m22;
    float ab20 = m20*y00+m21*y10+m22*y20 + y20*m00+y21*m10+y22*m20;
    float ab21 = m20*y01+m21*y11+m22*y21 + y20*m01+y21*m11+y22*m21;
    float ab22 = m20*y02+m21*y12+m22*y22 + y20*m02+y21*m12+y22*m22;
    float a2 = (ab00+ab11+ab22)*(1.0f/3.0f);
    float w0 = 0.5f*(ab21-ab12), w1 = 0.5f*(ab02-ab20), w2 = 0.5f*(ab10-ab01);
    float t0 = ab00-a2, t1 = 0.5f*(ab01+ab10), t2 = 0.5f*(ab02+ab20);
    float t3 = ab11-a2, t4 = 0.5f*(ab12+ab21), t5 = ab22-a2;
    float dnm = ab00*ab00+ab01*ab01+ab02*ab02+ab10*ab10+ab11*ab11+ab12*ab12
              + ab20*ab20+ab21*ab21+ab22*ab22 + 1.0f;
    float inv = 1.0f/dnm;
    sm[nn][0][h]=a2*inv; sm[nn][1][h]=w0*inv; sm[nn][2][h]=w1*inv; sm[nn][3][h]=w2*inv;
    sm[nn][4][h]=t0*inv; sm[nn][5][h]=t1*inv; sm[nn][6][h]=t2*inv;
    sm[nn][7][h]=t3*inv; sm[nn][8][h]=t4*inv; sm[nn][9][h]=t5*inv;
  }
  __syncthreads();
  float at[4]={0,0,0,0};
  float vt0[4]={0,0,0,0}, vt1[4]={0,0,0,0}, vt2[4]={0,0,0,0};
  float st0[4]={0,0,0,0}, st1[4]={0,0,0,0}, st2[4]={0,0,0,0};
  float st3[4]={0,0,0,0}, st4[4]={0,0,0,0}, st5[4]={0,0,0,0};
  for (int r=0;r<128;++r){
    float ww0 = ldf(lt,(size_t)r*128+h);
    float ww1 = ldf(lt,(size_t)16384+r*128+h);
    float ww2 = ldf(lt,(size_t)32768+r*128+h);
    #pragma unroll
    for (int nn=0;nn<4;++nn){
      at[nn]  += sm[nn][0][r]*ww0;
      vt0[nn] += sm[nn][1][r]*ww1; vt1[nn] += sm[nn][2][r]*ww1; vt2[nn] += sm[nn][3][r]*ww1;
      st0[nn] += sm[nn][4][r]*ww2; st1[nn] += sm[nn][5][r]*ww2; st2[nn] += sm[nn][6][r]*ww2;
      st3[nn] += sm[nn][7][r]*ww2; st4[nn] += sm[nn][8][r]*ww2; st5[nn] += sm[nn][9][r]*ww2;
    }
  }
  #pragma unroll
  for (int nn=0;nn<4;++nn){
    int n = n0+nn;
    float d00=at[nn]+st0[nn],   d01=-vt2[nn]+st1[nn], d02= vt1[nn]+st2[nn];
    float d10= vt2[nn]+st1[nn], d11=at[nn]+st3[nn],  d12=-vt0[nn]+st4[nn];
    float d20=-vt1[nn]+st2[nn], d21= vt0[nn]+st4[nn], d22=at[nn]+st5[nn];
    float g00 = d00 + d00*d00+d01*d10+d02*d20;
    float g01 = d01 + d00*d01+d01*d11+d02*d21;
    float g02 = d02 + d00*d02+d01*d12+d02*d22;
    float g10 = d10 + d10*d00+d11*d10+d12*d20;
    float g11 = d11 + d10*d01+d11*d11+d12*d21;
    float g12 = d12 + d10*d02+d11*d12+d12*d22;
    float g20 = d20 + d20*d00+d21*d10+d22*d20;
    float g21 = d21 + d20*d01+d21*d11+d22*d21;
    float g22 = d22 + d20*d02+d21*d12+d22*d22;
    float* xp = X9 + (size_t)n*1152;
    float x00=xp[0*128+h]+g00, x01=xp[1*128+h]+g01, x02=xp[2*128+h]+g02;
    float x10=xp[3*128+h]+g10, x11=xp[4*128+h]+g11, x12=xp[5*128+h]+g12;
    float x20=xp[6*128+h]+g20, x21=xp[7*128+h]+g21, x22=xp[8*128+h]+g22;
    if (write_out){
      T* o = (T*)out + ((size_t)n*128 + h)*9;
      if (sizeof(T)==4){
        float* of = (float*)o;
        of[0]=x00; of[1]=x01; of[2]=x02; of[3]=x10; of[4]=x11; of[5]=x12; of[6]=x20; of[7]=x21; of[8]=x22;
      } else {
        bf16* ob = (bf16*)o;
        ob[0]=__float2bfloat16(x00); ob[1]=__float2bfloat16(x01); ob[2]=__float2bfloat16(x02);
        ob[3]=__float2bfloat16(x10); ob[4]=__float2bfloat16(x11); ob[5]=__float2bfloat16(x12);
        ob[6]=__float2bfloat16(x20); ob[7]=__float2bfloat16(x21); ob[8]=__float2bfloat16(x22);
      }
    } else {
      xp[0*128+h]=x00; xp[1*128+h]=x01; xp[2*128+h]=x02;
      xp[3*128+h]=x10; xp[4*128+h]=x11; xp[5*128+h]=x12;
      xp[6*128+h]=x20; xp[7*128+h]=x21; xp[8*128+h]=x22;
    }
  }
}

extern "C" void kernel_launch(void* const* d_in, const int* in_sizes, int n_in,
                              void* d_out, int out_size, void* d_ws, size_t ws_size,
                              hipStream_t stream)
{
  (void)in_sizes; (void)n_in; (void)out_size; (void)ws_size;
  const int* z    = (const int*)d_in[0];
  const int* eidx = (const int*)d_in[1];
  const int* src  = eidx;
  const int* dst  = eidx + NE;

  // Workspace: ~58 MiB (proven budget >= 74 MiB).
  char* w = (char*)d_ws;
  int* flag    = (int*)w;   w += 64;
  int* counts  = (int*)w;   w += (size_t)NN*4;
  int* offsets = (int*)w;   w += (size_t)(NN+1)*4 + 60;
  int* cursor  = (int*)w;   w += (size_t)NN*4;
  int* csr     = (int*)w;   w += (size_t)NE*4;
  float* gC    = (float*)w; w += (size_t)NE*4;
  float* gV    = (float*)w; w += (size_t)NE*12;
  float* P1z   = (float*)w; w += (size_t)MAXZ*HH*4;
  float* P2z   = (float*)w; w += (size_t)MAXZ*HH*4;
  bf16* eabuf  = (bf16*)w;  w += (size_t)NE*384*2;       // 25.17 MB
  float* X9    = (float*)w; w += (size_t)NN*1152*4;      // 18.87 MB
  bf16* Y10    = (bf16*)w;  w += (size_t)NN*1280*2;      // 10.49 MB
  unsigned short* eattr_c = (unsigned short*)w; w += (size_t)NE*32*2;   // 2.10 MB
  unsigned short* pw0[2]; unsigned short* pw1[2]; unsigned short* pw2[2];
  for (int l=0;l<2;++l){
    pw0[l] = (unsigned short*)w; w += 8*64*8*2;      //   8 KB
    pw1[l] = (unsigned short*)w; w += 64*64*8*2;     //  64 KB
    pw2[l] = (unsigned short*)w; w += 192*64*8*2;    // 192 KB
  }

  k_detect<<<1, 256, 0, stream>>>((const unsigned int*)d_in[4], flag);
  hipMemsetAsync(counts, 0, (size_t)NN*4, stream);
  k_count<<<NE/256, 256, 0, stream>>>(dst, counts);
  k_scan<<<1, 1024, 0, stream>>>(counts, offsets, cursor);
  k_fill<<<NE/256, 256, 0, stream>>>(dst, cursor, csr);

  #define DUAL(call_f32, call_bf16) do { call_f32; call_bf16; } while(0)

  DUAL(
    (k_geom<float><<<NE/256, 256, 0, stream>>>((const float*)d_in[2], (const float*)d_in[3], src, dst, gC, gV, flag)),
    (k_geom<bf16 ><<<NE/256, 256, 0, stream>>>((const bf16* )d_in[2], (const bf16* )d_in[3], src, dst, gC, gV, flag)));
  DUAL(
    (k_zemb<float><<<MAXZ, 128, 0, stream>>>((const float*)d_in[5], (const float*)d_in[12], P1z, P2z, flag)),
    (k_zemb<bf16 ><<<MAXZ, 128, 0, stream>>>((const bf16* )d_in[5], (const bf16* )d_in[12], P1z, P2z, flag)));
  DUAL(
    (k_cvt_attr<float><<<NE*32/256, 256, 0, stream>>>((const float*)d_in[4], eattr_c, flag)),
    (k_cvt_attr<bf16 ><<<NE*32/256, 256, 0, stream>>>((const bf16* )d_in[4], eattr_c, flag)));

  PackDescs pd;
  for (int l=0;l<2;++l){
    pd.W[l*3+0] = (const void*)((const float*)d_in[21] + (size_t)l*32*128);
    pd.W[l*3+1] = (const void*)((const float*)d_in[23] + (size_t)l*128*256);
    pd.W[l*3+2] = (const void*)((const float*)d_in[25] + (size_t)l*256*384);
    pd.out[l*3+0] = pw0[l]; pd.K[l*3+0]=32;  pd.N[l*3+0]=128;
    pd.out[l*3+1] = pw1[l]; pd.K[l*3+1]=128; pd.N[l*3+1]=256;
    pd.out[l*3+2] = pw2[l]; pd.K[l*3+2]=256; pd.N[l*3+2]=384;
  }
  PackDescs pdb = pd;
  for (int l=0;l<2;++l){
    pdb.W[l*3+0] = (const void*)((const bf16*)d_in[21] + (size_t)l*32*128);
    pdb.W[l*3+1] = (const void*)((const bf16*)d_in[23] + (size_t)l*128*256);
    pdb.W[l*3+2] = (const void*)((const bf16*)d_in[25] + (size_t)l*256*384);
  }
  DUAL(
    (k_pack<float><<<dim3(48, 6), 256, 0, stream>>>(pd,  flag)),
    (k_pack<bf16 ><<<dim3(48, 6), 256, 0, stream>>>(pdb, flag)));

  DUAL(
    (k_tne_edge<float><<<NE/TPB, 128, 0, stream>>>((const float*)d_in[4], src, dst, z,
        (const float*)d_in[6], (const float*)d_in[7], (const float*)d_in[8], (const float*)d_in[9],
        (const float*)d_in[10], (const float*)d_in[11], (const float*)d_in[13], P1z, P2z, gC, eabuf, flag)),
    (k_tne_edge<bf16 ><<<NE/TPB, 128, 0, stream>>>((const bf16* )d_in[4], src, dst, z,
        (const bf16* )d_in[6], (const bf16* )d_in[7], (const bf16* )d_in[8], (const bf16* )d_in[9],
        (const bf16* )d_in[10], (const bf16* )d_in[11], (const bf16* )d_in[13], P1z, P2z, gC, eabuf, flag)));
  DUAL(
    (k_tne_node<float><<<NN/4, 128, 0, stream>>>(offsets, csr, gV, eabuf,
        (const float*)d_in[19], (const float*)d_in[20], (const float*)d_in[14],
        (const float*)d_in[15], (const float*)d_in[16], (const float*)d_in[17], (const float*)d_in[18], X9, flag)),
    (k_tne_node<bf16 ><<<NN/4, 128, 0, stream>>>(offsets, csr, gV, eabuf,
        (const bf16* )d_in[19], (const bf16* )d_in[20], (const bf16* )d_in[14],
        (const bf16* )d_in[15], (const bf16* )d_in[16], (const bf16* )d_in[17], (const bf16* )d_in[18], X9, flag)));

  for (int l=0; l<2; ++l){
    size_t o0b = (size_t)l*128, o1b = (size_t)l*256, o2b = (size_t)l*384;
    size_t oxt = (size_t)l*3*128*128;
    DUAL(
      (k_msg_edge_mfma<float><<<NE/32, 128, 0, stream>>>(eattr_c, gC, pw0[l], pw1[l], pw2[l],
          (const float*)d_in[22]+o0b, (const float*)d_in[24]+o1b, (const float*)d_in[26]+o2b,
          (unsigned short*)eabuf, flag)),
      (k_msg_edge_mfma<bf16 ><<<NE/32, 128, 0, stream>>>(eattr_c, gC, pw0[l], pw1[l], pw2[l],
          (const bf16* )d_in[22]+o0b, (const bf16* )d_in[24]+o1b, (const bf16* )d_in[26]+o2b,
          (unsigned short*)eabuf, flag)));
    DUAL(
      (k_msg_prep<float><<<NN/4, 128, 0, stream>>>(X9, (const float*)d_in[27]+oxt, Y10, flag)),
      (k_msg_prep<bf16 ><<<NN/4, 128, 0, stream>>>(X9, (const bf16* )d_in[27]+oxt, Y10, flag)));
    DUAL(
      (k_msg_sf<float><<<NN/4, 128, 0, stream>>>(offsets, csr, src, eabuf, Y10,
          (const float*)d_in[28]+oxt, X9, d_out, flag, (l==1)?1:0)),
      (k_msg_sf<bf16 ><<<NN/4, 128, 0, stream>>>(offsets, csr, src, eabuf, Y10,
          (const bf16* )d_in[28]+oxt, X9, d_out, flag, (l==1)?1:0)));
  }
  #undef DUAL
}

// Round 12
// 458.847 us; speedup vs baseline: 1.5656x; 1.0808x over previous
//
#include <hip/hip_runtime.h>
#include <hip/hip_bf16.h>

typedef __hip_bfloat16 bf16;
typedef __attribute__((ext_vector_type(8))) short short8v;   // 8 bf16 = 4 VGPRs (MFMA A/B frag)
typedef __attribute__((ext_vector_type(4))) float f32x4;     // MFMA C/D frag

#define NN 4096
#define NE 32768
#define HH 128
#define MAXZ 100
#define TPB 8    // edges per block, TNE edge kernel
#define NB 2     // nodes per block in node-side kernels (grid 2048 = 8 blocks/CU)

// ENVIRONMENT FACTS (r0-r11): float tensors are FLOAT32; runtime detector kept as
// insurance (now single-dispatch: uniform branch into template impls).
// MFMA msg-edge path hardware-validated r10. r11 lesson: 4-node batching starved
// the grid (1024 blocks = 4/CU, occ 21%); NB=2 rebalances.

__device__ __forceinline__ float b2f(bf16 v){ return __bfloat162float(v); }
__device__ __forceinline__ float ldf(const float* p, size_t i){ return p[i]; }
__device__ __forceinline__ float ldf(const bf16*  p, size_t i){ return __bfloat162float(p[i]); }
__device__ __forceinline__ float siluf(float x){ return x / (1.0f + __expf(-x)); }
__device__ __forceinline__ unsigned short f2bu(float x){
  bf16 h = __float2bfloat16(x);
  return *reinterpret_cast<unsigned short*>(&h);
}

// dtype detect: flag[0]=1 if float inputs are f32, 0 if bf16.
__global__ void __launch_bounds__(256) k_detect(const unsigned int* __restrict__ w, int* __restrict__ flag){
  __shared__ int cnt[256];
  int t = threadIdx.x;
  int c = 0;
  for (int i = t; i < 4096; i += 256){
    unsigned int lo = w[i] & 0xffffu;
    int e = (int)((lo >> 7) & 0xffu);
    c += (e >= 110 && e <= 132) ? 1 : 0;
  }
  cnt[t] = c; __syncthreads();
  for (int off=128; off>=1; off>>=1){ if (t<off) cnt[t]+=cnt[t+off]; __syncthreads(); }
  if (t==0) flag[0] = (cnt[0] < 2048) ? 1 : 0;
}

// ---------------- CSR build ----------------
__global__ void __launch_bounds__(256) k_count(const int* __restrict__ dst, int* __restrict__ counts){
  int e = blockIdx.x*256 + threadIdx.x;
  if (e < NE) atomicAdd(&counts[dst[e]], 1);
}

__global__ void __launch_bounds__(1024) k_scan(const int* __restrict__ counts, int* __restrict__ offsets, int* __restrict__ cursor){
  __shared__ int lds[1024];
  int t = threadIdx.x;
  int c0 = counts[4*t+0], c1 = counts[4*t+1], c2 = counts[4*t+2], c3 = counts[4*t+3];
  int s1 = c0+c1, s2 = s1+c2, s3 = s2+c3;
  lds[t] = s3;
  __syncthreads();
  for (int off=1; off<1024; off<<=1){
    int v = lds[t];
    int add = (t>=off)? lds[t-off] : 0;
    __syncthreads();
    lds[t] = v + add;
    __syncthreads();
  }
  int incl = lds[t];
  int base = incl - s3;
  offsets[4*t+0]=base;    offsets[4*t+1]=base+c0; offsets[4*t+2]=base+s1; offsets[4*t+3]=base+s2;
  cursor [4*t+0]=base;    cursor [4*t+1]=base+c0; cursor [4*t+2]=base+s1; cursor [4*t+3]=base+s2;
  if (t==1023) offsets[4096]=incl;
}

__global__ void __launch_bounds__(256) k_fill(const int* __restrict__ dst, int* __restrict__ cursor, int* __restrict__ csr){
  int e = blockIdx.x*256 + threadIdx.x;
  if (e < NE){ int p = atomicAdd(&cursor[dst[e]], 1); csr[p] = e; }
}

// ---------------- edge geometry ----------------
template<typename T>
__device__ __forceinline__ void geom_impl(const T* ew, const T* evec,
    const int* src, const int* dst, float* gC, float* gV){
  int e = blockIdx.x*256 + threadIdx.x;
  if (e >= NE) return;
  float d = ldf(ew, e);
  float c = 0.5f*(cosf(d*0.6283185307179586f)+1.0f);
  c = (d < 5.0f) ? c : 0.0f;
  gC[e] = c;
  float x = ldf(evec, (size_t)e*3+0), y = ldf(evec, (size_t)e*3+1), z = ldf(evec, (size_t)e*3+2);
  if (src[e] != dst[e]){
    float n = sqrtf(x*x+y*y+z*z);
    float inv = 1.0f/fmaxf(n, 1e-12f);
    x*=inv; y*=inv; z*=inv;
  }
  gV[e*3+0]=x; gV[e*3+1]=y; gV[e*3+2]=z;
}
__global__ void __launch_bounds__(256) k_geom(const void* ew, const void* evec,
    const int* __restrict__ src, const int* __restrict__ dst,
    float* __restrict__ gC, float* __restrict__ gV, const int* __restrict__ flag){
  if (flag[0]) geom_impl<float>((const float*)ew, (const float*)evec, src, dst, gC, gV);
  else         geom_impl<bf16 >((const bf16* )ew, (const bf16* )evec, src, dst, gC, gV);
}

// ---------------- per-z embedding products ----------------
template<typename T>
__device__ __forceinline__ void zemb_impl(const T* emb, const T* emb2_w,
    float* P1z, float* P2z, float* Zr){
  int zv = blockIdx.x, h = threadIdx.x;
  Zr[h] = ldf(emb, (size_t)zv*HH + h);
  __syncthreads();
  float p1=0.f, p2=0.f;
  for (int r=0;r<128;++r){
    float x = Zr[r];
    p1 += x*ldf(emb2_w, (size_t)r*HH+h);
    p2 += x*ldf(emb2_w, (size_t)(r+128)*HH+h);
  }
  P1z[zv*HH+h]=p1; P2z[zv*HH+h]=p2;
}
__global__ void __launch_bounds__(128) k_zemb(const void* emb, const void* emb2_w,
    float* __restrict__ P1z, float* __restrict__ P2z, const int* __restrict__ flag){
  __shared__ float Zr[128];
  if (flag[0]) zemb_impl<float>((const float*)emb, (const float*)emb2_w, P1z, P2z, Zr);
  else         zemb_impl<bf16 >((const bf16* )emb, (const bf16* )emb2_w, P1z, P2z, Zr);
}

// ---------------- convert edge_attr -> bf16 ----------------
__global__ void __launch_bounds__(256) k_cvt_attr(const void* in, unsigned short* __restrict__ out,
                                                  const int* __restrict__ flag){
  int i = blockIdx.x*256 + threadIdx.x;
  if (flag[0]) out[i] = f2bu(((const float*)in)[i]);
  else         out[i] = ((const unsigned short*)in)[i];
}

// ---------------- weight repack into MFMA B-fragment layout ----------------
struct PackDescs {
  const void*     base[6];   // raw d_in pointer
  long            eoff[6];   // element offset (same count either dtype)
  unsigned short* out[6];
  int K[6]; int N[6];
};
template<typename T>
__device__ __forceinline__ void pack_impl(const PackDescs& d){
  int y = blockIdx.y;
  int K = d.K[y], N = d.N[y];
  int ktiles = K>>5, ntiles = N>>4;
  int total = ktiles*ntiles*64;
  int idx = blockIdx.x*256 + threadIdx.x;
  if (idx >= total) return;
  int lane = idx & 63, tile = idx >> 6;
  int kt = tile % ktiles, nt = tile / ktiles;
  const T* W = (const T*)d.base[y] + d.eoff[y];
  int n = nt*16 + (lane&15), k0 = kt*32 + (lane>>4)*8;
  unsigned int t[8];
  #pragma unroll
  for (int j=0;j<8;++j) t[j] = f2bu(ldf(W, (size_t)(k0+j)*N + n));
  uint4 v;
  v.x = t[0] | (t[1]<<16);
  v.y = t[2] | (t[3]<<16);
  v.z = t[4] | (t[5]<<16);
  v.w = t[6] | (t[7]<<16);
  *reinterpret_cast<uint4*>(d.out[y] + ((size_t)tile*64 + lane)*8) = v;
}
__global__ void __launch_bounds__(256) k_pack(PackDescs d, const int* __restrict__ flag){
  if (flag[0]) pack_impl<float>(d);
  else         pack_impl<bf16 >(d);
}

// ---------------- TNE edge coefficients -> eabuf bf16 [E][3][128] ----------------
template<typename T>
__device__ __forceinline__ void tne_edge_impl(
  const T* eattr, const int* src, const int* dst, const int* z,
  const T* dp1_w, const T* dp1_b, const T* dp2_w, const T* dp2_b,
  const T* dp3_w, const T* dp3_b, const T* emb2_b,
  const float* P1z, const float* P2z, const float* gC, bf16* eabuf,
  float (*attr)[32], int* zd, int* zs)
{
  int e0 = blockIdx.x*TPB;
  int h  = threadIdx.x;
  for (int i=h; i<TPB*32; i+=128) attr[i>>5][i&31] = ldf(eattr, (size_t)e0*32 + i);
  if (h < TPB){ int e=e0+h; zd[h]=z[dst[e]]; zs[h]=z[src[e]]; }
  __syncthreads();
  float w1[TPB], w2[TPB], w3[TPB];
  float b1v=ldf(dp1_b,h), b2v=ldf(dp2_b,h), b3v=ldf(dp3_b,h);
  #pragma unroll
  for (int e=0;e<TPB;++e){ w1[e]=b1v; w2[e]=b2v; w3[e]=b3v; }
  for (int r=0;r<32;++r){
    float u1=ldf(dp1_w,(size_t)r*HH+h), u2=ldf(dp2_w,(size_t)r*HH+h), u3=ldf(dp3_w,(size_t)r*HH+h);
    #pragma unroll
    for (int e=0;e<TPB;++e){ float a=attr[e][r]; w1[e]+=a*u1; w2[e]+=a*u2; w3[e]+=a*u3; }
  }
  float eb = ldf(emb2_b,h);
  #pragma unroll
  for (int e=0;e<TPB;++e){
    float zij = P1z[zd[e]*HH+h] + P2z[zs[e]*HH+h] + eb;
    float c = gC[e0+e];
    bf16* p = eabuf + (size_t)(e0+e)*384;
    p[h]     = __float2bfloat16(zij*w1[e]*c);
    p[128+h] = __float2bfloat16(zij*w2[e]*c);
    p[256+h] = __float2bfloat16(zij*w3[e]*c);
  }
}
__global__ void __launch_bounds__(128) k_tne_edge(
  const void* eattr, const int* __restrict__ src, const int* __restrict__ dst, const int* __restrict__ z,
  const void* dp1_w, const void* dp1_b, const void* dp2_w, const void* dp2_b,
  const void* dp3_w, const void* dp3_b, const void* emb2_b,
  const float* __restrict__ P1z, const float* __restrict__ P2z,
  const float* __restrict__ gC, bf16* __restrict__ eabuf, const int* __restrict__ flag)
{
  __shared__ float attr[TPB][32];
  __shared__ int zd[TPB], zs[TPB];
  if (flag[0]) tne_edge_impl<float>((const float*)eattr, src, dst, z,
      (const float*)dp1_w, (const float*)dp1_b, (const float*)dp2_w, (const float*)dp2_b,
      (const float*)dp3_w, (const float*)dp3_b, (const float*)emb2_b, P1z, P2z, gC, eabuf, attr, zd, zs);
  else tne_edge_impl<bf16>((const bf16*)eattr, src, dst, z,
      (const bf16*)dp1_w, (const bf16*)dp1_b, (const bf16*)dp2_w, (const bf16*)dp2_b,
      (const bf16*)dp3_w, (const bf16*)dp3_b, (const bf16*)emb2_b, P1z, P2z, gC, eabuf, attr, zd, zs);
}

// ---------------- TNE node: NB nodes/block ----------------
template<typename T>
__device__ __forceinline__ void tne_node_impl(
  const int* offsets, const int* csr, const float* gV, const bf16* eabuf,
  const T* ln_g, const T* ln_b, const T* tne_lt,
  const T* s0_w, const T* s0_b, const T* s1_w, const T* s1_b, float* X9,
  float (*sm)[10][128], float* red, float (*lnv)[128], float (*h1s)[256])
{
  int n0 = blockIdx.x*NB, h = threadIdx.x;
  float tnv[NB];
  #pragma unroll
  for (int nn=0;nn<NB;++nn){
    int n = n0+nn;
    float a=0, v0=0,v1=0,v2=0, s0=0,s1=0,s2=0,s3=0,s4=0,s5=0;
    int beg = offsets[n], end = offsets[n+1];
    for (int i=beg;i<end;++i){
      int e = csr[i];
      const bf16* p = eabuf + (size_t)e*384;
      float c1 = b2f(p[h]), c2 = b2f(p[128+h]), c3 = b2f(p[256+h]);
      float vx = gV[e*3+0], vy = gV[e*3+1], vz = gV[e*3+2];
      float tr3 = (vx*vx+vy*vy+vz*vz)*(1.0f/3.0f);
      a  += c1;
      v0 += c2*vx; v1 += c2*vy; v2 += c2*vz;
      s0 += c3*(vx*vx - tr3); s1 += c3*vx*vy;          s2 += c3*vx*vz;
      s3 += c3*(vy*vy - tr3); s4 += c3*vy*vz;          s5 += c3*(vz*vz - tr3);
    }
    sm[nn][0][h]=a; sm[nn][1][h]=v0; sm[nn][2][h]=v1; sm[nn][3][h]=v2;
    sm[nn][4][h]=s0; sm[nn][5][h]=s1; sm[nn][6][h]=s2; sm[nn][7][h]=s3; sm[nn][8][h]=s4; sm[nn][9][h]=s5;
    tnv[nn] = 3.0f*a*a + 2.0f*(v0*v0+v1*v1+v2*v2)
            + s0*s0 + s3*s3 + s5*s5 + 2.0f*(s1*s1 + s2*s2 + s4*s4);
  }
  float gg = ldf(ln_g,h), bb = ldf(ln_b,h);
  #pragma unroll
  for (int nn=0;nn<NB;++nn){
    __syncthreads();
    red[h] = tnv[nn]; __syncthreads();
    for (int off=64; off>=1; off>>=1){ if (h<off) red[h]+=red[h+off]; __syncthreads(); }
    float mean = red[0]*(1.0f/128.0f);
    __syncthreads();
    float dm = tnv[nn] - mean;
    red[h] = dm*dm; __syncthreads();
    for (int off=64; off>=1; off>>=1){ if (h<off) red[h]+=red[h+off]; __syncthreads(); }
    float var = red[0]*(1.0f/128.0f);
    lnv[nn][h] = dm*rsqrtf(var+1e-5f)*gg + bb;
  }
  __syncthreads();
  {
    float ba = ldf(s0_b,2*h), bc = ldf(s0_b,2*h+1);
    float a0[NB], a1[NB];
    #pragma unroll
    for (int nn=0;nn<NB;++nn){ a0[nn]=ba; a1[nn]=bc; }
    for (int r=0;r<128;++r){
      float u0 = ldf(s0_w,(size_t)r*256+2*h), u1 = ldf(s0_w,(size_t)r*256+2*h+1);
      #pragma unroll
      for (int nn=0;nn<NB;++nn){ float x = lnv[nn][r]; a0[nn]+=x*u0; a1[nn]+=x*u1; }
    }
    #pragma unroll
    for (int nn=0;nn<NB;++nn){ h1s[nn][2*h] = siluf(a0[nn]); h1s[nn][2*h+1] = siluf(a1[nn]); }
  }
  __syncthreads();
  float f0[NB], f1[NB], f2[NB];
  {
    float b0 = ldf(s1_b,3*h), b1 = ldf(s1_b,3*h+1), b2 = ldf(s1_b,3*h+2);
    #pragma unroll
    for (int nn=0;nn<NB;++nn){ f0[nn]=b0; f1[nn]=b1; f2[nn]=b2; }
    for (int r=0;r<256;++r){
      float u0 = ldf(s1_w,(size_t)r*384+3*h), u1 = ldf(s1_w,(size_t)r*384+3*h+1), u2 = ldf(s1_w,(size_t)r*384+3*h+2);
      #pragma unroll
      for (int nn=0;nn<NB;++nn){ float x = h1s[nn][r]; f0[nn]+=x*u0; f1[nn]+=x*u1; f2[nn]+=x*u2; }
    }
    #pragma unroll
    for (int nn=0;nn<NB;++nn){ f0[nn]=siluf(f0[nn]); f1[nn]=siluf(f1[nn]); f2[nn]=siluf(f2[nn]); }
  }
  float am[NB]={0};
  float wm0[NB]={0}, wm1[NB]={0}, wm2[NB]={0};
  float t0[NB]={0}, t1[NB]={0}, t2[NB]={0};
  float t3[NB]={0}, t4[NB]={0}, t5[NB]={0};
  for (int r=0;r<128;++r){
    float w0 = ldf(tne_lt,(size_t)r*128+h);
    float w1 = ldf(tne_lt,(size_t)16384+r*128+h);
    float w2 = ldf(tne_lt,(size_t)32768+r*128+h);
    #pragma unroll
    for (int nn=0;nn<NB;++nn){
      am[nn]  += sm[nn][0][r]*w0;
      wm0[nn] += sm[nn][1][r]*w1; wm1[nn] += sm[nn][2][r]*w1; wm2[nn] += sm[nn][3][r]*w1;
      t0[nn] += sm[nn][4][r]*w2; t1[nn] += sm[nn][5][r]*w2; t2[nn] += sm[nn][6][r]*w2;
      t3[nn] += sm[nn][7][r]*w2; t4[nn] += sm[nn][8][r]*w2; t5[nn] += sm[nn][9][r]*w2;
    }
  }
  #pragma unroll
  for (int nn=0;nn<NB;++nn){
    float x00 = f0[nn]*am[nn] + f2[nn]*t0[nn];
    float x01 = -f1[nn]*wm2[nn] + f2[nn]*t1[nn];
    float x02 =  f1[nn]*wm1[nn] + f2[nn]*t2[nn];
    float x10 =  f1[nn]*wm2[nn] + f2[nn]*t1[nn];
    float x11 = f0[nn]*am[nn] + f2[nn]*t3[nn];
    float x12 = -f1[nn]*wm0[nn] + f2[nn]*t4[nn];
    float x20 = -f1[nn]*wm1[nn] + f2[nn]*t2[nn];
    float x21 =  f1[nn]*wm0[nn] + f2[nn]*t4[nn];
    float x22 = f0[nn]*am[nn] + f2[nn]*t5[nn];
    float* xp = X9 + (size_t)(n0+nn)*1152;
    xp[0*128+h]=x00; xp[1*128+h]=x01; xp[2*128+h]=x02;
    xp[3*128+h]=x10; xp[4*128+h]=x11; xp[5*128+h]=x12;
    xp[6*128+h]=x20; xp[7*128+h]=x21; xp[8*128+h]=x22;
  }
}
__global__ void __launch_bounds__(128) k_tne_node(
  const int* __restrict__ offsets, const int* __restrict__ csr,
  const float* __restrict__ gV, const bf16* __restrict__ eabuf,
  const void* ln_g, const void* ln_b, const void* tne_lt,
  const void* s0_w, const void* s0_b, const void* s1_w, const void* s1_b,
  float* __restrict__ X9, const int* __restrict__ flag)
{
  __shared__ float sm[NB][10][128];
  __shared__ float red[128];
  __shared__ float lnv[NB][128];
  __shared__ float h1s[NB][256];
  if (flag[0]) tne_node_impl<float>(offsets, csr, gV, eabuf,
      (const float*)ln_g, (const float*)ln_b, (const float*)tne_lt,
      (const float*)s0_w, (const float*)s0_b, (const float*)s1_w, (const float*)s1_b, X9, sm, red, lnv, h1s);
  else tne_node_impl<bf16>(offsets, csr, gV, eabuf,
      (const bf16*)ln_g, (const bf16*)ln_b, (const bf16*)tne_lt,
      (const bf16*)s0_w, (const bf16*)s0_b, (const bf16*)s1_w, (const bf16*)s1_b, X9, sm, red, lnv, h1s);
}

// ---------------- msg edge MLP via MFMA (r10-validated math) ----------------
template<typename T>
__device__ __forceinline__ void mfma_impl(
  const unsigned short* eattr_c, const float* gC,
  const unsigned short* p0, const unsigned short* p1, const unsigned short* p2,
  const T* b0, const T* b1, const T* b2,
  unsigned short* eabuf, unsigned short (*h1p)[2048], unsigned short (*h2p)[4096])
{
  int wid  = threadIdx.x >> 6;
  int lane = threadIdx.x & 63;
  int e0 = blockIdx.x*32 + wid*16;
  int m = lane & 15, g = lane >> 4;
  float cc[4];
  #pragma unroll
  for (int r=0;r<4;++r) cc[r] = gC[e0 + g*4 + r];
  short8v a1 = *reinterpret_cast<const short8v*>(eattr_c + (size_t)(e0+m)*32 + g*8);
  #pragma unroll
  for (int nt=0; nt<8; ++nt){
    float bias = ldf(b0, nt*16+m);
    f32x4 acc = {bias,bias,bias,bias};
    short8v b = *reinterpret_cast<const short8v*>(p0 + ((size_t)nt*64 + lane)*8);
    acc = __builtin_amdgcn_mfma_f32_16x16x32_bf16(a1, b, acc, 0,0,0);
    #pragma unroll
    for (int r=0;r<4;++r){
      int n = nt*16 + m, row = g*4 + r;
      h1p[wid][(n>>5)*512 + (((n>>3)&3)*16+row)*8 + (n&7)] = f2bu(siluf(acc[r]));
    }
  }
  __syncthreads();
  short8v a2[4];
  #pragma unroll
  for (int ks=0; ks<4; ++ks) a2[ks] = *reinterpret_cast<const short8v*>(&h1p[wid][ks*512 + lane*8]);
  for (int nt=0; nt<16; ++nt){
    float bias = ldf(b1, nt*16+m);
    f32x4 acc = {bias,bias,bias,bias};
    #pragma unroll
    for (int ks=0; ks<4; ++ks){
      short8v b = *reinterpret_cast<const short8v*>(p1 + ((size_t)(nt*4+ks)*64 + lane)*8);
      acc = __builtin_amdgcn_mfma_f32_16x16x32_bf16(a2[ks], b, acc, 0,0,0);
    }
    #pragma unroll
    for (int r=0;r<4;++r){
      int n = nt*16 + m, row = g*4 + r;
      h2p[wid][(n>>5)*512 + (((n>>3)&3)*16+row)*8 + (n&7)] = f2bu(siluf(acc[r]));
    }
  }
  __syncthreads();
  short8v a3[8];
  #pragma unroll
  for (int ks=0; ks<8; ++ks) a3[ks] = *reinterpret_cast<const short8v*>(&h2p[wid][ks*512 + lane*8]);
  for (int nt=0; nt<24; ++nt){
    float bias = ldf(b2, nt*16+m);
    f32x4 acc = {bias,bias,bias,bias};
    #pragma unroll
    for (int ks=0; ks<8; ++ks){
      short8v b = *reinterpret_cast<const short8v*>(p2 + ((size_t)(nt*8+ks)*64 + lane)*8);
      acc = __builtin_amdgcn_mfma_f32_16x16x32_bf16(a3[ks], b, acc, 0,0,0);
    }
    #pragma unroll
    for (int r=0;r<4;++r){
      int n = nt*16 + m, row = g*4 + r;
      float v = siluf(acc[r]) * cc[r];
      eabuf[(size_t)(e0+row)*384 + (n%3)*128 + (n/3)] = f2bu(v);
    }
  }
}
__global__ void __launch_bounds__(128) k_msg_edge_mfma(
  const unsigned short* __restrict__ eattr_c, const float* __restrict__ gC,
  const unsigned short* __restrict__ p0, const unsigned short* __restrict__ p1,
  const unsigned short* __restrict__ p2,
  const void* b0, const void* b1, const void* b2, long boff0, long boff1, long boff2,
  unsigned short* __restrict__ eabuf, const int* __restrict__ flag)
{
  __shared__ __align__(16) unsigned short h1p[2][2048];
  __shared__ __align__(16) unsigned short h2p[2][4096];
  if (flag[0]) mfma_impl<float>(eattr_c, gC, p0, p1, p2,
      (const float*)b0 + boff0, (const float*)b1 + boff1, (const float*)b2 + boff2, eabuf, h1p, h2p);
  else mfma_impl<bf16>(eattr_c, gC, p0, p1, p2,
      (const bf16*)b0 + boff0, (const bf16*)b1 + boff1, (const bf16*)b2 + boff2, eabuf, h1p, h2p);
}

// ---------------- msg node prep (NB nodes/block) ----------------
template<typename T>
__device__ __forceinline__ void prep_impl(
  float* X9, const T* lx, bf16* Y10, float (*sm)[10][128])
{
  int n0 = blockIdx.x*NB, h = threadIdx.x;
  #pragma unroll
  for (int nn=0;nn<NB;++nn){
    float* xp = X9 + (size_t)(n0+nn)*1152;
    float x00=xp[0*128+h], x01=xp[1*128+h], x02=xp[2*128+h];
    float x10=xp[3*128+h], x11=xp[4*128+h], x12=xp[5*128+h];
    float x20=xp[6*128+h], x21=xp[7*128+h], x22=xp[8*128+h];
    float tn = x00*x00+x01*x01+x02*x02+x10*x10+x11*x11+x12*x12+x20*x20+x21*x21+x22*x22;
    float inv = 1.0f/(tn+1.0f);
    x00*=inv; x01*=inv; x02*=inv; x10*=inv; x11*=inv; x12*=inv; x20*=inv; x21*=inv; x22*=inv;
    // Reference REBINDS X to normalized before the update (r3 fix).
    xp[0*128+h]=x00; xp[1*128+h]=x01; xp[2*128+h]=x02;
    xp[3*128+h]=x10; xp[4*128+h]=x11; xp[5*128+h]=x12;
    xp[6*128+h]=x20; xp[7*128+h]=x21; xp[8*128+h]=x22;
    float a = (x00+x11+x22)*(1.0f/3.0f);
    sm[nn][0][h]=a;
    sm[nn][1][h]=0.5f*(x21-x12);
    sm[nn][2][h]=0.5f*(x02-x20);
    sm[nn][3][h]=0.5f*(x10-x01);
    sm[nn][4][h]=x00-a;
    sm[nn][5][h]=0.5f*(x01+x10);
    sm[nn][6][h]=0.5f*(x02+x20);
    sm[nn][7][h]=x11-a;
    sm[nn][8][h]=0.5f*(x12+x21);
    sm[nn][9][h]=x22-a;
  }
  __syncthreads();
  float A[NB]={0};
  float V0[NB]={0}, V1[NB]={0}, V2[NB]={0};
  float S0[NB]={0}, S1[NB]={0}, S2[NB]={0};
  float S3[NB]={0}, S4[NB]={0}, S5[NB]={0};
  for (int r=0;r<128;++r){
    float w0 = ldf(lx,(size_t)r*128+h), w1 = ldf(lx,(size_t)16384+r*128+h), w2 = ldf(lx,(size_t)32768+r*128+h);
    #pragma unroll
    for (int nn=0;nn<NB;++nn){
      A[nn]  += sm[nn][0][r]*w0;
      V0[nn] += sm[nn][1][r]*w1; V1[nn] += sm[nn][2][r]*w1; V2[nn] += sm[nn][3][r]*w1;
      S0[nn] += sm[nn][4][r]*w2; S1[nn] += sm[nn][5][r]*w2; S2[nn] += sm[nn][6][r]*w2;
      S3[nn] += sm[nn][7][r]*w2; S4[nn] += sm[nn][8][r]*w2; S5[nn] += sm[nn][9][r]*w2;
    }
  }
  #pragma unroll
  for (int nn=0;nn<NB;++nn){
    bf16* yp = Y10 + (size_t)(n0+nn)*1280;
    yp[0*128+h]=__float2bfloat16(A[nn]);
    yp[1*128+h]=__float2bfloat16(V0[nn]); yp[2*128+h]=__float2bfloat16(V1[nn]); yp[3*128+h]=__float2bfloat16(V2[nn]);
    yp[4*128+h]=__float2bfloat16(S0[nn]); yp[5*128+h]=__float2bfloat16(S1[nn]); yp[6*128+h]=__float2bfloat16(S2[nn]);
    yp[7*128+h]=__float2bfloat16(S3[nn]); yp[8*128+h]=__float2bfloat16(S4[nn]); yp[9*128+h]=__float2bfloat16(S5[nn]);
  }
}
__global__ void __launch_bounds__(128) k_msg_prep(
  float* __restrict__ X9, const void* lx, long lxoff, bf16* __restrict__ Y10,
  const int* __restrict__ flag)
{
  __shared__ float sm[NB][10][128];
  if (flag[0]) prep_impl<float>(X9, (const float*)lx + lxoff, Y10, sm);
  else         prep_impl<bf16 >(X9, (const bf16* )lx + lxoff, Y10, sm);
}

// ---------------- msg scatter+AB+decompose + NB-batched lt cmix + dX update ----------------
template<typename T>
__device__ __forceinline__ void sf_impl(
  const int* offsets, const int* csr, const int* srcA,
  const bf16* eabuf, const bf16* Y10, const T* lt,
  float* X9, T* out, int write_out, float (*sm)[10][128])
{
  int n0 = blockIdx.x*NB, h = threadIdx.x;
  #pragma unroll
  for (int nn=0;nn<NB;++nn){
    int n = n0+nn;
    float am=0, vm0=0,vm1=0,vm2=0, smm0=0,smm1=0,smm2=0,smm3=0,smm4=0,smm5=0;
    int beg = offsets[n], end = offsets[n+1];
    for (int i=beg;i<end;++i){
      int e = csr[i]; int s = srcA[e];
      const bf16* ep = eabuf + (size_t)e*384;
      float e0 = b2f(ep[h]), e1 = b2f(ep[128+h]), e2 = b2f(ep[256+h]);
      const bf16* yp = Y10 + (size_t)s*1280;
      am   += e0*b2f(yp[0*128+h]);
      vm0  += e1*b2f(yp[1*128+h]); vm1 += e1*b2f(yp[2*128+h]); vm2 += e1*b2f(yp[3*128+h]);
      smm0 += e2*b2f(yp[4*128+h]); smm1 += e2*b2f(yp[5*128+h]); smm2 += e2*b2f(yp[6*128+h]);
      smm3 += e2*b2f(yp[7*128+h]); smm4 += e2*b2f(yp[8*128+h]); smm5 += e2*b2f(yp[9*128+h]);
    }
    const bf16* yp = Y10 + (size_t)n*1280;
    float aY=b2f(yp[0*128+h]), u0=b2f(yp[1*128+h]), u1=b2f(yp[2*128+h]), u2=b2f(yp[3*128+h]);
    float q0=b2f(yp[4*128+h]), q1=b2f(yp[5*128+h]), q2=b2f(yp[6*128+h]);
    float q3=b2f(yp[7*128+h]), q4=b2f(yp[8*128+h]), q5=b2f(yp[9*128+h]);
    float m00=am+smm0,   m01=-vm2+smm1, m02= vm1+smm2;
    float m10= vm2+smm1, m11=am+smm3,  m12=-vm0+smm4;
    float m20=-vm1+smm2, m21= vm0+smm4, m22=am+smm5;
    float y00=aY+q0,  y01=-u2+q1, y02= u1+q2;
    float y10= u2+q1, y11=aY+q3,  y12=-u0+q4;
    float y20=-u1+q2, y21= u0+q4, y22=aY+q5;
    float ab00 = m00*y00+m01*y10+m02*y20 + y00*m00+y01*m10+y02*m20;
    float ab01 = m00*y01+m01*y11+m02*y21 + y00*m01+y01*m11+y02*m21;
    float ab02 = m00*y02+m01*y12+m02*y22 + y00*m02+y01*m12+y02*m22;
    float ab10 = m10*y00+m11*y10+m12*y20 + y10*m00+y11*m10+y12*m20;
    float ab11 = m10*y01+m11*y11+m12*y21 + y10*m01+y11*m11+y12*m21;
    float ab12 = m10*y02+m11*y12+m12*y22 + y10*m02+y11*m12+y12*m22;
    float ab20 = m20*y00+m21*y10+m22*y20 + y20*m00+y21*m10+y22*m20;
    float ab21 = m20*y01+m21*y11+m22*y21 + y20*m01+y21*m11+y22*m21;
    float ab22 = m20*y02+m21*y12+m22*y22 + y20*m02+y21*m12+y22*m22;
    float a2 = (ab00+ab11+ab22)*(1.0f/3.0f);
    float w0 = 0.5f*(ab21-ab12), w1 = 0.5f*(ab02-ab20), w2 = 0.5f*(ab10-ab01);
    float t0 = ab00-a2, t1 = 0.5f*(ab01+ab10), t2 = 0.5f*(ab02+ab20);
    float t3 = ab11-a2, t4 = 0.5f*(ab12+ab21), t5 = ab22-a2;
    float dnm = ab00*ab00+ab01*ab01+ab02*ab02+ab10*ab10+ab11*ab11+ab12*ab12
              + ab20*ab20+ab21*ab21+ab22*ab22 + 1.0f;
    float inv = 1.0f/dnm;
    sm[nn][0][h]=a2*inv; sm[nn][1][h]=w0*inv; sm[nn][2][h]=w1*inv; sm[nn][3][h]=w2*inv;
    sm[nn][4][h]=t0*inv; sm[nn][5][h]=t1*inv; sm[nn][6][h]=t2*inv;
    sm[nn][7][h]=t3*inv; sm[nn][8][h]=t4*inv; sm[nn][9][h]=t5*inv;
  }
  __syncthreads();
  float at[NB]={0};
  float vt0[NB]={0}, vt1[NB]={0}, vt2[NB]={0};
  float st0[NB]={0}, st1[NB]={0}, st2[NB]={0};
  float st3[NB]={0}, st4[NB]={0}, st5[NB]={0};
  for (int r=0;r<128;++r){
    float ww0 = ldf(lt,(size_t)r*128+h);
    float ww1 = ldf(lt,(size_t)16384+r*128+h);
    float ww2 = ldf(lt,(size_t)32768+r*128+h);
    #pragma unroll
    for (int nn=0;nn<NB;++nn){
      at[nn]  += sm[nn][0][r]*ww0;
      vt0[nn] += sm[nn][1][r]*ww1; vt1[nn] += sm[nn][2][r]*ww1; vt2[nn] += sm[nn][3][r]*ww1;
      st0[nn] += sm[nn][4][r]*ww2; st1[nn] += sm[nn][5][r]*ww2; st2[nn] += sm[nn][6][r]*ww2;
      st3[nn] += sm[nn][7][r]*ww2; st4[nn] += sm[nn][8][r]*ww2; st5[nn] += sm[nn][9][r]*ww2;
    }
  }
  #pragma unroll
  for (int nn=0;nn<NB;++nn){
    int n = n0+nn;
    float d00=at[nn]+st0[nn],   d01=-vt2[nn]+st1[nn], d02= vt1[nn]+st2[nn];
    float d10= vt2[nn]+st1[nn], d11=at[nn]+st3[nn],  d12=-vt0[nn]+st4[nn];
    float d20=-vt1[nn]+st2[nn], d21= vt0[nn]+st4[nn], d22=at[nn]+st5[nn];
    float g00 = d00 + d00*d00+d01*d10+d02*d20;
    float g01 = d01 + d00*d01+d01*d11+d02*d21;
    float g02 = d02 + d00*d02+d01*d12+d02*d22;
    float g10 = d10 + d10*d00+d11*d10+d12*d20;
    float g11 = d11 + d10*d01+d11*d11+d12*d21;
    float g12 = d12 + d10*d02+d11*d12+d12*d22;
    float g20 = d20 + d20*d00+d21*d10+d22*d20;
    float g21 = d21 + d20*d01+d21*d11+d22*d21;
    float g22 = d22 + d20*d02+d21*d12+d22*d22;
    float* xp = X9 + (size_t)n*1152;
    float x00=xp[0*128+h]+g00, x01=xp[1*128+h]+g01, x02=xp[2*128+h]+g02;
    float x10=xp[3*128+h]+g10, x11=xp[4*128+h]+g11, x12=xp[5*128+h]+g12;
    float x20=xp[6*128+h]+g20, x21=xp[7*128+h]+g21, x22=xp[8*128+h]+g22;
    if (write_out){
      if (sizeof(T)==4){
        float* of = (float*)out + ((size_t)n*128 + h)*9;
        of[0]=x00; of[1]=x01; of[2]=x02; of[3]=x10; of[4]=x11; of[5]=x12; of[6]=x20; of[7]=x21; of[8]=x22;
      } else {
        bf16* ob = (bf16*)out + ((size_t)n*128 + h)*9;
        ob[0]=__float2bfloat16(x00); ob[1]=__float2bfloat16(x01); ob[2]=__float2bfloat16(x02);
        ob[3]=__float2bfloat16(x10); ob[4]=__float2bfloat16(x11); ob[5]=__float2bfloat16(x12);
        ob[6]=__float2bfloat16(x20); ob[7]=__float2bfloat16(x21); ob[8]=__float2bfloat16(x22);
      }
    } else {
      xp[0*128+h]=x00; xp[1*128+h]=x01; xp[2*128+h]=x02;
      xp[3*128+h]=x10; xp[4*128+h]=x11; xp[5*128+h]=x12;
      xp[6*128+h]=x20; xp[7*128+h]=x21; xp[8*128+h]=x22;
    }
  }
}
__global__ void __launch_bounds__(128) k_msg_sf(
  const int* __restrict__ offsets, const int* __restrict__ csr, const int* __restrict__ srcA,
  const bf16* __restrict__ eabuf, const bf16* __restrict__ Y10,
  const void* lt, long ltoff, float* __restrict__ X9, void* __restrict__ out,
  const int* __restrict__ flag, int write_out)
{
  __shared__ float sm[NB][10][128];
  if (flag[0]) sf_impl<float>(offsets, csr, srcA, eabuf, Y10, (const float*)lt + ltoff, X9, (float*)out, write_out, sm);
  else         sf_impl<bf16 >(offsets, csr, srcA, eabuf, Y10, (const bf16* )lt + ltoff, X9, (bf16* )out, write_out, sm);
}

extern "C" void kernel_launch(void* const* d_in, const int* in_sizes, int n_in,
                              void* d_out, int out_size, void* d_ws, size_t ws_size,
                              hipStream_t stream)
{
  (void)in_sizes; (void)n_in; (void)out_size; (void)ws_size;
  const int* z    = (const int*)d_in[0];
  const int* eidx = (const int*)d_in[1];
  const int* src  = eidx;
  const int* dst  = eidx + NE;

  // Workspace: ~58 MiB (proven budget >= 74 MiB).
  char* w = (char*)d_ws;
  int* flag    = (int*)w;   w += 64;
  int* counts  = (int*)w;   w += (size_t)NN*4;
  int* offsets = (int*)w;   w += (size_t)(NN+1)*4 + 60;
  int* cursor  = (int*)w;   w += (size_t)NN*4;
  int* csr     = (int*)w;   w += (size_t)NE*4;
  float* gC    = (float*)w; w += (size_t)NE*4;
  float* gV    = (float*)w; w += (size_t)NE*12;
  float* P1z   = (float*)w; w += (size_t)MAXZ*HH*4;
  float* P2z   = (float*)w; w += (size_t)MAXZ*HH*4;
  bf16* eabuf  = (bf16*)w;  w += (size_t)NE*384*2;
  float* X9    = (float*)w; w += (size_t)NN*1152*4;
  bf16* Y10    = (bf16*)w;  w += (size_t)NN*1280*2;
  unsigned short* eattr_c = (unsigned short*)w; w += (size_t)NE*32*2;
  unsigned short* pw0[2]; unsigned short* pw1[2]; unsigned short* pw2[2];
  for (int l=0;l<2;++l){
    pw0[l] = (unsigned short*)w; w += 8*64*8*2;
    pw1[l] = (unsigned short*)w; w += 64*64*8*2;
    pw2[l] = (unsigned short*)w; w += 192*64*8*2;
  }

  k_detect<<<1, 256, 0, stream>>>((const unsigned int*)d_in[4], flag);
  hipMemsetAsync(counts, 0, (size_t)NN*4, stream);
  k_count<<<NE/256, 256, 0, stream>>>(dst, counts);
  k_scan<<<1, 1024, 0, stream>>>(counts, offsets, cursor);
  k_fill<<<NE/256, 256, 0, stream>>>(dst, cursor, csr);
  k_geom<<<NE/256, 256, 0, stream>>>(d_in[2], d_in[3], src, dst, gC, gV, flag);
  k_zemb<<<MAXZ, 128, 0, stream>>>(d_in[5], d_in[12], P1z, P2z, flag);
  k_cvt_attr<<<NE*32/256, 256, 0, stream>>>(d_in[4], eattr_c, flag);

  PackDescs pd;
  for (int l=0;l<2;++l){
    pd.base[l*3+0] = d_in[21]; pd.eoff[l*3+0] = (long)l*32*128;
    pd.base[l*3+1] = d_in[23]; pd.eoff[l*3+1] = (long)l*128*256;
    pd.base[l*3+2] = d_in[25]; pd.eoff[l*3+2] = (long)l*256*384;
    pd.out[l*3+0] = pw0[l]; pd.K[l*3+0]=32;  pd.N[l*3+0]=128;
    pd.out[l*3+1] = pw1[l]; pd.K[l*3+1]=128; pd.N[l*3+1]=256;
    pd.out[l*3+2] = pw2[l]; pd.K[l*3+2]=256; pd.N[l*3+2]=384;
  }
  k_pack<<<dim3(48, 6), 256, 0, stream>>>(pd, flag);

  k_tne_edge<<<NE/TPB, 128, 0, stream>>>(d_in[4], src, dst, z,
      d_in[6], d_in[7], d_in[8], d_in[9], d_in[10], d_in[11], d_in[13],
      P1z, P2z, gC, eabuf, flag);
  k_tne_node<<<NN/NB, 128, 0, stream>>>(offsets, csr, gV, eabuf,
      d_in[19], d_in[20], d_in[14], d_in[15], d_in[16], d_in[17], d_in[18], X9, flag);

  for (int l=0; l<2; ++l){
    k_msg_edge_mfma<<<NE/32, 128, 0, stream>>>(eattr_c, gC, pw0[l], pw1[l], pw2[l],
        d_in[22], d_in[24], d_in[26], (long)l*128, (long)l*256, (long)l*384,
        (unsigned short*)eabuf, flag);
    k_msg_prep<<<NN/NB, 128, 0, stream>>>(X9, d_in[27], (long)l*3*128*128, Y10, flag);
    k_msg_sf<<<NN/NB, 128, 0, stream>>>(offsets, csr, src, eabuf, Y10,
        d_in[28], (long)l*3*128*128, X9, d_out, flag, (l==1)?1:0);
  }
}